// Round 4
// baseline (924.245 us; speedup 1.0000x reference)
//
#include <hip/hip_runtime.h>
#include <hip/hip_bf16.h>

#define NN 50000
#define NE 1600000
#define NIN 256
#define HID 32
#define FOUT 128
#define OSTR 256
#define NB ((NN + 31) / 32)   // 1563 coarse buckets (32 nodes each)

static constexpr float EPS = 1e-12f;

// ---------------- degree (both views, one launch) ----------------
__global__ __launch_bounds__(256) void k_deg2(const int* __restrict__ dstA,
                                              const int* __restrict__ dstB,
                                              unsigned* __restrict__ degA,
                                              unsigned* __restrict__ degB, int half) {
    bool sec = blockIdx.x >= half;
    int i = (sec ? blockIdx.x - half : blockIdx.x) * 256 + threadIdx.x;
    if (i < NE) {
        if (sec) atomicAdd(&degB[dstB[i]], 1u);
        else     atomicAdd(&degA[dstA[i]], 1u);
    }
}

__global__ __launch_bounds__(256) void k_dinv2(const unsigned* __restrict__ degA,
                                               const unsigned* __restrict__ degB,
                                               float* __restrict__ dinvA,
                                               float* __restrict__ dinvB, int N) {
    int i = blockIdx.x * 256 + threadIdx.x;
    if (i < N) {
        dinvA[i] = rsqrtf((float)(degA[i] + 1u));
        dinvB[i] = rsqrtf((float)(degB[i] + 1u));
    }
}

// ---------------- exclusive scan (both views per launch) ----------------
__global__ __launch_bounds__(256) void k_scan1_2(const unsigned* __restrict__ degA,
                                                 const unsigned* __restrict__ degB,
                                                 int* __restrict__ outA, int* __restrict__ outB,
                                                 unsigned* __restrict__ bsumA,
                                                 unsigned* __restrict__ bsumB, int N, int half) {
    __shared__ unsigned tmp[256];
    bool sec = blockIdx.x >= half;
    int blk = sec ? blockIdx.x - half : blockIdx.x;
    const unsigned* deg = sec ? degB : degA;
    int* out = sec ? outB : outA;
    unsigned* bsum = sec ? bsumB : bsumA;
    int i = blk * 256 + threadIdx.x;
    unsigned v = (i < N) ? deg[i] : 0u;
    tmp[threadIdx.x] = v;
    __syncthreads();
    for (int off = 1; off < 256; off <<= 1) {
        unsigned t = (threadIdx.x >= (unsigned)off) ? tmp[threadIdx.x - off] : 0u;
        __syncthreads();
        tmp[threadIdx.x] += t;
        __syncthreads();
    }
    if (i < N) out[i] = (int)(tmp[threadIdx.x] - v);
    if (threadIdx.x == 255) bsum[blk] = tmp[255];
}

__global__ __launch_bounds__(256) void k_scan2_2(unsigned* __restrict__ bsumA,
                                                 unsigned* __restrict__ bsumB, int NBk) {
    __shared__ unsigned tmp[256];
    unsigned* bsum = (blockIdx.x == 0) ? bsumA : bsumB;
    unsigned v = (threadIdx.x < (unsigned)NBk) ? bsum[threadIdx.x] : 0u;
    tmp[threadIdx.x] = v;
    __syncthreads();
    for (int off = 1; off < 256; off <<= 1) {
        unsigned t = (threadIdx.x >= (unsigned)off) ? tmp[threadIdx.x - off] : 0u;
        __syncthreads();
        tmp[threadIdx.x] += t;
        __syncthreads();
    }
    if (threadIdx.x < (unsigned)NBk) bsum[threadIdx.x] = tmp[threadIdx.x] - v;
}

__global__ __launch_bounds__(256) void k_scan3_2(int* __restrict__ outA, int* __restrict__ outB,
                                                 const unsigned* __restrict__ bsumA,
                                                 const unsigned* __restrict__ bsumB,
                                                 int N, int half) {
    bool sec = blockIdx.x >= half;
    int blk = sec ? blockIdx.x - half : blockIdx.x;
    int* out = sec ? outB : outA;
    const unsigned* bsum = sec ? bsumB : bsumA;
    int i = blk * 256 + threadIdx.x;
    if (i < N) out[i] += (int)bsum[blk];
}

// ---------------- 2-pass CSR build ----------------
__global__ __launch_bounds__(256) void k_curinit(const int* __restrict__ rpA,
                                                 const int* __restrict__ rpB,
                                                 unsigned* __restrict__ curA,
                                                 unsigned* __restrict__ curB) {
    int b = blockIdx.x * 256 + threadIdx.x;
    if (b < NB) {
        curA[b] = (unsigned)rpA[b * 32];
        curB[b] = (unsigned)rpB[b * 32];
    }
}

// pass 1: coarse bin by dst>>5, payload = (dst&31)<<16 | src  (both < 2^16)
__global__ __launch_bounds__(256) void k_bin1(const int* __restrict__ srcA,
                                              const int* __restrict__ dstA,
                                              unsigned* __restrict__ curA,
                                              int* __restrict__ tmpA,
                                              const int* __restrict__ srcB,
                                              const int* __restrict__ dstB,
                                              unsigned* __restrict__ curB,
                                              int* __restrict__ tmpB, int half) {
    bool sec = blockIdx.x >= half;
    int e = (sec ? blockIdx.x - half : blockIdx.x) * 256 + threadIdx.x;
    if (e >= NE) return;
    const int* src = sec ? srcB : srcA;
    const int* dst = sec ? dstB : dstA;
    unsigned* cur = sec ? curB : curA;
    int* tmp = sec ? tmpB : tmpA;
    int d = dst[e];
    unsigned p = atomicAdd(&cur[d >> 5], 1u);
    tmp[p] = ((d & 31) << 16) | src[e];
}

// pass 2: one block per coarse bucket; LDS cursors for 32 dst rows
__global__ __launch_bounds__(256) void k_bin2(const int* __restrict__ tmpA,
                                              const int* __restrict__ rpA,
                                              int* __restrict__ csrA,
                                              const int* __restrict__ tmpB,
                                              const int* __restrict__ rpB,
                                              int* __restrict__ csrB, int half) {
    __shared__ int lcur[32];
    bool sec = blockIdx.x >= half;
    int b = sec ? blockIdx.x - half : blockIdx.x;
    const int* tmp = sec ? tmpB : tmpA;
    const int* rowptr = sec ? rpB : rpA;
    int* csr = sec ? csrB : csrA;
    int base = b * 32;
    int beg = rowptr[base];
    int end = (b == NB - 1) ? NE : rowptr[base + 32];
    if (threadIdx.x < 32) {
        int n = base + threadIdx.x;
        lcur[threadIdx.x] = (n < NN) ? rowptr[n] : 0;
    }
    __syncthreads();
    for (int e = beg + (int)threadIdx.x; e < end; e += 256) {
        int packed = tmp[e];
        int pos = atomicAdd(&lcur[packed >> 16], 1);
        csr[pos] = packed & 0xFFFF;
    }
}

// ---------------- GEMMs (W staged in LDS) ----------------
__global__ __launch_bounds__(256) void k_gemm_in(const float* __restrict__ x,
                                                 const float* __restrict__ W,
                                                 float* __restrict__ h, int N) {
    __shared__ float Ws[NIN * HID];
    for (int i = threadIdx.x; i < NIN * HID; i += 256) Ws[i] = W[i];
    __syncthreads();
    int row = blockIdx.x * 8 + (threadIdx.x >> 5);
    int col = threadIdx.x & 31;
    if (row >= N) return;
    const float4* xr = reinterpret_cast<const float4*>(x + (size_t)row * NIN);
    float acc = 0.f;
#pragma unroll
    for (int k4 = 0; k4 < NIN / 4; ++k4) {
        float4 v = xr[k4];
        int k = k4 * 4;
        acc = fmaf(v.x, Ws[(k + 0) * HID + col], acc);
        acc = fmaf(v.y, Ws[(k + 1) * HID + col], acc);
        acc = fmaf(v.z, Ws[(k + 2) * HID + col], acc);
        acc = fmaf(v.w, Ws[(k + 3) * HID + col], acc);
    }
    h[(size_t)row * HID + col] = acc;
}

// both views: out = (in @ W) * dinv[row], one launch
__global__ __launch_bounds__(256) void k_gemm_hid2(const float* __restrict__ inA,
                                                   const float* __restrict__ dinvA,
                                                   float* __restrict__ outA,
                                                   const float* __restrict__ inB,
                                                   const float* __restrict__ dinvB,
                                                   float* __restrict__ outB,
                                                   const float* __restrict__ W,
                                                   int N, int half) {
    __shared__ float Ws[HID * HID];
    for (int i = threadIdx.x; i < HID * HID; i += 256) Ws[i] = W[i];
    __syncthreads();
    bool sec = blockIdx.x >= half;
    int blk = sec ? blockIdx.x - half : blockIdx.x;
    const float* in = sec ? inB : inA;
    const float* dinv = sec ? dinvB : dinvA;
    float* out = sec ? outB : outA;
    int row = blk * 8 + (threadIdx.x >> 5);
    int col = threadIdx.x & 31;
    if (row >= N) return;
    const float4* xr = reinterpret_cast<const float4*>(in + (size_t)row * HID);
    float acc = 0.f;
#pragma unroll
    for (int k4 = 0; k4 < HID / 4; ++k4) {
        float4 v = xr[k4];
        int k = k4 * 4;
        acc = fmaf(v.x, Ws[(k + 0) * HID + col], acc);
        acc = fmaf(v.y, Ws[(k + 1) * HID + col], acc);
        acc = fmaf(v.z, Ws[(k + 2) * HID + col], acc);
        acc = fmaf(v.w, Ws[(k + 3) * HID + col], acc);
    }
    out[(size_t)row * HID + col] = acc * dinv[row];
}

// out[row,0:128] = Q[row,0:32] @ W + b ; out[row,128:256] = Q[row,32:64] @ W + b
__global__ __launch_bounds__(256) void k_gemm_out2(const float* __restrict__ Q,
                                                   const float* __restrict__ W,
                                                   const float* __restrict__ b,
                                                   float* __restrict__ out, int N) {
    __shared__ float Ws[HID * FOUT];
    for (int i = threadIdx.x; i < HID * FOUT; i += 256) Ws[i] = W[i];
    __syncthreads();
    int row = blockIdx.x * 2 + (threadIdx.x >> 7);
    int col = threadIdx.x & 127;
    if (row >= N) return;
    const float4* q4 = reinterpret_cast<const float4*>(Q + (size_t)row * 64);
    float acc1 = 0.f, acc2 = 0.f;
#pragma unroll
    for (int k4 = 0; k4 < HID / 4; ++k4) {
        float4 v1 = q4[k4];
        float4 v2 = q4[k4 + 8];
        int k = k4 * 4;
        acc1 = fmaf(v1.x, Ws[(k + 0) * FOUT + col], acc1);
        acc1 = fmaf(v1.y, Ws[(k + 1) * FOUT + col], acc1);
        acc1 = fmaf(v1.z, Ws[(k + 2) * FOUT + col], acc1);
        acc1 = fmaf(v1.w, Ws[(k + 3) * FOUT + col], acc1);
        acc2 = fmaf(v2.x, Ws[(k + 0) * FOUT + col], acc2);
        acc2 = fmaf(v2.y, Ws[(k + 1) * FOUT + col], acc2);
        acc2 = fmaf(v2.z, Ws[(k + 2) * FOUT + col], acc2);
        acc2 = fmaf(v2.w, Ws[(k + 3) * FOUT + col], acc2);
    }
    float bb = b[col];
    out[(size_t)row * OSTR + col] = acc1 + bb;
    out[(size_t)row * OSTR + FOUT + col] = acc2 + bb;
}

// ---------------- layer-1 scale: two views from one h ----------------
__global__ __launch_bounds__(256) void k_scale2(const float* __restrict__ h,
                                                const float* __restrict__ d1,
                                                const float* __restrict__ d2,
                                                float* __restrict__ o1,
                                                float* __restrict__ o2, int N) {
    int idx = blockIdx.x * 256 + threadIdx.x;
    int i = idx >> 5;
    if (i >= N) return;
    float v = h[idx];
    o1[idx] = v * d1[i];
    o2[idx] = v * d2[i];
}

// ---------------- pull aggregation (float4 gather) ----------------
template <int F, int S, bool BIAS>
__device__ __forceinline__ void pull_body(const float* __restrict__ hs,
                                          const int* __restrict__ csr,
                                          const int* __restrict__ rowptr,
                                          const unsigned* __restrict__ deg,
                                          const float* __restrict__ dinv,
                                          const float* __restrict__ b,
                                          float* __restrict__ out, int N,
                                          int blk, int tid) {
    constexpr int L = F / 4;
    int node = blk * (256 / L) + tid / L;
    int q = tid % L;
    if (node >= N) return;
    const float4* h4 = reinterpret_cast<const float4*>(hs);
    int beg = rowptr[node];
    int end = beg + (int)deg[node];
    float4 acc = h4[(size_t)node * L + q];
    int e = beg;
    for (; e + 2 <= end; e += 2) {
        int s0 = csr[e];
        int s1 = csr[e + 1];
        float4 v0 = h4[(size_t)s0 * L + q];
        float4 v1 = h4[(size_t)s1 * L + q];
        acc.x += v0.x + v1.x;
        acc.y += v0.y + v1.y;
        acc.z += v0.z + v1.z;
        acc.w += v0.w + v1.w;
    }
    if (e < end) {
        float4 v = h4[(size_t)csr[e] * L + q];
        acc.x += v.x; acc.y += v.y; acc.z += v.z; acc.w += v.w;
    }
    float di = dinv[node];
    float4 r;
    r.x = acc.x * di; r.y = acc.y * di; r.z = acc.z * di; r.w = acc.w * di;
    if (BIAS) {
        r.x += b[q * 4 + 0]; r.y += b[q * 4 + 1];
        r.z += b[q * 4 + 2]; r.w += b[q * 4 + 3];
    }
    *reinterpret_cast<float4*>(out + (size_t)node * S + q * 4) = r;
}

template <int F, int S, bool BIAS>
__global__ __launch_bounds__(256) void k_pullv(const float* __restrict__ hs,
                                               const int* __restrict__ csr,
                                               const int* __restrict__ rowptr,
                                               const unsigned* __restrict__ deg,
                                               const float* __restrict__ dinv,
                                               const float* __restrict__ b,
                                               float* __restrict__ out, int N) {
    pull_body<F, S, BIAS>(hs, csr, rowptr, deg, dinv, b, out, N, blockIdx.x, threadIdx.x);
}

// both views in one launch
template <int F, int S, bool BIAS>
__global__ __launch_bounds__(256) void k_pullv2(
    const float* __restrict__ hsA, const int* __restrict__ csrA, const int* __restrict__ rpA,
    const unsigned* __restrict__ degA, const float* __restrict__ dinvA, float* __restrict__ outA,
    const float* __restrict__ hsB, const int* __restrict__ csrB, const int* __restrict__ rpB,
    const unsigned* __restrict__ degB, const float* __restrict__ dinvB, float* __restrict__ outB,
    const float* __restrict__ b, int N, int half) {
    bool sec = blockIdx.x >= half;
    int blk = sec ? blockIdx.x - half : blockIdx.x;
    if (sec) pull_body<F, S, BIAS>(hsB, csrB, rpB, degB, dinvB, b, outB, N, blk, threadIdx.x);
    else     pull_body<F, S, BIAS>(hsA, csrA, rpA, degA, dinvA, b, outA, N, blk, threadIdx.x);
}

// ---------------- cross-view mixing ----------------
__global__ __launch_bounds__(256) void k_mix(float* __restrict__ x1,
                                             float* __restrict__ x2, int N) {
    int i = blockIdx.x * 256 + threadIdx.x;
    if (i >= N) return;
    float4* a4 = reinterpret_cast<float4*>(x1 + (size_t)i * HID);
    float4* b4 = reinterpret_cast<float4*>(x2 + (size_t)i * HID);
    float4 a[HID / 4], b[HID / 4];
    float n1 = 0.f, n2 = 0.f, dt = 0.f;
#pragma unroll
    for (int j = 0; j < HID / 4; ++j) {
        a[j] = a4[j];
        b[j] = b4[j];
        n1 += a[j].x * a[j].x + a[j].y * a[j].y + a[j].z * a[j].z + a[j].w * a[j].w;
        n2 += b[j].x * b[j].x + b[j].y * b[j].y + b[j].z * b[j].z + b[j].w * b[j].w;
        dt += a[j].x * b[j].x + a[j].y * b[j].y + a[j].z * b[j].z + a[j].w * b[j].w;
    }
    float sim = dt / (fmaxf(sqrtf(n1), EPS) * fmaxf(sqrtf(n2), EPS));
#pragma unroll
    for (int j = 0; j < HID / 4; ++j) {
        float4 m, s;
        m.x = fmaf(b[j].x, sim, a[j].x);
        m.y = fmaf(b[j].y, sim, a[j].y);
        m.z = fmaf(b[j].z, sim, a[j].z);
        m.w = fmaf(b[j].w, sim, a[j].w);
        s.x = fmaf(a[j].x, sim, b[j].x);
        s.y = fmaf(a[j].y, sim, b[j].y);
        s.z = fmaf(a[j].z, sim, b[j].z);
        s.w = fmaf(a[j].w, sim, b[j].w);
        a4[j] = m;
        b4[j] = s;
    }
}

// mix + pack for layer 3: P[i] = [(x1+x2*sim)*dinv_u[i] | (x2+x1*sim)*dinv_u[i]]
__global__ __launch_bounds__(256) void k_mix_pack(const float* __restrict__ x1,
                                                  const float* __restrict__ x2,
                                                  const float* __restrict__ dinv,
                                                  float* __restrict__ P, int N) {
    int i = blockIdx.x * 256 + threadIdx.x;
    if (i >= N) return;
    const float4* a4 = reinterpret_cast<const float4*>(x1 + (size_t)i * HID);
    const float4* b4 = reinterpret_cast<const float4*>(x2 + (size_t)i * HID);
    float4* p4 = reinterpret_cast<float4*>(P + (size_t)i * 64);
    float4 a[HID / 4], b[HID / 4];
    float n1 = 0.f, n2 = 0.f, dt = 0.f;
#pragma unroll
    for (int j = 0; j < HID / 4; ++j) {
        a[j] = a4[j];
        b[j] = b4[j];
        n1 += a[j].x * a[j].x + a[j].y * a[j].y + a[j].z * a[j].z + a[j].w * a[j].w;
        n2 += b[j].x * b[j].x + b[j].y * b[j].y + b[j].z * b[j].z + b[j].w * b[j].w;
        dt += a[j].x * b[j].x + a[j].y * b[j].y + a[j].z * b[j].z + a[j].w * b[j].w;
    }
    float sim = dt / (fmaxf(sqrtf(n1), EPS) * fmaxf(sqrtf(n2), EPS));
    float di = dinv[i];
#pragma unroll
    for (int j = 0; j < HID / 4; ++j) {
        float4 m, s;
        m.x = fmaf(b[j].x, sim, a[j].x) * di;
        m.y = fmaf(b[j].y, sim, a[j].y) * di;
        m.z = fmaf(b[j].z, sim, a[j].z) * di;
        m.w = fmaf(b[j].w, sim, a[j].w) * di;
        s.x = fmaf(a[j].x, sim, b[j].x) * di;
        s.y = fmaf(a[j].y, sim, b[j].y) * di;
        s.z = fmaf(a[j].z, sim, b[j].z) * di;
        s.w = fmaf(a[j].w, sim, b[j].w) * di;
        p4[j] = m;
        p4[j + 8] = s;
    }
}

// ---------------- host ----------------
extern "C" void kernel_launch(void* const* d_in, const int* in_sizes, int n_in,
                              void* d_out, int out_size, void* d_ws, size_t ws_size,
                              hipStream_t stream) {
    const float* x     = (const float*)d_in[0];
    const int*   ei_u  = (const int*)d_in[1];
    const int*   ei_u2 = (const int*)d_in[2];
    const float* W_in  = (const float*)d_in[3];
    const float* b_in  = (const float*)d_in[4];
    const float* W_hid = (const float*)d_in[5];
    const float* b_hid = (const float*)d_in[6];
    const float* W_out = (const float*)d_in[7];
    const float* b_out = (const float*)d_in[8];
    float* out = (float*)d_out;

    const int* src_u  = ei_u;
    const int* dst_u  = ei_u + NE;
    const int* src_u2 = ei_u2;
    const int* dst_u2 = ei_u2 + NE;

    char* w = (char*)d_ws;
    auto carve = [&](size_t bytes) {
        char* p = w;
        w += (bytes + 255) & ~(size_t)255;
        return p;
    };
    unsigned* deg_u   = (unsigned*)carve(NN * sizeof(unsigned));
    unsigned* deg_u2  = (unsigned*)carve(NN * sizeof(unsigned));
    float*    dinv_u  = (float*)carve(NN * sizeof(float));
    float*    dinv_u2 = (float*)carve(NN * sizeof(float));
    int*      rp_u    = (int*)carve(NN * sizeof(int));
    int*      rp_u2   = (int*)carve(NN * sizeof(int));
    unsigned* cur_u   = (unsigned*)carve(NB * sizeof(unsigned));
    unsigned* cur_u2  = (unsigned*)carve(NB * sizeof(unsigned));
    unsigned* bsumA   = (unsigned*)carve(256 * sizeof(unsigned));
    unsigned* bsumB   = (unsigned*)carve(256 * sizeof(unsigned));
    int*      csr_u   = (int*)carve((size_t)NE * sizeof(int));
    int*      csr_u2  = (int*)carve((size_t)NE * sizeof(int));
    float* A = (float*)carve((size_t)NN * HID * sizeof(float));
    float* B = (float*)carve((size_t)NN * HID * sizeof(float));
    float* C = (float*)carve((size_t)NN * HID * sizeof(float));
    float* D = (float*)carve((size_t)NN * HID * sizeof(float));
    float* Ebuf = (float*)carve((size_t)NN * HID * sizeof(float));
    float* P = (float*)carve((size_t)NN * 64 * sizeof(float));
    float* Q = (float*)carve((size_t)NN * 64 * sizeof(float));
    // tmp coarse-bin buffers alias P/Q (each NE ints = 6.4 MB <= 12.8 MB; P/Q used only later)
    int* tmp_u  = (int*)P;
    int* tmp_u2 = (int*)Q;

    const int BLK = 256;
    const int gE  = (NE + BLK - 1) / BLK;    // 6250
    const int gN  = (NN + BLK - 1) / BLK;    // 196
    const int gN32 = (NN * HID) / BLK;       // 6250 exact
    const int gP32 = (NN + 31) / 32;         // 1563
    const int gP64 = (NN + 15) / 16;         // 3125
    const int gG   = (NN + 7) / 8;           // 6250
    const int gG2  = (NN + 1) / 2;           // 25000

    // --- degrees, dinv, rowptr (both views per launch) ---
    hipMemsetAsync(deg_u, 0, 2 * ((NN * sizeof(unsigned) + 255) & ~(size_t)255), stream);
    k_deg2<<<2 * gE, BLK, 0, stream>>>(dst_u, dst_u2, deg_u, deg_u2, gE);
    k_dinv2<<<gN, BLK, 0, stream>>>(deg_u, deg_u2, dinv_u, dinv_u2, NN);
    k_scan1_2<<<2 * gN, BLK, 0, stream>>>(deg_u, deg_u2, rp_u, rp_u2, bsumA, bsumB, NN, gN);
    k_scan2_2<<<2, BLK, 0, stream>>>(bsumA, bsumB, gN);
    k_scan3_2<<<2 * gN, BLK, 0, stream>>>(rp_u, rp_u2, bsumA, bsumB, NN, gN);

    // --- 2-pass CSR build (both views per launch) ---
    k_curinit<<<(NB + BLK - 1) / BLK, BLK, 0, stream>>>(rp_u, rp_u2, cur_u, cur_u2);
    k_bin1<<<2 * gE, BLK, 0, stream>>>(src_u, dst_u, cur_u, tmp_u,
                                       src_u2, dst_u2, cur_u2, tmp_u2, gE);
    k_bin2<<<2 * NB, BLK, 0, stream>>>(tmp_u, rp_u, csr_u, tmp_u2, rp_u2, csr_u2, NB);

    // --- layer 1 ---
    k_gemm_in<<<gG, BLK, 0, stream>>>(x, W_in, A, NN);
    k_scale2<<<gN32, BLK, 0, stream>>>(A, dinv_u, dinv_u2, B, D, NN);
    k_pullv2<HID, HID, true><<<2 * gP32, BLK, 0, stream>>>(
        B, csr_u, rp_u, deg_u, dinv_u, C,
        D, csr_u2, rp_u2, deg_u2, dinv_u2, Ebuf, b_in, NN, gP32);
    k_mix<<<gN, BLK, 0, stream>>>(C, Ebuf, NN);

    // --- layer 2 ---
    k_gemm_hid2<<<2 * gG, BLK, 0, stream>>>(C, dinv_u, A, Ebuf, dinv_u2, B, W_hid, NN, gG);
    k_pullv2<HID, HID, true><<<2 * gP32, BLK, 0, stream>>>(
        A, csr_u, rp_u, deg_u, dinv_u, C,
        B, csr_u2, rp_u2, deg_u2, dinv_u2, Ebuf, b_hid, NN, gP32);
    // mix + pack both branches scaled by dinv_u (layer 3 uses view u for BOTH)
    k_mix_pack<<<gN, BLK, 0, stream>>>(C, Ebuf, dinv_u, P, NN);

    // --- layer 3: one packed F=64 pull, then one fused GEMM ---
    k_pullv<64, 64, false><<<gP64, BLK, 0, stream>>>(P, csr_u, rp_u, deg_u, dinv_u, nullptr, Q, NN);
    k_gemm_out2<<<gG2, BLK, 0, stream>>>(Q, W_out, b_out, out, NN);

    (void)in_sizes; (void)n_in; (void)out_size; (void)ws_size;
}

// Round 5
// 427.126 us; speedup vs baseline: 2.1639x; 2.1639x over previous
//
#include <hip/hip_runtime.h>
#include <hip/hip_bf16.h>

#define NN 50000
#define NE 1600000
#define NIN 256
#define HID 32
#define FOUT 128
#define OSTR 256
#define NB ((NN + 31) / 32)        // 1563 coarse buckets (32 nodes each)
#define CHUNK 16384                 // edges per bin1/hist block

static constexpr float EPS = 1e-12f;

// ---------------- pass 0: coarse bucket histogram (LDS-privatized) ----------------
__global__ __launch_bounds__(256) void k_hist(const int* __restrict__ dstA,
                                              const int* __restrict__ dstB,
                                              unsigned* __restrict__ bcntA,
                                              unsigned* __restrict__ bcntB, int half) {
    __shared__ unsigned h[NB];
    for (int i = threadIdx.x; i < NB; i += 256) h[i] = 0u;
    __syncthreads();
    bool sec = blockIdx.x >= half;
    int blk = sec ? blockIdx.x - half : blockIdx.x;
    const int* dst = sec ? dstB : dstA;
    unsigned* bcnt = sec ? bcntB : bcntA;
    int beg = blk * CHUNK;
    int end = min(beg + CHUNK, NE);
    for (int e = beg + (int)threadIdx.x; e < end; e += 256)
        atomicAdd(&h[dst[e] >> 5], 1u);
    __syncthreads();
    for (int i = threadIdx.x; i < NB; i += 256)
        if (h[i]) atomicAdd(&bcnt[i], h[i]);
}

// ---------------- bucket scan: bases + cursors (1 block per view) ----------------
__global__ __launch_bounds__(256) void k_bscan(const unsigned* __restrict__ bcntA,
                                               const unsigned* __restrict__ bcntB,
                                               int* __restrict__ bbA, int* __restrict__ bbB,
                                               unsigned* __restrict__ curA,
                                               unsigned* __restrict__ curB) {
    __shared__ unsigned tile[256];
    __shared__ unsigned carry;
    const unsigned* bcnt = blockIdx.x ? bcntB : bcntA;
    int* bb = blockIdx.x ? bbB : bbA;
    unsigned* cur = blockIdx.x ? curB : curA;
    if (threadIdx.x == 0) carry = 0u;
    __syncthreads();
    for (int base = 0; base < NB; base += 256) {
        int i = base + (int)threadIdx.x;
        unsigned v = (i < NB) ? bcnt[i] : 0u;
        tile[threadIdx.x] = v;
        __syncthreads();
        for (int off = 1; off < 256; off <<= 1) {
            unsigned t = (threadIdx.x >= (unsigned)off) ? tile[threadIdx.x - off] : 0u;
            __syncthreads();
            tile[threadIdx.x] += t;
            __syncthreads();
        }
        if (i < NB) {
            unsigned excl = carry + tile[threadIdx.x] - v;
            bb[i] = (int)excl;
            cur[i] = excl;
        }
        __syncthreads();
        if (threadIdx.x == 0) carry += tile[255];
        __syncthreads();
    }
    if (threadIdx.x == 0) bb[NB] = NE;
}

// ---------------- pass 1: coarse scatter with LDS hist + bulk reservation ----------------
// payload = (dst&31)<<16 | src (both < 2^16)
__global__ __launch_bounds__(256) void k_bin1(const int* __restrict__ srcA,
                                              const int* __restrict__ dstA,
                                              unsigned* __restrict__ curA,
                                              int* __restrict__ tmpA,
                                              const int* __restrict__ srcB,
                                              const int* __restrict__ dstB,
                                              unsigned* __restrict__ curB,
                                              int* __restrict__ tmpB, int half) {
    __shared__ unsigned hcnt[NB];
    __shared__ unsigned hbase[NB];
    bool sec = blockIdx.x >= half;
    int blk = sec ? blockIdx.x - half : blockIdx.x;
    const int* src = sec ? srcB : srcA;
    const int* dst = sec ? dstB : dstA;
    unsigned* cur = sec ? curB : curA;
    int* tmp = sec ? tmpB : tmpA;
    for (int i = threadIdx.x; i < NB; i += 256) hcnt[i] = 0u;
    __syncthreads();
    int beg = blk * CHUNK;
    int end = min(beg + CHUNK, NE);
    for (int e = beg + (int)threadIdx.x; e < end; e += 256)
        atomicAdd(&hcnt[dst[e] >> 5], 1u);
    __syncthreads();
    for (int i = threadIdx.x; i < NB; i += 256) {
        unsigned c = hcnt[i];
        hbase[i] = c ? atomicAdd(&cur[i], c) : 0u;
        hcnt[i] = 0u;  // reuse as running offset
    }
    __syncthreads();
    for (int e = beg + (int)threadIdx.x; e < end; e += 256) {
        int d = dst[e];
        int bkt = d >> 5;
        unsigned pos = hbase[bkt] + atomicAdd(&hcnt[bkt], 1u);
        tmp[pos] = ((d & 31) << 16) | src[e];
    }
}

// ---------------- pass 2: per-bucket fine scatter + deg/rowptr/dinv ----------------
__global__ __launch_bounds__(256) void k_bin2(const int* __restrict__ tmpA,
                                              const int* __restrict__ bbA,
                                              int* __restrict__ csrA,
                                              unsigned* __restrict__ degA,
                                              float* __restrict__ dinvA,
                                              int* __restrict__ rpA,
                                              const int* __restrict__ tmpB,
                                              const int* __restrict__ bbB,
                                              int* __restrict__ csrB,
                                              unsigned* __restrict__ degB,
                                              float* __restrict__ dinvB,
                                              int* __restrict__ rpB, int half) {
    __shared__ unsigned cnt[32];
    __shared__ unsigned curs[32];
    bool sec = blockIdx.x >= half;
    int b = sec ? blockIdx.x - half : blockIdx.x;
    const int* tmp = sec ? tmpB : tmpA;
    const int* bb = sec ? bbB : bbA;
    int* csr = sec ? csrB : csrA;
    unsigned* deg = sec ? degB : degA;
    float* dinv = sec ? dinvB : dinvA;
    int* rp = sec ? rpB : rpA;
    int beg = bb[b], end = bb[b + 1];
    if (threadIdx.x < 32) cnt[threadIdx.x] = 0u;
    __syncthreads();
    for (int e = beg + (int)threadIdx.x; e < end; e += 256)
        atomicAdd(&cnt[((unsigned)tmp[e]) >> 16], 1u);
    __syncthreads();
    if (threadIdx.x < 32) {
        unsigned c = cnt[threadIdx.x];
        unsigned lp = 0u;
        for (int j = 0; j < (int)threadIdx.x; ++j) lp += cnt[j];
        int n = b * 32 + (int)threadIdx.x;
        if (n < NN) {
            deg[n] = c;
            rp[n] = beg + (int)lp;
            dinv[n] = rsqrtf((float)(c + 1u));
        }
        curs[threadIdx.x] = (unsigned)beg + lp;
    }
    __syncthreads();
    for (int e = beg + (int)threadIdx.x; e < end; e += 256) {
        int p = tmp[e];
        unsigned pos = atomicAdd(&curs[((unsigned)p) >> 16], 1u);
        csr[pos] = p & 0xFFFF;
    }
}

// ---------------- GEMMs (W staged in LDS) ----------------
// h = x @ W_in, epilogue writes both scaled views: o1 = h*d1[row], o2 = h*d2[row]
__global__ __launch_bounds__(256) void k_gemm_in2(const float* __restrict__ x,
                                                  const float* __restrict__ W,
                                                  const float* __restrict__ d1,
                                                  const float* __restrict__ d2,
                                                  float* __restrict__ o1,
                                                  float* __restrict__ o2, int N) {
    __shared__ float Ws[NIN * HID];
    for (int i = threadIdx.x; i < NIN * HID; i += 256) Ws[i] = W[i];
    __syncthreads();
    int row = blockIdx.x * 8 + (threadIdx.x >> 5);
    int col = threadIdx.x & 31;
    if (row >= N) return;
    const float4* xr = reinterpret_cast<const float4*>(x + (size_t)row * NIN);
    float acc = 0.f;
#pragma unroll
    for (int k4 = 0; k4 < NIN / 4; ++k4) {
        float4 v = xr[k4];
        int k = k4 * 4;
        acc = fmaf(v.x, Ws[(k + 0) * HID + col], acc);
        acc = fmaf(v.y, Ws[(k + 1) * HID + col], acc);
        acc = fmaf(v.z, Ws[(k + 2) * HID + col], acc);
        acc = fmaf(v.w, Ws[(k + 3) * HID + col], acc);
    }
    o1[(size_t)row * HID + col] = acc * d1[row];
    o2[(size_t)row * HID + col] = acc * d2[row];
}

// both views: out = (in @ W) * dinv[row], one launch
__global__ __launch_bounds__(256) void k_gemm_hid2(const float* __restrict__ inA,
                                                   const float* __restrict__ dinvA,
                                                   float* __restrict__ outA,
                                                   const float* __restrict__ inB,
                                                   const float* __restrict__ dinvB,
                                                   float* __restrict__ outB,
                                                   const float* __restrict__ W,
                                                   int N, int half) {
    __shared__ float Ws[HID * HID];
    for (int i = threadIdx.x; i < HID * HID; i += 256) Ws[i] = W[i];
    __syncthreads();
    bool sec = blockIdx.x >= half;
    int blk = sec ? blockIdx.x - half : blockIdx.x;
    const float* in = sec ? inB : inA;
    const float* dinv = sec ? dinvB : dinvA;
    float* out = sec ? outB : outA;
    int row = blk * 8 + (threadIdx.x >> 5);
    int col = threadIdx.x & 31;
    if (row >= N) return;
    const float4* xr = reinterpret_cast<const float4*>(in + (size_t)row * HID);
    float acc = 0.f;
#pragma unroll
    for (int k4 = 0; k4 < HID / 4; ++k4) {
        float4 v = xr[k4];
        int k = k4 * 4;
        acc = fmaf(v.x, Ws[(k + 0) * HID + col], acc);
        acc = fmaf(v.y, Ws[(k + 1) * HID + col], acc);
        acc = fmaf(v.z, Ws[(k + 2) * HID + col], acc);
        acc = fmaf(v.w, Ws[(k + 3) * HID + col], acc);
    }
    out[(size_t)row * HID + col] = acc * dinv[row];
}

// out[row,0:128] = Q[row,0:32] @ W + b ; out[row,128:256] = Q[row,32:64] @ W + b
__global__ __launch_bounds__(256) void k_gemm_out2(const float* __restrict__ Q,
                                                   const float* __restrict__ W,
                                                   const float* __restrict__ b,
                                                   float* __restrict__ out, int N) {
    __shared__ float Ws[HID * FOUT];
    for (int i = threadIdx.x; i < HID * FOUT; i += 256) Ws[i] = W[i];
    __syncthreads();
    int row = blockIdx.x * 2 + (threadIdx.x >> 7);
    int col = threadIdx.x & 127;
    if (row >= N) return;
    const float4* q4 = reinterpret_cast<const float4*>(Q + (size_t)row * 64);
    float acc1 = 0.f, acc2 = 0.f;
#pragma unroll
    for (int k4 = 0; k4 < HID / 4; ++k4) {
        float4 v1 = q4[k4];
        float4 v2 = q4[k4 + 8];
        int k = k4 * 4;
        acc1 = fmaf(v1.x, Ws[(k + 0) * FOUT + col], acc1);
        acc1 = fmaf(v1.y, Ws[(k + 1) * FOUT + col], acc1);
        acc1 = fmaf(v1.z, Ws[(k + 2) * FOUT + col], acc1);
        acc1 = fmaf(v1.w, Ws[(k + 3) * FOUT + col], acc1);
        acc2 = fmaf(v2.x, Ws[(k + 0) * FOUT + col], acc2);
        acc2 = fmaf(v2.y, Ws[(k + 1) * FOUT + col], acc2);
        acc2 = fmaf(v2.z, Ws[(k + 2) * FOUT + col], acc2);
        acc2 = fmaf(v2.w, Ws[(k + 3) * FOUT + col], acc2);
    }
    float bb = b[col];
    out[(size_t)row * OSTR + col] = acc1 + bb;
    out[(size_t)row * OSTR + FOUT + col] = acc2 + bb;
}

// ---------------- pull aggregation (float4 gather) ----------------
template <int F, int S, bool BIAS>
__device__ __forceinline__ void pull_body(const float* __restrict__ hs,
                                          const int* __restrict__ csr,
                                          const int* __restrict__ rowptr,
                                          const unsigned* __restrict__ deg,
                                          const float* __restrict__ dinv,
                                          const float* __restrict__ b,
                                          float* __restrict__ out, int N,
                                          int blk, int tid) {
    constexpr int L = F / 4;
    int node = blk * (256 / L) + tid / L;
    int q = tid % L;
    if (node >= N) return;
    const float4* h4 = reinterpret_cast<const float4*>(hs);
    int beg = rowptr[node];
    int end = beg + (int)deg[node];
    float4 acc = h4[(size_t)node * L + q];
    int e = beg;
    for (; e + 2 <= end; e += 2) {
        int s0 = csr[e];
        int s1 = csr[e + 1];
        float4 v0 = h4[(size_t)s0 * L + q];
        float4 v1 = h4[(size_t)s1 * L + q];
        acc.x += v0.x + v1.x;
        acc.y += v0.y + v1.y;
        acc.z += v0.z + v1.z;
        acc.w += v0.w + v1.w;
    }
    if (e < end) {
        float4 v = h4[(size_t)csr[e] * L + q];
        acc.x += v.x; acc.y += v.y; acc.z += v.z; acc.w += v.w;
    }
    float di = dinv[node];
    float4 r;
    r.x = acc.x * di; r.y = acc.y * di; r.z = acc.z * di; r.w = acc.w * di;
    if (BIAS) {
        r.x += b[q * 4 + 0]; r.y += b[q * 4 + 1];
        r.z += b[q * 4 + 2]; r.w += b[q * 4 + 3];
    }
    *reinterpret_cast<float4*>(out + (size_t)node * S + q * 4) = r;
}

template <int F, int S, bool BIAS>
__global__ __launch_bounds__(256) void k_pullv(const float* __restrict__ hs,
                                               const int* __restrict__ csr,
                                               const int* __restrict__ rowptr,
                                               const unsigned* __restrict__ deg,
                                               const float* __restrict__ dinv,
                                               const float* __restrict__ b,
                                               float* __restrict__ out, int N) {
    pull_body<F, S, BIAS>(hs, csr, rowptr, deg, dinv, b, out, N, blockIdx.x, threadIdx.x);
}

template <int F, int S, bool BIAS>
__global__ __launch_bounds__(256) void k_pullv2(
    const float* __restrict__ hsA, const int* __restrict__ csrA, const int* __restrict__ rpA,
    const unsigned* __restrict__ degA, const float* __restrict__ dinvA, float* __restrict__ outA,
    const float* __restrict__ hsB, const int* __restrict__ csrB, const int* __restrict__ rpB,
    const unsigned* __restrict__ degB, const float* __restrict__ dinvB, float* __restrict__ outB,
    const float* __restrict__ b, int N, int half) {
    bool sec = blockIdx.x >= half;
    int blk = sec ? blockIdx.x - half : blockIdx.x;
    if (sec) pull_body<F, S, BIAS>(hsB, csrB, rpB, degB, dinvB, b, outB, N, blk, threadIdx.x);
    else     pull_body<F, S, BIAS>(hsA, csrA, rpA, degA, dinvA, b, outA, N, blk, threadIdx.x);
}

// ---------------- cross-view mixing ----------------
__global__ __launch_bounds__(256) void k_mix(float* __restrict__ x1,
                                             float* __restrict__ x2, int N) {
    int i = blockIdx.x * 256 + threadIdx.x;
    if (i >= N) return;
    float4* a4 = reinterpret_cast<float4*>(x1 + (size_t)i * HID);
    float4* b4 = reinterpret_cast<float4*>(x2 + (size_t)i * HID);
    float4 a[HID / 4], b[HID / 4];
    float n1 = 0.f, n2 = 0.f, dt = 0.f;
#pragma unroll
    for (int j = 0; j < HID / 4; ++j) {
        a[j] = a4[j];
        b[j] = b4[j];
        n1 += a[j].x * a[j].x + a[j].y * a[j].y + a[j].z * a[j].z + a[j].w * a[j].w;
        n2 += b[j].x * b[j].x + b[j].y * b[j].y + b[j].z * b[j].z + b[j].w * b[j].w;
        dt += a[j].x * b[j].x + a[j].y * b[j].y + a[j].z * b[j].z + a[j].w * b[j].w;
    }
    float sim = dt / (fmaxf(sqrtf(n1), EPS) * fmaxf(sqrtf(n2), EPS));
#pragma unroll
    for (int j = 0; j < HID / 4; ++j) {
        float4 m, s;
        m.x = fmaf(b[j].x, sim, a[j].x);
        m.y = fmaf(b[j].y, sim, a[j].y);
        m.z = fmaf(b[j].z, sim, a[j].z);
        m.w = fmaf(b[j].w, sim, a[j].w);
        s.x = fmaf(a[j].x, sim, b[j].x);
        s.y = fmaf(a[j].y, sim, b[j].y);
        s.z = fmaf(a[j].z, sim, b[j].z);
        s.w = fmaf(a[j].w, sim, b[j].w);
        a4[j] = m;
        b4[j] = s;
    }
}

// mix + pack for layer 3: P[i] = [(x1+x2*sim)*dinv_u[i] | (x2+x1*sim)*dinv_u[i]]
__global__ __launch_bounds__(256) void k_mix_pack(const float* __restrict__ x1,
                                                  const float* __restrict__ x2,
                                                  const float* __restrict__ dinv,
                                                  float* __restrict__ P, int N) {
    int i = blockIdx.x * 256 + threadIdx.x;
    if (i >= N) return;
    const float4* a4 = reinterpret_cast<const float4*>(x1 + (size_t)i * HID);
    const float4* b4 = reinterpret_cast<const float4*>(x2 + (size_t)i * HID);
    float4* p4 = reinterpret_cast<float4*>(P + (size_t)i * 64);
    float4 a[HID / 4], b[HID / 4];
    float n1 = 0.f, n2 = 0.f, dt = 0.f;
#pragma unroll
    for (int j = 0; j < HID / 4; ++j) {
        a[j] = a4[j];
        b[j] = b4[j];
        n1 += a[j].x * a[j].x + a[j].y * a[j].y + a[j].z * a[j].z + a[j].w * a[j].w;
        n2 += b[j].x * b[j].x + b[j].y * b[j].y + b[j].z * b[j].z + b[j].w * b[j].w;
        dt += a[j].x * b[j].x + a[j].y * b[j].y + a[j].z * b[j].z + a[j].w * b[j].w;
    }
    float sim = dt / (fmaxf(sqrtf(n1), EPS) * fmaxf(sqrtf(n2), EPS));
    float di = dinv[i];
#pragma unroll
    for (int j = 0; j < HID / 4; ++j) {
        float4 m, s;
        m.x = fmaf(b[j].x, sim, a[j].x) * di;
        m.y = fmaf(b[j].y, sim, a[j].y) * di;
        m.z = fmaf(b[j].z, sim, a[j].z) * di;
        m.w = fmaf(b[j].w, sim, a[j].w) * di;
        s.x = fmaf(a[j].x, sim, b[j].x) * di;
        s.y = fmaf(a[j].y, sim, b[j].y) * di;
        s.z = fmaf(a[j].z, sim, b[j].z) * di;
        s.w = fmaf(a[j].w, sim, b[j].w) * di;
        p4[j] = m;
        p4[j + 8] = s;
    }
}

// ---------------- host ----------------
extern "C" void kernel_launch(void* const* d_in, const int* in_sizes, int n_in,
                              void* d_out, int out_size, void* d_ws, size_t ws_size,
                              hipStream_t stream) {
    const float* x     = (const float*)d_in[0];
    const int*   ei_u  = (const int*)d_in[1];
    const int*   ei_u2 = (const int*)d_in[2];
    const float* W_in  = (const float*)d_in[3];
    const float* b_in  = (const float*)d_in[4];
    const float* W_hid = (const float*)d_in[5];
    const float* b_hid = (const float*)d_in[6];
    const float* W_out = (const float*)d_in[7];
    const float* b_out = (const float*)d_in[8];
    float* out = (float*)d_out;

    const int* src_u  = ei_u;
    const int* dst_u  = ei_u + NE;
    const int* src_u2 = ei_u2;
    const int* dst_u2 = ei_u2 + NE;

    char* w = (char*)d_ws;
    auto carve = [&](size_t bytes) {
        char* p = w;
        w += (bytes + 255) & ~(size_t)255;
        return p;
    };
    unsigned* bcnt_u  = (unsigned*)carve(NB * sizeof(unsigned));
    unsigned* bcnt_u2 = (unsigned*)carve(NB * sizeof(unsigned));
    int*      bb_u    = (int*)carve((NB + 1) * sizeof(int));
    int*      bb_u2   = (int*)carve((NB + 1) * sizeof(int));
    unsigned* cur_u   = (unsigned*)carve(NB * sizeof(unsigned));
    unsigned* cur_u2  = (unsigned*)carve(NB * sizeof(unsigned));
    unsigned* deg_u   = (unsigned*)carve(NN * sizeof(unsigned));
    unsigned* deg_u2  = (unsigned*)carve(NN * sizeof(unsigned));
    float*    dinv_u  = (float*)carve(NN * sizeof(float));
    float*    dinv_u2 = (float*)carve(NN * sizeof(float));
    int*      rp_u    = (int*)carve(NN * sizeof(int));
    int*      rp_u2   = (int*)carve(NN * sizeof(int));
    int*      csr_u   = (int*)carve((size_t)NE * sizeof(int));
    int*      csr_u2  = (int*)carve((size_t)NE * sizeof(int));
    float* A = (float*)carve((size_t)NN * HID * sizeof(float));
    float* B = (float*)carve((size_t)NN * HID * sizeof(float));
    float* C = (float*)carve((size_t)NN * HID * sizeof(float));
    float* D = (float*)carve((size_t)NN * HID * sizeof(float));
    float* Ebuf = (float*)carve((size_t)NN * HID * sizeof(float));
    float* P = (float*)carve((size_t)NN * 64 * sizeof(float));
    float* Q = (float*)carve((size_t)NN * 64 * sizeof(float));
    // tmp coarse-bin buffers alias P/Q (NE ints = 6.4 MB each; P/Q used only after bin2)
    int* tmp_u  = (int*)P;
    int* tmp_u2 = (int*)Q;

    const int BLK = 256;
    const int gN  = (NN + BLK - 1) / BLK;        // 196
    const int nch = (NE + CHUNK - 1) / CHUNK;    // 98 chunks per view
    const int gP32 = (NN + 31) / 32;             // 1563
    const int gP64 = (NN + 15) / 16;             // 3125
    const int gG   = (NN + 7) / 8;               // 6250
    const int gG2  = (NN + 1) / 2;               // 25000

    // --- CSR build (both views per launch), also produces deg/dinv/rowptr ---
    hipMemsetAsync(bcnt_u, 0, 2 * ((NB * sizeof(unsigned) + 255) & ~(size_t)255), stream);
    k_hist<<<2 * nch, BLK, 0, stream>>>(dst_u, dst_u2, bcnt_u, bcnt_u2, nch);
    k_bscan<<<2, BLK, 0, stream>>>(bcnt_u, bcnt_u2, bb_u, bb_u2, cur_u, cur_u2);
    k_bin1<<<2 * nch, BLK, 0, stream>>>(src_u, dst_u, cur_u, tmp_u,
                                        src_u2, dst_u2, cur_u2, tmp_u2, nch);
    k_bin2<<<2 * NB, BLK, 0, stream>>>(tmp_u, bb_u, csr_u, deg_u, dinv_u, rp_u,
                                       tmp_u2, bb_u2, csr_u2, deg_u2, dinv_u2, rp_u2, NB);

    // --- layer 1 (GEMM fused with per-view dinv scaling) ---
    k_gemm_in2<<<gG, BLK, 0, stream>>>(x, W_in, dinv_u, dinv_u2, B, D, NN);
    k_pullv2<HID, HID, true><<<2 * gP32, BLK, 0, stream>>>(
        B, csr_u, rp_u, deg_u, dinv_u, C,
        D, csr_u2, rp_u2, deg_u2, dinv_u2, Ebuf, b_in, NN, gP32);
    k_mix<<<gN, BLK, 0, stream>>>(C, Ebuf, NN);

    // --- layer 2 ---
    k_gemm_hid2<<<2 * gG, BLK, 0, stream>>>(C, dinv_u, A, Ebuf, dinv_u2, B, W_hid, NN, gG);
    k_pullv2<HID, HID, true><<<2 * gP32, BLK, 0, stream>>>(
        A, csr_u, rp_u, deg_u, dinv_u, C,
        B, csr_u2, rp_u2, deg_u2, dinv_u2, Ebuf, b_hid, NN, gP32);
    k_mix_pack<<<gN, BLK, 0, stream>>>(C, Ebuf, dinv_u, P, NN);

    // --- layer 3: one packed F=64 pull, then one fused GEMM ---
    k_pullv<64, 64, false><<<gP64, BLK, 0, stream>>>(P, csr_u, rp_u, deg_u, dinv_u, nullptr, Q, NN);
    k_gemm_out2<<<gG2, BLK, 0, stream>>>(Q, W_out, b_out, out, NN);

    (void)in_sizes; (void)n_in; (void)out_size; (void)ws_size;
}

// Round 6
// 369.425 us; speedup vs baseline: 2.5018x; 1.1562x over previous
//
#include <hip/hip_runtime.h>
#include <hip/hip_bf16.h>

#define NN 50000
#define NE 1600000
#define NIN 256
#define HID 32
#define FOUT 128
#define OSTR 256
#define NSB ((NN + 255) / 256)      // 196 superbuckets of 256 nodes
#define CHUNK 2048
#define NCH ((NE + CHUNK - 1) / CHUNK)  // 782 chunks per view

static constexpr float EPS = 1e-12f;

// ---------- pass 0: per-chunk histogram, stored (no atomics) ----------
__global__ __launch_bounds__(256) void k_hist(const int* __restrict__ dstA,
                                              const int* __restrict__ dstB,
                                              unsigned* __restrict__ hcA,
                                              unsigned* __restrict__ hcB, int half) {
    __shared__ unsigned h[NSB];
    for (int i = threadIdx.x; i < NSB; i += 256) h[i] = 0u;
    __syncthreads();
    bool sec = blockIdx.x >= half;
    int c = sec ? blockIdx.x - half : blockIdx.x;
    const int* dst = sec ? dstB : dstA;
    unsigned* hc = sec ? hcB : hcA;
    int beg = c * CHUNK, end = min(beg + CHUNK, NE);
    for (int e = beg + (int)threadIdx.x; e < end; e += 256)
        atomicAdd(&h[dst[e] >> 8], 1u);
    __syncthreads();
    for (int i = threadIdx.x; i < NSB; i += 256) hc[(size_t)c * NSB + i] = h[i];
}

// ---------- per-bucket scan over chunks: hcount -> exclusive offsets; totals out ----------
__global__ __launch_bounds__(256) void k_cscan(unsigned* __restrict__ hcA,
                                               unsigned* __restrict__ hcB,
                                               unsigned* __restrict__ totA,
                                               unsigned* __restrict__ totB, int half) {
    __shared__ unsigned tile[256];
    __shared__ unsigned carry;
    bool sec = blockIdx.x >= half;
    int sb = sec ? blockIdx.x - half : blockIdx.x;
    unsigned* hc = sec ? hcB : hcA;
    unsigned* tot = sec ? totB : totA;
    if (threadIdx.x == 0) carry = 0u;
    __syncthreads();
    for (int base = 0; base < NCH; base += 256) {
        int c = base + (int)threadIdx.x;
        unsigned v = (c < NCH) ? hc[(size_t)c * NSB + sb] : 0u;
        tile[threadIdx.x] = v;
        __syncthreads();
        for (int off = 1; off < 256; off <<= 1) {
            unsigned t = (threadIdx.x >= (unsigned)off) ? tile[threadIdx.x - off] : 0u;
            __syncthreads();
            tile[threadIdx.x] += t;
            __syncthreads();
        }
        if (c < NCH) hc[(size_t)c * NSB + sb] = carry + tile[threadIdx.x] - v;
        __syncthreads();
        if (threadIdx.x == 0) carry += tile[255];
        __syncthreads();
    }
    if (threadIdx.x == 0) tot[sb] = carry;
}

// ---------- bucket bases: exclusive scan of totals ----------
__global__ __launch_bounds__(256) void k_bscan(const unsigned* __restrict__ totA,
                                               const unsigned* __restrict__ totB,
                                               int* __restrict__ bbA, int* __restrict__ bbB) {
    __shared__ unsigned tile[256];
    const unsigned* tot = blockIdx.x ? totB : totA;
    int* bb = blockIdx.x ? bbB : bbA;
    unsigned v = (threadIdx.x < NSB) ? tot[threadIdx.x] : 0u;
    tile[threadIdx.x] = v;
    __syncthreads();
    for (int off = 1; off < 256; off <<= 1) {
        unsigned t = (threadIdx.x >= (unsigned)off) ? tile[threadIdx.x - off] : 0u;
        __syncthreads();
        tile[threadIdx.x] += t;
        __syncthreads();
    }
    if (threadIdx.x < NSB) bb[threadIdx.x] = (int)(tile[threadIdx.x] - v);
    if (threadIdx.x == 0) bb[NSB] = NE;
}

// ---------- pass 1: coarse scatter, deterministic bases, no global atomics ----------
__global__ __launch_bounds__(256) void k_bin1(const int* __restrict__ srcA,
                                              const int* __restrict__ dstA,
                                              const unsigned* __restrict__ hcA,
                                              const int* __restrict__ bbA,
                                              int* __restrict__ tmpA,
                                              const int* __restrict__ srcB,
                                              const int* __restrict__ dstB,
                                              const unsigned* __restrict__ hcB,
                                              const int* __restrict__ bbB,
                                              int* __restrict__ tmpB, int half) {
    __shared__ unsigned hbase[NSB];
    __shared__ unsigned hcnt[NSB];
    bool sec = blockIdx.x >= half;
    int c = sec ? blockIdx.x - half : blockIdx.x;
    const int* src = sec ? srcB : srcA;
    const int* dst = sec ? dstB : dstA;
    const unsigned* hc = sec ? hcB : hcA;
    const int* bb = sec ? bbB : bbA;
    int* tmp = sec ? tmpB : tmpA;
    for (int i = threadIdx.x; i < NSB; i += 256) {
        hbase[i] = (unsigned)bb[i] + hc[(size_t)c * NSB + i];
        hcnt[i] = 0u;
    }
    __syncthreads();
    int beg = c * CHUNK, end = min(beg + CHUNK, NE);
    for (int e = beg + (int)threadIdx.x; e < end; e += 256) {
        int d = dst[e];
        int sb = d >> 8;
        unsigned pos = hbase[sb] + atomicAdd(&hcnt[sb], 1u);
        tmp[pos] = ((d & 255) << 16) | src[e];
    }
}

// ---------- pass 2: per-superbucket fine scatter + deg/rowptr/dinv, ushort csr ----------
__global__ __launch_bounds__(256) void k_bin2(const int* __restrict__ tmpA,
                                              const int* __restrict__ bbA,
                                              unsigned short* __restrict__ csrA,
                                              unsigned* __restrict__ degA,
                                              float* __restrict__ dinvA,
                                              int* __restrict__ rpA,
                                              const int* __restrict__ tmpB,
                                              const int* __restrict__ bbB,
                                              unsigned short* __restrict__ csrB,
                                              unsigned* __restrict__ degB,
                                              float* __restrict__ dinvB,
                                              int* __restrict__ rpB, int half) {
    __shared__ unsigned cnt[256];
    __shared__ unsigned scan[256];
    __shared__ unsigned curs[256];
    bool sec = blockIdx.x >= half;
    int sb = sec ? blockIdx.x - half : blockIdx.x;
    const int* tmp = sec ? tmpB : tmpA;
    const int* bb = sec ? bbB : bbA;
    unsigned short* csr = sec ? csrB : csrA;
    unsigned* deg = sec ? degB : degA;
    float* dinv = sec ? dinvB : dinvA;
    int* rp = sec ? rpB : rpA;
    int beg = bb[sb], end = bb[sb + 1];
    cnt[threadIdx.x] = 0u;
    __syncthreads();
    for (int e = beg + (int)threadIdx.x; e < end; e += 256)
        atomicAdd(&cnt[(tmp[e] >> 16) & 255], 1u);
    __syncthreads();
    unsigned v = cnt[threadIdx.x];
    scan[threadIdx.x] = v;
    __syncthreads();
    for (int off = 1; off < 256; off <<= 1) {
        unsigned t = (threadIdx.x >= (unsigned)off) ? scan[threadIdx.x - off] : 0u;
        __syncthreads();
        scan[threadIdx.x] += t;
        __syncthreads();
    }
    unsigned excl = scan[threadIdx.x] - v;
    int n = sb * 256 + (int)threadIdx.x;
    if (n < NN) {
        deg[n] = v;
        rp[n] = beg + (int)excl;
        dinv[n] = rsqrtf((float)(v + 1u));
    }
    curs[threadIdx.x] = (unsigned)beg + excl;
    __syncthreads();
    for (int e = beg + (int)threadIdx.x; e < end; e += 256) {
        int p = tmp[e];
        unsigned pos = atomicAdd(&curs[(p >> 16) & 255], 1u);
        csr[pos] = (unsigned short)(p & 0xFFFF);
    }
}

// ---------- layer-1 GEMM: h = x @ W_in (shared by both views) ----------
__global__ __launch_bounds__(256) void k_gemm_in(const float* __restrict__ x,
                                                 const float* __restrict__ W,
                                                 float* __restrict__ h, int N) {
    __shared__ float Ws[NIN * HID];
    for (int i = threadIdx.x; i < NIN * HID; i += 256) Ws[i] = W[i];
    __syncthreads();
    int row = blockIdx.x * 8 + (threadIdx.x >> 5);
    int col = threadIdx.x & 31;
    if (row >= N) return;
    const float4* xr = reinterpret_cast<const float4*>(x + (size_t)row * NIN);
    float acc = 0.f;
#pragma unroll
    for (int k4 = 0; k4 < NIN / 4; ++k4) {
        float4 v = xr[k4];
        int k = k4 * 4;
        acc = fmaf(v.x, Ws[(k + 0) * HID + col], acc);
        acc = fmaf(v.y, Ws[(k + 1) * HID + col], acc);
        acc = fmaf(v.z, Ws[(k + 2) * HID + col], acc);
        acc = fmaf(v.w, Ws[(k + 3) * HID + col], acc);
    }
    h[(size_t)row * HID + col] = acc;
}

// ---------- L1: pull both views from SHARED h (per-edge dinv_v[s]) + fused sim-mix ----------
// outputs: Tu = (x1 + x2*sim)*dinv_u ; Tv = (x2 + x1*sim)*dinv_u2  (L2 gather tables)
__global__ __launch_bounds__(256) void k_pull_mix(
    const float* __restrict__ h,
    const unsigned short* __restrict__ csrU, const int* __restrict__ rpU,
    const unsigned* __restrict__ degU, const float* __restrict__ dinvU,
    const unsigned short* __restrict__ csrV, const int* __restrict__ rpV,
    const unsigned* __restrict__ degV, const float* __restrict__ dinvV,
    const float* __restrict__ bin, float* __restrict__ Tu, float* __restrict__ Tv) {
    __shared__ float sh[16][2][36];  // padded: 2-way max bank aliasing
    int t = threadIdx.x;
    int nl = t >> 4;
    int view = (t >> 3) & 1;
    int q = t & 7;
    int node = blockIdx.x * 16 + nl;   // 3125*16 = 50000 exact
    const unsigned short* csr = view ? csrV : csrU;
    const int* rp = view ? rpV : rpU;
    const unsigned* deg = view ? degV : degU;
    const float* dv = view ? dinvV : dinvU;
    const float4* h4 = reinterpret_cast<const float4*>(h);
    float dnode = dv[node];
    float4 self = h4[(size_t)node * 8 + q];
    float4 acc;
    acc.x = self.x * dnode; acc.y = self.y * dnode;
    acc.z = self.z * dnode; acc.w = self.w * dnode;
    int beg = rp[node];
    int end = beg + (int)deg[node];
    int e = beg;
    for (; e + 2 <= end; e += 2) {
        int s0 = csr[e], s1 = csr[e + 1];
        float w0 = dv[s0], w1 = dv[s1];
        float4 x0 = h4[(size_t)s0 * 8 + q];
        float4 x1 = h4[(size_t)s1 * 8 + q];
        acc.x = fmaf(x0.x, w0, acc.x); acc.y = fmaf(x0.y, w0, acc.y);
        acc.z = fmaf(x0.z, w0, acc.z); acc.w = fmaf(x0.w, w0, acc.w);
        acc.x = fmaf(x1.x, w1, acc.x); acc.y = fmaf(x1.y, w1, acc.y);
        acc.z = fmaf(x1.z, w1, acc.z); acc.w = fmaf(x1.w, w1, acc.w);
    }
    if (e < end) {
        int s0 = csr[e];
        float w0 = dv[s0];
        float4 x0 = h4[(size_t)s0 * 8 + q];
        acc.x = fmaf(x0.x, w0, acc.x); acc.y = fmaf(x0.y, w0, acc.y);
        acc.z = fmaf(x0.z, w0, acc.z); acc.w = fmaf(x0.w, w0, acc.w);
    }
    sh[nl][view][q * 4 + 0] = fmaf(acc.x, dnode, bin[q * 4 + 0]);
    sh[nl][view][q * 4 + 1] = fmaf(acc.y, dnode, bin[q * 4 + 1]);
    sh[nl][view][q * 4 + 2] = fmaf(acc.z, dnode, bin[q * 4 + 2]);
    sh[nl][view][q * 4 + 3] = fmaf(acc.w, dnode, bin[q * 4 + 3]);
    __syncthreads();
    // mix: 16 lanes per node, each owns elems l16 and l16+16
    int l16 = t & 15;
    float a0 = sh[nl][0][l16], a1 = sh[nl][0][l16 + 16];
    float b0 = sh[nl][1][l16], b1 = sh[nl][1][l16 + 16];
    float n1 = a0 * a0 + a1 * a1;
    float n2 = b0 * b0 + b1 * b1;
    float dt = a0 * b0 + a1 * b1;
#pragma unroll
    for (int m = 8; m >= 1; m >>= 1) {
        n1 += __shfl_xor(n1, m);
        n2 += __shfl_xor(n2, m);
        dt += __shfl_xor(dt, m);
    }
    float sim = dt / (fmaxf(sqrtf(n1), EPS) * fmaxf(sqrtf(n2), EPS));
    float du = dinvU[node], dw = dinvV[node];
    Tu[(size_t)node * 32 + l16]      = (a0 + b0 * sim) * du;
    Tu[(size_t)node * 32 + l16 + 16] = (a1 + b1 * sim) * du;
    Tv[(size_t)node * 32 + l16]      = (b0 + a0 * sim) * dw;
    Tv[(size_t)node * 32 + l16 + 16] = (b1 + a1 * sim) * dw;
}

// ---------- generic pull (float4 gather, ushort csr), table pre-scaled by dinv_s ----------
template <int F, int S>
__device__ __forceinline__ void pull_body(const float* __restrict__ hs,
                                          const unsigned short* __restrict__ csr,
                                          const int* __restrict__ rowptr,
                                          const unsigned* __restrict__ deg,
                                          const float* __restrict__ dinv,
                                          float* __restrict__ out, int N,
                                          int blk, int tid) {
    constexpr int L = F / 4;
    int node = blk * (256 / L) + tid / L;
    int q = tid % L;
    if (node >= N) return;
    const float4* h4 = reinterpret_cast<const float4*>(hs);
    int beg = rowptr[node];
    int end = beg + (int)deg[node];
    float4 acc = h4[(size_t)node * L + q];  // self term (table already dinv_s-scaled... self uses own row)
    int e = beg;
    for (; e + 2 <= end; e += 2) {
        int s0 = csr[e], s1 = csr[e + 1];
        float4 v0 = h4[(size_t)s0 * L + q];
        float4 v1 = h4[(size_t)s1 * L + q];
        acc.x += v0.x + v1.x;
        acc.y += v0.y + v1.y;
        acc.z += v0.z + v1.z;
        acc.w += v0.w + v1.w;
    }
    if (e < end) {
        float4 v0 = h4[(size_t)csr[e] * L + q];
        acc.x += v0.x; acc.y += v0.y; acc.z += v0.z; acc.w += v0.w;
    }
    float di = dinv[node];
    float4 r;
    r.x = acc.x * di; r.y = acc.y * di; r.z = acc.z * di; r.w = acc.w * di;
    *reinterpret_cast<float4*>(out + (size_t)node * S + q * 4) = r;
}

// L2: both views, one launch (z_v = dinv_d * (sum T_v[s] + T_v[d]))
__global__ __launch_bounds__(256) void k_pull2(
    const float* __restrict__ hsA, const unsigned short* __restrict__ csrA,
    const int* __restrict__ rpA, const unsigned* __restrict__ degA,
    const float* __restrict__ dinvA, float* __restrict__ outA,
    const float* __restrict__ hsB, const unsigned short* __restrict__ csrB,
    const int* __restrict__ rpB, const unsigned* __restrict__ degB,
    const float* __restrict__ dinvB, float* __restrict__ outB, int N, int half) {
    bool sec = blockIdx.x >= half;
    int blk = sec ? blockIdx.x - half : blockIdx.x;
    if (sec) pull_body<HID, HID>(hsB, csrB, rpB, degB, dinvB, outB, N, blk, threadIdx.x);
    else     pull_body<HID, HID>(hsA, csrA, rpA, degA, dinvA, outA, N, blk, threadIdx.x);
}

// L3 pull: F=64 packed
__global__ __launch_bounds__(256) void k_pull64(const float* __restrict__ hs,
                                                const unsigned short* __restrict__ csr,
                                                const int* __restrict__ rowptr,
                                                const unsigned* __restrict__ deg,
                                                const float* __restrict__ dinv,
                                                float* __restrict__ out, int N) {
    pull_body<64, 64>(hs, csr, rowptr, deg, dinv, out, N, blockIdx.x, threadIdx.x);
}

// ---------- L2 epilogue: GEMM(32x32)+bias on both views, sim-mix, pack P scaled by dinv_u ----------
__global__ __launch_bounds__(256) void k_hid_mix_pack(const float* __restrict__ zU,
                                                      const float* __restrict__ zV,
                                                      const float* __restrict__ W,
                                                      const float* __restrict__ bias,
                                                      const float* __restrict__ dinvU,
                                                      float* __restrict__ P) {
    __shared__ float Ws[HID * HID];
    __shared__ float zs[8][2][33];
    for (int i = threadIdx.x; i < HID * HID; i += 256) Ws[i] = W[i];
    int nb = blockIdx.x * 8;   // 6250*8 = 50000 exact
    for (int i = threadIdx.x; i < 8 * 32; i += 256) {
        int nl = i >> 5, k = i & 31;
        zs[nl][0][k] = zU[(size_t)(nb + nl) * 32 + k];
        zs[nl][1][k] = zV[(size_t)(nb + nl) * 32 + k];
    }
    __syncthreads();
    int nl = threadIdx.x >> 5, col = threadIdx.x & 31;
    int node = nb + nl;
    float bb = bias[col];
    float x1 = bb, x2 = bb;
#pragma unroll
    for (int k = 0; k < 32; ++k) {
        float wk = Ws[k * 32 + col];
        x1 = fmaf(zs[nl][0][k], wk, x1);
        x2 = fmaf(zs[nl][1][k], wk, x2);
    }
    float n1 = x1 * x1, n2 = x2 * x2, dt = x1 * x2;
#pragma unroll
    for (int m = 16; m >= 1; m >>= 1) {
        n1 += __shfl_xor(n1, m);
        n2 += __shfl_xor(n2, m);
        dt += __shfl_xor(dt, m);
    }
    float sim = dt / (fmaxf(sqrtf(n1), EPS) * fmaxf(sqrtf(n2), EPS));
    float du = dinvU[node];
    P[(size_t)node * 64 + col]      = (x1 + x2 * sim) * du;
    P[(size_t)node * 64 + 32 + col] = (x2 + x1 * sim) * du;
}

// ---------- L3 GEMM: out[:,0:128] = Q[:,0:32]@W+b ; out[:,128:256] = Q[:,32:64]@W+b ----------
__global__ __launch_bounds__(256) void k_gemm_out2(const float* __restrict__ Q,
                                                   const float* __restrict__ W,
                                                   const float* __restrict__ b,
                                                   float* __restrict__ out, int N) {
    __shared__ float Ws[HID * FOUT];
    for (int i = threadIdx.x; i < HID * FOUT; i += 256) Ws[i] = W[i];
    __syncthreads();
    int row = blockIdx.x * 2 + (threadIdx.x >> 7);
    int col = threadIdx.x & 127;
    if (row >= N) return;
    const float4* q4 = reinterpret_cast<const float4*>(Q + (size_t)row * 64);
    float acc1 = 0.f, acc2 = 0.f;
#pragma unroll
    for (int k4 = 0; k4 < HID / 4; ++k4) {
        float4 v1 = q4[k4];
        float4 v2 = q4[k4 + 8];
        int k = k4 * 4;
        acc1 = fmaf(v1.x, Ws[(k + 0) * FOUT + col], acc1);
        acc1 = fmaf(v1.y, Ws[(k + 1) * FOUT + col], acc1);
        acc1 = fmaf(v1.z, Ws[(k + 2) * FOUT + col], acc1);
        acc1 = fmaf(v1.w, Ws[(k + 3) * FOUT + col], acc1);
        acc2 = fmaf(v2.x, Ws[(k + 0) * FOUT + col], acc2);
        acc2 = fmaf(v2.y, Ws[(k + 1) * FOUT + col], acc2);
        acc2 = fmaf(v2.z, Ws[(k + 2) * FOUT + col], acc2);
        acc2 = fmaf(v2.w, Ws[(k + 3) * FOUT + col], acc2);
    }
    float bb = b[col];
    out[(size_t)row * OSTR + col] = acc1 + bb;
    out[(size_t)row * OSTR + FOUT + col] = acc2 + bb;
}

// ---------------- host ----------------
extern "C" void kernel_launch(void* const* d_in, const int* in_sizes, int n_in,
                              void* d_out, int out_size, void* d_ws, size_t ws_size,
                              hipStream_t stream) {
    const float* x     = (const float*)d_in[0];
    const int*   ei_u  = (const int*)d_in[1];
    const int*   ei_u2 = (const int*)d_in[2];
    const float* W_in  = (const float*)d_in[3];
    const float* b_in  = (const float*)d_in[4];
    const float* W_hid = (const float*)d_in[5];
    const float* b_hid = (const float*)d_in[6];
    const float* W_out = (const float*)d_in[7];
    const float* b_out = (const float*)d_in[8];
    float* out = (float*)d_out;

    const int* src_u  = ei_u;
    const int* dst_u  = ei_u + NE;
    const int* src_u2 = ei_u2;
    const int* dst_u2 = ei_u2 + NE;

    char* w = (char*)d_ws;
    auto carve = [&](size_t bytes) {
        char* p = w;
        w += (bytes + 255) & ~(size_t)255;
        return p;
    };
    unsigned* hc_u   = (unsigned*)carve((size_t)NCH * NSB * sizeof(unsigned));
    unsigned* hc_u2  = (unsigned*)carve((size_t)NCH * NSB * sizeof(unsigned));
    unsigned* tot_u  = (unsigned*)carve(NSB * sizeof(unsigned));
    unsigned* tot_u2 = (unsigned*)carve(NSB * sizeof(unsigned));
    int*      bb_u   = (int*)carve((NSB + 1) * sizeof(int));
    int*      bb_u2  = (int*)carve((NSB + 1) * sizeof(int));
    unsigned* deg_u  = (unsigned*)carve(NN * sizeof(unsigned));
    unsigned* deg_u2 = (unsigned*)carve(NN * sizeof(unsigned));
    float*    dinv_u  = (float*)carve(NN * sizeof(float));
    float*    dinv_u2 = (float*)carve(NN * sizeof(float));
    int*      rp_u   = (int*)carve(NN * sizeof(int));
    int*      rp_u2  = (int*)carve(NN * sizeof(int));
    unsigned short* csr_u  = (unsigned short*)carve((size_t)NE * sizeof(unsigned short));
    unsigned short* csr_u2 = (unsigned short*)carve((size_t)NE * sizeof(unsigned short));
    float* h    = (float*)carve((size_t)NN * HID * sizeof(float));
    float* T_u  = (float*)carve((size_t)NN * HID * sizeof(float));
    float* T_u2 = (float*)carve((size_t)NN * HID * sizeof(float));
    float* z_u  = (float*)carve((size_t)NN * HID * sizeof(float));
    float* z_u2 = (float*)carve((size_t)NN * HID * sizeof(float));
    float* P    = (float*)carve((size_t)NN * 64 * sizeof(float));
    float* Q    = (float*)carve((size_t)NN * 64 * sizeof(float));
    // coarse-bin payload buffers alias P/Q (each NE ints = 6.4 MB; P/Q written only later)
    int* tmp_u  = (int*)P;
    int* tmp_u2 = (int*)Q;

    const int BLK = 256;
    const int gP32 = (NN + 31) / 32;   // 1563
    const int gP64 = (NN + 15) / 16;   // 3125
    const int gG   = (NN + 7) / 8;     // 6250
    const int gG2  = (NN + 1) / 2;     // 25000

    // --- CSR build: hist -> cscan -> bscan -> bin1 -> bin2 (zero global atomics) ---
    k_hist<<<2 * NCH, BLK, 0, stream>>>(dst_u, dst_u2, hc_u, hc_u2, NCH);
    k_cscan<<<2 * NSB, BLK, 0, stream>>>(hc_u, hc_u2, tot_u, tot_u2, NSB);
    k_bscan<<<2, BLK, 0, stream>>>(tot_u, tot_u2, bb_u, bb_u2);
    k_bin1<<<2 * NCH, BLK, 0, stream>>>(src_u, dst_u, hc_u, bb_u, tmp_u,
                                        src_u2, dst_u2, hc_u2, bb_u2, tmp_u2, NCH);
    k_bin2<<<2 * NSB, BLK, 0, stream>>>(tmp_u, bb_u, csr_u, deg_u, dinv_u, rp_u,
                                        tmp_u2, bb_u2, csr_u2, deg_u2, dinv_u2, rp_u2, NSB);

    // --- layer 1: shared-h pull on both views + fused mix -> L2 gather tables ---
    k_gemm_in<<<gG, BLK, 0, stream>>>(x, W_in, h, NN);
    k_pull_mix<<<gP64, BLK, 0, stream>>>(h,
        csr_u, rp_u, deg_u, dinv_u,
        csr_u2, rp_u2, deg_u2, dinv_u2,
        b_in, T_u, T_u2);

    // --- layer 2: aggregate-then-GEMM (agg(x@W) = agg(x)@W) ---
    k_pull2<<<2 * gP32, BLK, 0, stream>>>(
        T_u, csr_u, rp_u, deg_u, dinv_u, z_u,
        T_u2, csr_u2, rp_u2, deg_u2, dinv_u2, z_u2, NN, gP32);
    k_hid_mix_pack<<<gG, BLK, 0, stream>>>(z_u, z_u2, W_hid, b_hid, dinv_u, P);

    // --- layer 3: packed F=64 pull on view u, then fused GEMM ---
    k_pull64<<<gP64, BLK, 0, stream>>>(P, csr_u, rp_u, deg_u, dinv_u, Q, NN);
    k_gemm_out2<<<gG2, BLK, 0, stream>>>(Q, W_out, b_out, out, NN);

    (void)in_sizes; (void)n_in; (void)out_size; (void)ws_size;
}

// Round 7
// 359.329 us; speedup vs baseline: 2.5721x; 1.0281x over previous
//
#include <hip/hip_runtime.h>
#include <hip/hip_bf16.h>

#define NN 50000
#define NE 1600000
#define NIN 256
#define HID 32
#define FOUT 128
#define OSTR 256
#define NSB ((NN + 255) / 256)      // 196 superbuckets of 256 nodes
#define CHUNK 2048
#define NCH ((NE + CHUNK - 1) / CHUNK)  // 782 chunks per view

static constexpr float EPS = 1e-12f;

// ---------- pass 0: per-chunk histogram, stored (no atomics) ----------
__global__ __launch_bounds__(256) void k_hist(const int* __restrict__ dstA,
                                              const int* __restrict__ dstB,
                                              unsigned* __restrict__ hcA,
                                              unsigned* __restrict__ hcB, int half) {
    __shared__ unsigned h[NSB];
    for (int i = threadIdx.x; i < NSB; i += 256) h[i] = 0u;
    __syncthreads();
    bool sec = blockIdx.x >= half;
    int c = sec ? blockIdx.x - half : blockIdx.x;
    const int* dst = sec ? dstB : dstA;
    unsigned* hc = sec ? hcB : hcA;
    int beg = c * CHUNK, end = min(beg + CHUNK, NE);
    for (int e = beg + (int)threadIdx.x; e < end; e += 256)
        atomicAdd(&h[dst[e] >> 8], 1u);
    __syncthreads();
    for (int i = threadIdx.x; i < NSB; i += 256) hc[(size_t)c * NSB + i] = h[i];
}

// ---------- per-bucket scan over chunks: hcount -> exclusive offsets; totals out ----------
__global__ __launch_bounds__(256) void k_cscan(unsigned* __restrict__ hcA,
                                               unsigned* __restrict__ hcB,
                                               unsigned* __restrict__ totA,
                                               unsigned* __restrict__ totB, int half) {
    __shared__ unsigned tile[256];
    __shared__ unsigned carry;
    bool sec = blockIdx.x >= half;
    int sb = sec ? blockIdx.x - half : blockIdx.x;
    unsigned* hc = sec ? hcB : hcA;
    unsigned* tot = sec ? totB : totA;
    if (threadIdx.x == 0) carry = 0u;
    __syncthreads();
    for (int base = 0; base < NCH; base += 256) {
        int c = base + (int)threadIdx.x;
        unsigned v = (c < NCH) ? hc[(size_t)c * NSB + sb] : 0u;
        tile[threadIdx.x] = v;
        __syncthreads();
        for (int off = 1; off < 256; off <<= 1) {
            unsigned t = (threadIdx.x >= (unsigned)off) ? tile[threadIdx.x - off] : 0u;
            __syncthreads();
            tile[threadIdx.x] += t;
            __syncthreads();
        }
        if (c < NCH) hc[(size_t)c * NSB + sb] = carry + tile[threadIdx.x] - v;
        __syncthreads();
        if (threadIdx.x == 0) carry += tile[255];
        __syncthreads();
    }
    if (threadIdx.x == 0) tot[sb] = carry;
}

// ---------- bucket bases: exclusive scan of totals ----------
__global__ __launch_bounds__(256) void k_bscan(const unsigned* __restrict__ totA,
                                               const unsigned* __restrict__ totB,
                                               int* __restrict__ bbA, int* __restrict__ bbB) {
    __shared__ unsigned tile[256];
    const unsigned* tot = blockIdx.x ? totB : totA;
    int* bb = blockIdx.x ? bbB : bbA;
    unsigned v = (threadIdx.x < NSB) ? tot[threadIdx.x] : 0u;
    tile[threadIdx.x] = v;
    __syncthreads();
    for (int off = 1; off < 256; off <<= 1) {
        unsigned t = (threadIdx.x >= (unsigned)off) ? tile[threadIdx.x - off] : 0u;
        __syncthreads();
        tile[threadIdx.x] += t;
        __syncthreads();
    }
    if (threadIdx.x < NSB) bb[threadIdx.x] = (int)(tile[threadIdx.x] - v);
    if (threadIdx.x == 0) bb[NSB] = NE;
}

// ---------- pass 1: coarse scatter, deterministic bases, no global atomics ----------
__global__ __launch_bounds__(256) void k_bin1(const int* __restrict__ srcA,
                                              const int* __restrict__ dstA,
                                              const unsigned* __restrict__ hcA,
                                              const int* __restrict__ bbA,
                                              int* __restrict__ tmpA,
                                              const int* __restrict__ srcB,
                                              const int* __restrict__ dstB,
                                              const unsigned* __restrict__ hcB,
                                              const int* __restrict__ bbB,
                                              int* __restrict__ tmpB, int half) {
    __shared__ unsigned hbase[NSB];
    __shared__ unsigned hcnt[NSB];
    bool sec = blockIdx.x >= half;
    int c = sec ? blockIdx.x - half : blockIdx.x;
    const int* src = sec ? srcB : srcA;
    const int* dst = sec ? dstB : dstA;
    const unsigned* hc = sec ? hcB : hcA;
    const int* bb = sec ? bbB : bbA;
    int* tmp = sec ? tmpB : tmpA;
    for (int i = threadIdx.x; i < NSB; i += 256) {
        hbase[i] = (unsigned)bb[i] + hc[(size_t)c * NSB + i];
        hcnt[i] = 0u;
    }
    __syncthreads();
    int beg = c * CHUNK, end = min(beg + CHUNK, NE);
    for (int e = beg + (int)threadIdx.x; e < end; e += 256) {
        int d = dst[e];
        int sb = d >> 8;
        unsigned pos = hbase[sb] + atomicAdd(&hcnt[sb], 1u);
        tmp[pos] = ((d & 255) << 16) | src[e];
    }
}

// ---------- pass 2: per-superbucket fine scatter + deg/rowptr/dinv, ushort csr ----------
__global__ __launch_bounds__(256) void k_bin2(const int* __restrict__ tmpA,
                                              const int* __restrict__ bbA,
                                              unsigned short* __restrict__ csrA,
                                              unsigned* __restrict__ degA,
                                              float* __restrict__ dinvA,
                                              int* __restrict__ rpA,
                                              const int* __restrict__ tmpB,
                                              const int* __restrict__ bbB,
                                              unsigned short* __restrict__ csrB,
                                              unsigned* __restrict__ degB,
                                              float* __restrict__ dinvB,
                                              int* __restrict__ rpB, int half) {
    __shared__ unsigned cnt[256];
    __shared__ unsigned scan[256];
    __shared__ unsigned curs[256];
    bool sec = blockIdx.x >= half;
    int sb = sec ? blockIdx.x - half : blockIdx.x;
    const int* tmp = sec ? tmpB : tmpA;
    const int* bb = sec ? bbB : bbA;
    unsigned short* csr = sec ? csrB : csrA;
    unsigned* deg = sec ? degB : degA;
    float* dinv = sec ? dinvB : dinvA;
    int* rp = sec ? rpB : rpA;
    int beg = bb[sb], end = bb[sb + 1];
    cnt[threadIdx.x] = 0u;
    __syncthreads();
    for (int e = beg + (int)threadIdx.x; e < end; e += 256)
        atomicAdd(&cnt[(tmp[e] >> 16) & 255], 1u);
    __syncthreads();
    unsigned v = cnt[threadIdx.x];
    scan[threadIdx.x] = v;
    __syncthreads();
    for (int off = 1; off < 256; off <<= 1) {
        unsigned t = (threadIdx.x >= (unsigned)off) ? scan[threadIdx.x - off] : 0u;
        __syncthreads();
        scan[threadIdx.x] += t;
        __syncthreads();
    }
    unsigned excl = scan[threadIdx.x] - v;
    int n = sb * 256 + (int)threadIdx.x;
    if (n < NN) {
        deg[n] = v;
        rp[n] = beg + (int)excl;
        dinv[n] = rsqrtf((float)(v + 1u));
    }
    curs[threadIdx.x] = (unsigned)beg + excl;
    __syncthreads();
    for (int e = beg + (int)threadIdx.x; e < end; e += 256) {
        int p = tmp[e];
        unsigned pos = atomicAdd(&curs[(p >> 16) & 255], 1u);
        csr[pos] = (unsigned short)(p & 0xFFFF);
    }
}

// ---------- layer-1 GEMM: h = x @ W_in (32 rows/block, staging amortized) ----------
__global__ __launch_bounds__(256) void k_gemm_in(const float* __restrict__ x,
                                                 const float* __restrict__ W,
                                                 float* __restrict__ h, int N) {
    __shared__ float Ws[NIN * HID];
    for (int i = threadIdx.x; i < NIN * HID; i += 256) Ws[i] = W[i];
    __syncthreads();
    int base = blockIdx.x * 32;
    int col = threadIdx.x & 31;
#pragma unroll
    for (int it = 0; it < 4; ++it) {
        int row = base + it * 8 + (threadIdx.x >> 5);
        if (row >= N) return;
        const float4* xr = reinterpret_cast<const float4*>(x + (size_t)row * NIN);
        float acc = 0.f;
#pragma unroll
        for (int k4 = 0; k4 < NIN / 4; ++k4) {
            float4 v = xr[k4];
            int k = k4 * 4;
            acc = fmaf(v.x, Ws[(k + 0) * HID + col], acc);
            acc = fmaf(v.y, Ws[(k + 1) * HID + col], acc);
            acc = fmaf(v.z, Ws[(k + 2) * HID + col], acc);
            acc = fmaf(v.w, Ws[(k + 3) * HID + col], acc);
        }
        h[(size_t)row * HID + col] = acc;
    }
}

// ---------- L1: pull both views from SHARED h (per-edge dinv_v[s]) + fused sim-mix ----------
__global__ __launch_bounds__(256) void k_pull_mix(
    const float* __restrict__ h,
    const unsigned short* __restrict__ csrU, const int* __restrict__ rpU,
    const unsigned* __restrict__ degU, const float* __restrict__ dinvU,
    const unsigned short* __restrict__ csrV, const int* __restrict__ rpV,
    const unsigned* __restrict__ degV, const float* __restrict__ dinvV,
    const float* __restrict__ bin, float* __restrict__ Tu, float* __restrict__ Tv) {
    __shared__ float sh[16][2][36];
    int t = threadIdx.x;
    int nl = t >> 4;
    int view = (t >> 3) & 1;
    int q = t & 7;
    int node = blockIdx.x * 16 + nl;   // 3125*16 = 50000 exact
    const unsigned short* csr = view ? csrV : csrU;
    const int* rp = view ? rpV : rpU;
    const unsigned* deg = view ? degV : degU;
    const float* dv = view ? dinvV : dinvU;
    const float4* h4 = reinterpret_cast<const float4*>(h);
    float dnode = dv[node];
    float4 self = h4[(size_t)node * 8 + q];
    float4 acc;
    acc.x = self.x * dnode; acc.y = self.y * dnode;
    acc.z = self.z * dnode; acc.w = self.w * dnode;
    int beg = rp[node];
    int end = beg + (int)deg[node];
    int e = beg;
    for (; e + 2 <= end; e += 2) {
        int s0 = csr[e], s1 = csr[e + 1];
        float w0 = dv[s0], w1 = dv[s1];
        float4 x0 = h4[(size_t)s0 * 8 + q];
        float4 x1 = h4[(size_t)s1 * 8 + q];
        acc.x = fmaf(x0.x, w0, acc.x); acc.y = fmaf(x0.y, w0, acc.y);
        acc.z = fmaf(x0.z, w0, acc.z); acc.w = fmaf(x0.w, w0, acc.w);
        acc.x = fmaf(x1.x, w1, acc.x); acc.y = fmaf(x1.y, w1, acc.y);
        acc.z = fmaf(x1.z, w1, acc.z); acc.w = fmaf(x1.w, w1, acc.w);
    }
    if (e < end) {
        int s0 = csr[e];
        float w0 = dv[s0];
        float4 x0 = h4[(size_t)s0 * 8 + q];
        acc.x = fmaf(x0.x, w0, acc.x); acc.y = fmaf(x0.y, w0, acc.y);
        acc.z = fmaf(x0.z, w0, acc.z); acc.w = fmaf(x0.w, w0, acc.w);
    }
    sh[nl][view][q * 4 + 0] = fmaf(acc.x, dnode, bin[q * 4 + 0]);
    sh[nl][view][q * 4 + 1] = fmaf(acc.y, dnode, bin[q * 4 + 1]);
    sh[nl][view][q * 4 + 2] = fmaf(acc.z, dnode, bin[q * 4 + 2]);
    sh[nl][view][q * 4 + 3] = fmaf(acc.w, dnode, bin[q * 4 + 3]);
    __syncthreads();
    int l16 = t & 15;
    float a0 = sh[nl][0][l16], a1 = sh[nl][0][l16 + 16];
    float b0 = sh[nl][1][l16], b1 = sh[nl][1][l16 + 16];
    float n1 = a0 * a0 + a1 * a1;
    float n2 = b0 * b0 + b1 * b1;
    float dt = a0 * b0 + a1 * b1;
#pragma unroll
    for (int m = 8; m >= 1; m >>= 1) {
        n1 += __shfl_xor(n1, m);
        n2 += __shfl_xor(n2, m);
        dt += __shfl_xor(dt, m);
    }
    float sim = dt / (fmaxf(sqrtf(n1), EPS) * fmaxf(sqrtf(n2), EPS));
    float du = dinvU[node], dw = dinvV[node];
    Tu[(size_t)node * 32 + l16]      = (a0 + b0 * sim) * du;
    Tu[(size_t)node * 32 + l16 + 16] = (a1 + b1 * sim) * du;
    Tv[(size_t)node * 32 + l16]      = (b0 + a0 * sim) * dw;
    Tv[(size_t)node * 32 + l16 + 16] = (b1 + a1 * sim) * dw;
}

// ---------- generic pull (float4 gather, ushort csr), table pre-scaled by dinv_s ----------
template <int F, int S>
__device__ __forceinline__ void pull_body(const float* __restrict__ hs,
                                          const unsigned short* __restrict__ csr,
                                          const int* __restrict__ rowptr,
                                          const unsigned* __restrict__ deg,
                                          const float* __restrict__ dinv,
                                          float* __restrict__ out, int N,
                                          int blk, int tid) {
    constexpr int L = F / 4;
    int node = blk * (256 / L) + tid / L;
    int q = tid % L;
    if (node >= N) return;
    const float4* h4 = reinterpret_cast<const float4*>(hs);
    int beg = rowptr[node];
    int end = beg + (int)deg[node];
    float4 acc = h4[(size_t)node * L + q];
    int e = beg;
    for (; e + 2 <= end; e += 2) {
        int s0 = csr[e], s1 = csr[e + 1];
        float4 v0 = h4[(size_t)s0 * L + q];
        float4 v1 = h4[(size_t)s1 * L + q];
        acc.x += v0.x + v1.x;
        acc.y += v0.y + v1.y;
        acc.z += v0.z + v1.z;
        acc.w += v0.w + v1.w;
    }
    if (e < end) {
        float4 v0 = h4[(size_t)csr[e] * L + q];
        acc.x += v0.x; acc.y += v0.y; acc.z += v0.z; acc.w += v0.w;
    }
    float di = dinv[node];
    float4 r;
    r.x = acc.x * di; r.y = acc.y * di; r.z = acc.z * di; r.w = acc.w * di;
    *reinterpret_cast<float4*>(out + (size_t)node * S + q * 4) = r;
}

// L2: both views, one launch
__global__ __launch_bounds__(256) void k_pull2(
    const float* __restrict__ hsA, const unsigned short* __restrict__ csrA,
    const int* __restrict__ rpA, const unsigned* __restrict__ degA,
    const float* __restrict__ dinvA, float* __restrict__ outA,
    const float* __restrict__ hsB, const unsigned short* __restrict__ csrB,
    const int* __restrict__ rpB, const unsigned* __restrict__ degB,
    const float* __restrict__ dinvB, float* __restrict__ outB, int N, int half) {
    bool sec = blockIdx.x >= half;
    int blk = sec ? blockIdx.x - half : blockIdx.x;
    if (sec) pull_body<HID, HID>(hsB, csrB, rpB, degB, dinvB, outB, N, blk, threadIdx.x);
    else     pull_body<HID, HID>(hsA, csrA, rpA, degA, dinvA, outA, N, blk, threadIdx.x);
}

// L3 pull: F=64 packed
__global__ __launch_bounds__(256) void k_pull64(const float* __restrict__ hs,
                                                const unsigned short* __restrict__ csr,
                                                const int* __restrict__ rowptr,
                                                const unsigned* __restrict__ deg,
                                                const float* __restrict__ dinv,
                                                float* __restrict__ out, int N) {
    pull_body<64, 64>(hs, csr, rowptr, deg, dinv, out, N, blockIdx.x, threadIdx.x);
}

// ---------- L2 epilogue: GEMM(32x32)+bias on both views, sim-mix, pack P scaled by dinv_u ----------
__global__ __launch_bounds__(256) void k_hid_mix_pack(const float* __restrict__ zU,
                                                      const float* __restrict__ zV,
                                                      const float* __restrict__ W,
                                                      const float* __restrict__ bias,
                                                      const float* __restrict__ dinvU,
                                                      float* __restrict__ P) {
    __shared__ float Ws[HID * HID];
    __shared__ float zs[8][2][33];
    for (int i = threadIdx.x; i < HID * HID; i += 256) Ws[i] = W[i];
    int nb = blockIdx.x * 8;   // 6250*8 = 50000 exact
    for (int i = threadIdx.x; i < 8 * 32; i += 256) {
        int nl = i >> 5, k = i & 31;
        zs[nl][0][k] = zU[(size_t)(nb + nl) * 32 + k];
        zs[nl][1][k] = zV[(size_t)(nb + nl) * 32 + k];
    }
    __syncthreads();
    int nl = threadIdx.x >> 5, col = threadIdx.x & 31;
    int node = nb + nl;
    float bb = bias[col];
    float x1 = bb, x2 = bb;
#pragma unroll
    for (int k = 0; k < 32; ++k) {
        float wk = Ws[k * 32 + col];
        x1 = fmaf(zs[nl][0][k], wk, x1);
        x2 = fmaf(zs[nl][1][k], wk, x2);
    }
    float n1 = x1 * x1, n2 = x2 * x2, dt = x1 * x2;
#pragma unroll
    for (int m = 16; m >= 1; m >>= 1) {
        n1 += __shfl_xor(n1, m);
        n2 += __shfl_xor(n2, m);
        dt += __shfl_xor(dt, m);
    }
    float sim = dt / (fmaxf(sqrtf(n1), EPS) * fmaxf(sqrtf(n2), EPS));
    float du = dinvU[node];
    P[(size_t)node * 64 + col]      = (x1 + x2 * sim) * du;
    P[(size_t)node * 64 + 32 + col] = (x2 + x1 * sim) * du;
}

// ---------- L3 GEMM (32 rows/block, staging amortized) ----------
__global__ __launch_bounds__(256) void k_gemm_out2(const float* __restrict__ Q,
                                                   const float* __restrict__ W,
                                                   const float* __restrict__ b,
                                                   float* __restrict__ out, int N) {
    __shared__ float Ws[HID * FOUT];
    for (int i = threadIdx.x; i < HID * FOUT; i += 256) Ws[i] = W[i];
    __syncthreads();
    int base = blockIdx.x * 32;
    int col = threadIdx.x & 127;
    float bb = b[col];
#pragma unroll
    for (int it = 0; it < 16; ++it) {
        int row = base + it * 2 + (threadIdx.x >> 7);
        if (row >= N) return;
        const float4* q4 = reinterpret_cast<const float4*>(Q + (size_t)row * 64);
        float acc1 = 0.f, acc2 = 0.f;
#pragma unroll
        for (int k4 = 0; k4 < HID / 4; ++k4) {
            float4 v1 = q4[k4];
            float4 v2 = q4[k4 + 8];
            int k = k4 * 4;
            acc1 = fmaf(v1.x, Ws[(k + 0) * FOUT + col], acc1);
            acc1 = fmaf(v1.y, Ws[(k + 1) * FOUT + col], acc1);
            acc1 = fmaf(v1.z, Ws[(k + 2) * FOUT + col], acc1);
            acc1 = fmaf(v1.w, Ws[(k + 3) * FOUT + col], acc1);
            acc2 = fmaf(v2.x, Ws[(k + 0) * FOUT + col], acc2);
            acc2 = fmaf(v2.y, Ws[(k + 1) * FOUT + col], acc2);
            acc2 = fmaf(v2.z, Ws[(k + 2) * FOUT + col], acc2);
            acc2 = fmaf(v2.w, Ws[(k + 3) * FOUT + col], acc2);
        }
        out[(size_t)row * OSTR + col] = acc1 + bb;
        out[(size_t)row * OSTR + FOUT + col] = acc2 + bb;
    }
}

// ---------------- host ----------------
extern "C" void kernel_launch(void* const* d_in, const int* in_sizes, int n_in,
                              void* d_out, int out_size, void* d_ws, size_t ws_size,
                              hipStream_t stream) {
    const float* x     = (const float*)d_in[0];
    const int*   ei_u  = (const int*)d_in[1];
    const int*   ei_u2 = (const int*)d_in[2];
    const float* W_in  = (const float*)d_in[3];
    const float* b_in  = (const float*)d_in[4];
    const float* W_hid = (const float*)d_in[5];
    const float* b_hid = (const float*)d_in[6];
    const float* W_out = (const float*)d_in[7];
    const float* b_out = (const float*)d_in[8];
    float* out = (float*)d_out;

    const int* src_u  = ei_u;
    const int* dst_u  = ei_u + NE;
    const int* src_u2 = ei_u2;
    const int* dst_u2 = ei_u2 + NE;

    char* w = (char*)d_ws;
    auto carve = [&](size_t bytes) {
        char* p = w;
        w += (bytes + 255) & ~(size_t)255;
        return p;
    };
    unsigned* hc_u   = (unsigned*)carve((size_t)NCH * NSB * sizeof(unsigned));
    unsigned* hc_u2  = (unsigned*)carve((size_t)NCH * NSB * sizeof(unsigned));
    unsigned* tot_u  = (unsigned*)carve(NSB * sizeof(unsigned));
    unsigned* tot_u2 = (unsigned*)carve(NSB * sizeof(unsigned));
    int*      bb_u   = (int*)carve((NSB + 1) * sizeof(int));
    int*      bb_u2  = (int*)carve((NSB + 1) * sizeof(int));
    unsigned* deg_u  = (unsigned*)carve(NN * sizeof(unsigned));
    unsigned* deg_u2 = (unsigned*)carve(NN * sizeof(unsigned));
    float*    dinv_u  = (float*)carve(NN * sizeof(float));
    float*    dinv_u2 = (float*)carve(NN * sizeof(float));
    int*      rp_u   = (int*)carve(NN * sizeof(int));
    int*      rp_u2  = (int*)carve(NN * sizeof(int));
    unsigned short* csr_u  = (unsigned short*)carve((size_t)NE * sizeof(unsigned short));
    unsigned short* csr_u2 = (unsigned short*)carve((size_t)NE * sizeof(unsigned short));
    float* h    = (float*)carve((size_t)NN * HID * sizeof(float));
    float* T_u  = (float*)carve((size_t)NN * HID * sizeof(float));
    float* T_u2 = (float*)carve((size_t)NN * HID * sizeof(float));
    float* z_u  = (float*)carve((size_t)NN * HID * sizeof(float));
    float* z_u2 = (float*)carve((size_t)NN * HID * sizeof(float));
    float* P    = (float*)carve((size_t)NN * 64 * sizeof(float));
    float* Q    = (float*)carve((size_t)NN * 64 * sizeof(float));
    int* tmp_u  = (int*)P;
    int* tmp_u2 = (int*)Q;

    const int BLK = 256;
    const int gP32 = (NN + 31) / 32;   // 1563
    const int gP64 = (NN + 15) / 16;   // 3125
    const int gR32 = (NN + 31) / 32;   // 1563 (32-row GEMM blocks)
    const int gG   = (NN + 7) / 8;     // 6250

    // --- CSR build: hist -> cscan -> bscan -> bin1 -> bin2 (zero global atomics) ---
    k_hist<<<2 * NCH, BLK, 0, stream>>>(dst_u, dst_u2, hc_u, hc_u2, NCH);
    k_cscan<<<2 * NSB, BLK, 0, stream>>>(hc_u, hc_u2, tot_u, tot_u2, NSB);
    k_bscan<<<2, BLK, 0, stream>>>(tot_u, tot_u2, bb_u, bb_u2);
    k_bin1<<<2 * NCH, BLK, 0, stream>>>(src_u, dst_u, hc_u, bb_u, tmp_u,
                                        src_u2, dst_u2, hc_u2, bb_u2, tmp_u2, NCH);
    k_bin2<<<2 * NSB, BLK, 0, stream>>>(tmp_u, bb_u, csr_u, deg_u, dinv_u, rp_u,
                                        tmp_u2, bb_u2, csr_u2, deg_u2, dinv_u2, rp_u2, NSB);

    // --- layer 1: shared-h pull on both views + fused mix -> L2 gather tables ---
    k_gemm_in<<<gR32, BLK, 0, stream>>>(x, W_in, h, NN);
    k_pull_mix<<<gP64, BLK, 0, stream>>>(h,
        csr_u, rp_u, deg_u, dinv_u,
        csr_u2, rp_u2, deg_u2, dinv_u2,
        b_in, T_u, T_u2);

    // --- layer 2: aggregate-then-GEMM ---
    k_pull2<<<2 * gP32, BLK, 0, stream>>>(
        T_u, csr_u, rp_u, deg_u, dinv_u, z_u,
        T_u2, csr_u2, rp_u2, deg_u2, dinv_u2, z_u2, NN, gP32);
    k_hid_mix_pack<<<gG, BLK, 0, stream>>>(z_u, z_u2, W_hid, b_hid, dinv_u, P);

    // --- layer 3: packed F=64 pull on view u, then fused GEMM ---
    k_pull64<<<gP64, BLK, 0, stream>>>(P, csr_u, rp_u, deg_u, dinv_u, Q, NN);
    k_gemm_out2<<<gR32, BLK, 0, stream>>>(Q, W_out, b_out, out, NN);

    (void)in_sizes; (void)n_in; (void)out_size; (void)ws_size;
}

// Round 8
// 312.931 us; speedup vs baseline: 2.9535x; 1.1483x over previous
//
#include <hip/hip_runtime.h>
#include <hip/hip_bf16.h>

#define NN 50000
#define NE 1600000
#define NIN 256
#define HID 32
#define FOUT 128
#define OSTR 256
#define NSB ((NN + 255) / 256)      // 196 superbuckets of 256 nodes
#define CHUNK 2048
#define NCH ((NE + CHUNK - 1) / CHUNK)  // 782 chunks per view

static constexpr float EPS = 1e-12f;

// ---------- pass 0: per-chunk histogram, stored (no atomics) ----------
__global__ __launch_bounds__(256) void k_hist(const int* __restrict__ dstA,
                                              const int* __restrict__ dstB,
                                              unsigned* __restrict__ hcA,
                                              unsigned* __restrict__ hcB, int half) {
    __shared__ unsigned h[NSB];
    for (int i = threadIdx.x; i < NSB; i += 256) h[i] = 0u;
    __syncthreads();
    bool sec = blockIdx.x >= half;
    int c = sec ? blockIdx.x - half : blockIdx.x;
    const int* dst = sec ? dstB : dstA;
    unsigned* hc = sec ? hcB : hcA;
    int beg = c * CHUNK, end = min(beg + CHUNK, NE);
    for (int e = beg + (int)threadIdx.x; e < end; e += 256)
        atomicAdd(&h[dst[e] >> 8], 1u);
    __syncthreads();
    for (int i = threadIdx.x; i < NSB; i += 256) hc[(size_t)c * NSB + i] = h[i];
}

// ---------- per-bucket scan over chunks ----------
__global__ __launch_bounds__(256) void k_cscan(unsigned* __restrict__ hcA,
                                               unsigned* __restrict__ hcB,
                                               unsigned* __restrict__ totA,
                                               unsigned* __restrict__ totB, int half) {
    __shared__ unsigned tile[256];
    __shared__ unsigned carry;
    bool sec = blockIdx.x >= half;
    int sb = sec ? blockIdx.x - half : blockIdx.x;
    unsigned* hc = sec ? hcB : hcA;
    unsigned* tot = sec ? totB : totA;
    if (threadIdx.x == 0) carry = 0u;
    __syncthreads();
    for (int base = 0; base < NCH; base += 256) {
        int c = base + (int)threadIdx.x;
        unsigned v = (c < NCH) ? hc[(size_t)c * NSB + sb] : 0u;
        tile[threadIdx.x] = v;
        __syncthreads();
        for (int off = 1; off < 256; off <<= 1) {
            unsigned t = (threadIdx.x >= (unsigned)off) ? tile[threadIdx.x - off] : 0u;
            __syncthreads();
            tile[threadIdx.x] += t;
            __syncthreads();
        }
        if (c < NCH) hc[(size_t)c * NSB + sb] = carry + tile[threadIdx.x] - v;
        __syncthreads();
        if (threadIdx.x == 0) carry += tile[255];
        __syncthreads();
    }
    if (threadIdx.x == 0) tot[sb] = carry;
}

// ---------- bucket bases ----------
__global__ __launch_bounds__(256) void k_bscan(const unsigned* __restrict__ totA,
                                               const unsigned* __restrict__ totB,
                                               int* __restrict__ bbA, int* __restrict__ bbB) {
    __shared__ unsigned tile[256];
    const unsigned* tot = blockIdx.x ? totB : totA;
    int* bb = blockIdx.x ? bbB : bbA;
    unsigned v = (threadIdx.x < NSB) ? tot[threadIdx.x] : 0u;
    tile[threadIdx.x] = v;
    __syncthreads();
    for (int off = 1; off < 256; off <<= 1) {
        unsigned t = (threadIdx.x >= (unsigned)off) ? tile[threadIdx.x - off] : 0u;
        __syncthreads();
        tile[threadIdx.x] += t;
        __syncthreads();
    }
    if (threadIdx.x < NSB) bb[threadIdx.x] = (int)(tile[threadIdx.x] - v);
    if (threadIdx.x == 0) bb[NSB] = NE;
}

// ---------- pass 1: coarse scatter ----------
__global__ __launch_bounds__(256) void k_bin1(const int* __restrict__ srcA,
                                              const int* __restrict__ dstA,
                                              const unsigned* __restrict__ hcA,
                                              const int* __restrict__ bbA,
                                              int* __restrict__ tmpA,
                                              const int* __restrict__ srcB,
                                              const int* __restrict__ dstB,
                                              const unsigned* __restrict__ hcB,
                                              const int* __restrict__ bbB,
                                              int* __restrict__ tmpB, int half) {
    __shared__ unsigned hbase[NSB];
    __shared__ unsigned hcnt[NSB];
    bool sec = blockIdx.x >= half;
    int c = sec ? blockIdx.x - half : blockIdx.x;
    const int* src = sec ? srcB : srcA;
    const int* dst = sec ? dstB : dstA;
    const unsigned* hc = sec ? hcB : hcA;
    const int* bb = sec ? bbB : bbA;
    int* tmp = sec ? tmpB : tmpA;
    for (int i = threadIdx.x; i < NSB; i += 256) {
        hbase[i] = (unsigned)bb[i] + hc[(size_t)c * NSB + i];
        hcnt[i] = 0u;
    }
    __syncthreads();
    int beg = c * CHUNK, end = min(beg + CHUNK, NE);
    for (int e = beg + (int)threadIdx.x; e < end; e += 256) {
        int d = dst[e];
        int sb = d >> 8;
        unsigned pos = hbase[sb] + atomicAdd(&hcnt[sb], 1u);
        tmp[pos] = ((d & 255) << 16) | src[e];
    }
}

// ---------- pass 2: per-superbucket fine scatter + deg/rowptr/dinv ----------
__global__ __launch_bounds__(256) void k_bin2(const int* __restrict__ tmpA,
                                              const int* __restrict__ bbA,
                                              unsigned short* __restrict__ csrA,
                                              unsigned* __restrict__ degA,
                                              float* __restrict__ dinvA,
                                              int* __restrict__ rpA,
                                              const int* __restrict__ tmpB,
                                              const int* __restrict__ bbB,
                                              unsigned short* __restrict__ csrB,
                                              unsigned* __restrict__ degB,
                                              float* __restrict__ dinvB,
                                              int* __restrict__ rpB, int half) {
    __shared__ unsigned cnt[256];
    __shared__ unsigned scan[256];
    __shared__ unsigned curs[256];
    bool sec = blockIdx.x >= half;
    int sb = sec ? blockIdx.x - half : blockIdx.x;
    const int* tmp = sec ? tmpB : tmpA;
    const int* bb = sec ? bbB : bbA;
    unsigned short* csr = sec ? csrB : csrA;
    unsigned* deg = sec ? degB : degA;
    float* dinv = sec ? dinvB : dinvA;
    int* rp = sec ? rpB : rpA;
    int beg = bb[sb], end = bb[sb + 1];
    cnt[threadIdx.x] = 0u;
    __syncthreads();
    for (int e = beg + (int)threadIdx.x; e < end; e += 256)
        atomicAdd(&cnt[(tmp[e] >> 16) & 255], 1u);
    __syncthreads();
    unsigned v = cnt[threadIdx.x];
    scan[threadIdx.x] = v;
    __syncthreads();
    for (int off = 1; off < 256; off <<= 1) {
        unsigned t = (threadIdx.x >= (unsigned)off) ? scan[threadIdx.x - off] : 0u;
        __syncthreads();
        scan[threadIdx.x] += t;
        __syncthreads();
    }
    unsigned excl = scan[threadIdx.x] - v;
    int n = sb * 256 + (int)threadIdx.x;
    if (n < NN) {
        deg[n] = v;
        rp[n] = beg + (int)excl;
        dinv[n] = rsqrtf((float)(v + 1u));
    }
    curs[threadIdx.x] = (unsigned)beg + excl;
    __syncthreads();
    for (int e = beg + (int)threadIdx.x; e < end; e += 256) {
        int p = tmp[e];
        unsigned pos = atomicAdd(&curs[(p >> 16) & 255], 1u);
        csr[pos] = (unsigned short)(p & 0xFFFF);
    }
}

// ---------- layer-1 GEMM: row-per-lane, W via scalar loads, no LDS ----------
__global__ __launch_bounds__(64) void k_gemm_in(const float* __restrict__ x,
                                                const float* __restrict__ W,
                                                float* __restrict__ h, int N) {
    int row = blockIdx.x * 64 + threadIdx.x;
    if (row >= N) return;
    const float4* xr = reinterpret_cast<const float4*>(x + (size_t)row * NIN);
    float acc[HID];
#pragma unroll
    for (int c = 0; c < HID; ++c) acc[c] = 0.f;
    for (int k4 = 0; k4 < NIN / 4; ++k4) {   // uniform loop -> W loads are scalar
        float4 v = xr[k4];
        const float* Wk = W + k4 * 4 * HID;
#pragma unroll
        for (int c = 0; c < HID; ++c) {
            acc[c] = fmaf(v.x, Wk[c], acc[c]);
            acc[c] = fmaf(v.y, Wk[HID + c], acc[c]);
            acc[c] = fmaf(v.z, Wk[2 * HID + c], acc[c]);
            acc[c] = fmaf(v.w, Wk[3 * HID + c], acc[c]);
        }
    }
    float4* hr = reinterpret_cast<float4*>(h + (size_t)row * HID);
#pragma unroll
    for (int q = 0; q < HID / 4; ++q)
        hr[q] = make_float4(acc[4 * q], acc[4 * q + 1], acc[4 * q + 2], acc[4 * q + 3]);
}

// ---------- L1: pull both views from SHARED h + fused sim-mix ----------
__global__ __launch_bounds__(256) void k_pull_mix(
    const float* __restrict__ h,
    const unsigned short* __restrict__ csrU, const int* __restrict__ rpU,
    const unsigned* __restrict__ degU, const float* __restrict__ dinvU,
    const unsigned short* __restrict__ csrV, const int* __restrict__ rpV,
    const unsigned* __restrict__ degV, const float* __restrict__ dinvV,
    const float* __restrict__ bin, float* __restrict__ Tu, float* __restrict__ Tv) {
    __shared__ float sh[16][2][36];
    int t = threadIdx.x;
    int nl = t >> 4;
    int view = (t >> 3) & 1;
    int q = t & 7;
    int node = blockIdx.x * 16 + nl;
    const unsigned short* csr = view ? csrV : csrU;
    const int* rp = view ? rpV : rpU;
    const unsigned* deg = view ? degV : degU;
    const float* dv = view ? dinvV : dinvU;
    const float4* h4 = reinterpret_cast<const float4*>(h);
    float dnode = dv[node];
    float4 self = h4[(size_t)node * 8 + q];
    float4 acc;
    acc.x = self.x * dnode; acc.y = self.y * dnode;
    acc.z = self.z * dnode; acc.w = self.w * dnode;
    int beg = rp[node];
    int end = beg + (int)deg[node];
    int e = beg;
    for (; e + 2 <= end; e += 2) {
        int s0 = csr[e], s1 = csr[e + 1];
        float w0 = dv[s0], w1 = dv[s1];
        float4 x0 = h4[(size_t)s0 * 8 + q];
        float4 x1 = h4[(size_t)s1 * 8 + q];
        acc.x = fmaf(x0.x, w0, acc.x); acc.y = fmaf(x0.y, w0, acc.y);
        acc.z = fmaf(x0.z, w0, acc.z); acc.w = fmaf(x0.w, w0, acc.w);
        acc.x = fmaf(x1.x, w1, acc.x); acc.y = fmaf(x1.y, w1, acc.y);
        acc.z = fmaf(x1.z, w1, acc.z); acc.w = fmaf(x1.w, w1, acc.w);
    }
    if (e < end) {
        int s0 = csr[e];
        float w0 = dv[s0];
        float4 x0 = h4[(size_t)s0 * 8 + q];
        acc.x = fmaf(x0.x, w0, acc.x); acc.y = fmaf(x0.y, w0, acc.y);
        acc.z = fmaf(x0.z, w0, acc.z); acc.w = fmaf(x0.w, w0, acc.w);
    }
    sh[nl][view][q * 4 + 0] = fmaf(acc.x, dnode, bin[q * 4 + 0]);
    sh[nl][view][q * 4 + 1] = fmaf(acc.y, dnode, bin[q * 4 + 1]);
    sh[nl][view][q * 4 + 2] = fmaf(acc.z, dnode, bin[q * 4 + 2]);
    sh[nl][view][q * 4 + 3] = fmaf(acc.w, dnode, bin[q * 4 + 3]);
    __syncthreads();
    int l16 = t & 15;
    float a0 = sh[nl][0][l16], a1 = sh[nl][0][l16 + 16];
    float b0 = sh[nl][1][l16], b1 = sh[nl][1][l16 + 16];
    float n1 = a0 * a0 + a1 * a1;
    float n2 = b0 * b0 + b1 * b1;
    float dt = a0 * b0 + a1 * b1;
#pragma unroll
    for (int m = 8; m >= 1; m >>= 1) {
        n1 += __shfl_xor(n1, m);
        n2 += __shfl_xor(n2, m);
        dt += __shfl_xor(dt, m);
    }
    float sim = dt / (fmaxf(sqrtf(n1), EPS) * fmaxf(sqrtf(n2), EPS));
    float du = dinvU[node], dw = dinvV[node];
    Tu[(size_t)node * 32 + l16]      = (a0 + b0 * sim) * du;
    Tu[(size_t)node * 32 + l16 + 16] = (a1 + b1 * sim) * du;
    Tv[(size_t)node * 32 + l16]      = (b0 + a0 * sim) * dw;
    Tv[(size_t)node * 32 + l16 + 16] = (b1 + a1 * sim) * dw;
}

// ---------- generic pull (float4 gather, ushort csr) ----------
template <int F, int S>
__device__ __forceinline__ void pull_body(const float* __restrict__ hs,
                                          const unsigned short* __restrict__ csr,
                                          const int* __restrict__ rowptr,
                                          const unsigned* __restrict__ deg,
                                          const float* __restrict__ dinv,
                                          float* __restrict__ out, int N,
                                          int blk, int tid) {
    constexpr int L = F / 4;
    int node = blk * (256 / L) + tid / L;
    int q = tid % L;
    if (node >= N) return;
    const float4* h4 = reinterpret_cast<const float4*>(hs);
    int beg = rowptr[node];
    int end = beg + (int)deg[node];
    float4 acc = h4[(size_t)node * L + q];
    int e = beg;
    for (; e + 2 <= end; e += 2) {
        int s0 = csr[e], s1 = csr[e + 1];
        float4 v0 = h4[(size_t)s0 * L + q];
        float4 v1 = h4[(size_t)s1 * L + q];
        acc.x += v0.x + v1.x;
        acc.y += v0.y + v1.y;
        acc.z += v0.z + v1.z;
        acc.w += v0.w + v1.w;
    }
    if (e < end) {
        float4 v0 = h4[(size_t)csr[e] * L + q];
        acc.x += v0.x; acc.y += v0.y; acc.z += v0.z; acc.w += v0.w;
    }
    float di = dinv[node];
    float4 r;
    r.x = acc.x * di; r.y = acc.y * di; r.z = acc.z * di; r.w = acc.w * di;
    *reinterpret_cast<float4*>(out + (size_t)node * S + q * 4) = r;
}

__global__ __launch_bounds__(256) void k_pull2(
    const float* __restrict__ hsA, const unsigned short* __restrict__ csrA,
    const int* __restrict__ rpA, const unsigned* __restrict__ degA,
    const float* __restrict__ dinvA, float* __restrict__ outA,
    const float* __restrict__ hsB, const unsigned short* __restrict__ csrB,
    const int* __restrict__ rpB, const unsigned* __restrict__ degB,
    const float* __restrict__ dinvB, float* __restrict__ outB, int N, int half) {
    bool sec = blockIdx.x >= half;
    int blk = sec ? blockIdx.x - half : blockIdx.x;
    if (sec) pull_body<HID, HID>(hsB, csrB, rpB, degB, dinvB, outB, N, blk, threadIdx.x);
    else     pull_body<HID, HID>(hsA, csrA, rpA, degA, dinvA, outA, N, blk, threadIdx.x);
}

__global__ __launch_bounds__(256) void k_pull64(const float* __restrict__ hs,
                                                const unsigned short* __restrict__ csr,
                                                const int* __restrict__ rowptr,
                                                const unsigned* __restrict__ deg,
                                                const float* __restrict__ dinv,
                                                float* __restrict__ out, int N) {
    pull_body<64, 64>(hs, csr, rowptr, deg, dinv, out, N, blockIdx.x, threadIdx.x);
}

// ---------- L2 epilogue: row-per-lane GEMM + in-register sim-mix + pack ----------
__global__ __launch_bounds__(128) void k_hid_mix_pack(const float* __restrict__ zU,
                                                      const float* __restrict__ zV,
                                                      const float* __restrict__ W,
                                                      const float* __restrict__ bias,
                                                      const float* __restrict__ dinvU,
                                                      float* __restrict__ P) {
    int node = blockIdx.x * 128 + threadIdx.x;
    if (node >= NN) return;
    const float4* zu4 = reinterpret_cast<const float4*>(zU + (size_t)node * HID);
    const float4* zv4 = reinterpret_cast<const float4*>(zV + (size_t)node * HID);
    float a[HID], b[HID];
#pragma unroll
    for (int c = 0; c < HID; ++c) { a[c] = bias[c]; b[c] = bias[c]; }
    for (int k4 = 0; k4 < HID / 4; ++k4) {   // uniform loop -> scalar W loads
        float4 u = zu4[k4];
        float4 v = zv4[k4];
        const float* Wk = W + k4 * 4 * HID;
#pragma unroll
        for (int c = 0; c < HID; ++c) {
            float w0 = Wk[c], w1 = Wk[HID + c], w2 = Wk[2 * HID + c], w3 = Wk[3 * HID + c];
            a[c] = fmaf(u.x, w0, a[c]); a[c] = fmaf(u.y, w1, a[c]);
            a[c] = fmaf(u.z, w2, a[c]); a[c] = fmaf(u.w, w3, a[c]);
            b[c] = fmaf(v.x, w0, b[c]); b[c] = fmaf(v.y, w1, b[c]);
            b[c] = fmaf(v.z, w2, b[c]); b[c] = fmaf(v.w, w3, b[c]);
        }
    }
    float n1 = 0.f, n2 = 0.f, dt = 0.f;
#pragma unroll
    for (int c = 0; c < HID; ++c) {
        n1 = fmaf(a[c], a[c], n1);
        n2 = fmaf(b[c], b[c], n2);
        dt = fmaf(a[c], b[c], dt);
    }
    float sim = dt / (fmaxf(sqrtf(n1), EPS) * fmaxf(sqrtf(n2), EPS));
    float du = dinvU[node];
    float4* p4 = reinterpret_cast<float4*>(P + (size_t)node * 64);
#pragma unroll
    for (int q = 0; q < HID / 4; ++q) {
        float4 m, s;
        m.x = (a[4 * q + 0] + b[4 * q + 0] * sim) * du;
        m.y = (a[4 * q + 1] + b[4 * q + 1] * sim) * du;
        m.z = (a[4 * q + 2] + b[4 * q + 2] * sim) * du;
        m.w = (a[4 * q + 3] + b[4 * q + 3] * sim) * du;
        s.x = (b[4 * q + 0] + a[4 * q + 0] * sim) * du;
        s.y = (b[4 * q + 1] + a[4 * q + 1] * sim) * du;
        s.z = (b[4 * q + 2] + a[4 * q + 2] * sim) * du;
        s.w = (b[4 * q + 3] + a[4 * q + 3] * sim) * du;
        p4[q] = m;
        p4[q + 8] = s;
    }
}

// ---------- L3 GEMM: 64 rows/block, wave = 32-col slice, scalar W ----------
__global__ __launch_bounds__(256) void k_gemm_out2(const float* __restrict__ Q,
                                                   const float* __restrict__ W,
                                                   const float* __restrict__ b,
                                                   float* __restrict__ out, int N) {
    int lane = threadIdx.x & 63;
    int c0 = __builtin_amdgcn_readfirstlane((threadIdx.x >> 6) * 32);  // wave-uniform col base
    int row = blockIdx.x * 64 + lane;
    if (row >= N) return;
    const float4* q4 = reinterpret_cast<const float4*>(Q + (size_t)row * 64);
    float a1[32], a2[32];
#pragma unroll
    for (int j = 0; j < 32; ++j) { a1[j] = b[c0 + j]; a2[j] = a1[j]; }
    for (int k4 = 0; k4 < 8; ++k4) {   // uniform loop -> scalar W loads
        float4 v1 = q4[k4];
        float4 v2 = q4[k4 + 8];
        const float* Wk = W + (k4 * 4) * FOUT + c0;
#pragma unroll
        for (int j = 0; j < 32; ++j) {
            float w0 = Wk[j], w1 = Wk[FOUT + j], w2 = Wk[2 * FOUT + j], w3 = Wk[3 * FOUT + j];
            a1[j] = fmaf(v1.x, w0, a1[j]); a1[j] = fmaf(v1.y, w1, a1[j]);
            a1[j] = fmaf(v1.z, w2, a1[j]); a1[j] = fmaf(v1.w, w3, a1[j]);
            a2[j] = fmaf(v2.x, w0, a2[j]); a2[j] = fmaf(v2.y, w1, a2[j]);
            a2[j] = fmaf(v2.z, w2, a2[j]); a2[j] = fmaf(v2.w, w3, a2[j]);
        }
    }
    float* o1 = out + (size_t)row * OSTR + c0;
    float* o2 = o1 + FOUT;
#pragma unroll
    for (int q = 0; q < 8; ++q) {
        *reinterpret_cast<float4*>(o1 + 4 * q) =
            make_float4(a1[4 * q], a1[4 * q + 1], a1[4 * q + 2], a1[4 * q + 3]);
        *reinterpret_cast<float4*>(o2 + 4 * q) =
            make_float4(a2[4 * q], a2[4 * q + 1], a2[4 * q + 2], a2[4 * q + 3]);
    }
}

// ---------------- host ----------------
extern "C" void kernel_launch(void* const* d_in, const int* in_sizes, int n_in,
                              void* d_out, int out_size, void* d_ws, size_t ws_size,
                              hipStream_t stream) {
    const float* x     = (const float*)d_in[0];
    const int*   ei_u  = (const int*)d_in[1];
    const int*   ei_u2 = (const int*)d_in[2];
    const float* W_in  = (const float*)d_in[3];
    const float* b_in  = (const float*)d_in[4];
    const float* W_hid = (const float*)d_in[5];
    const float* b_hid = (const float*)d_in[6];
    const float* W_out = (const float*)d_in[7];
    const float* b_out = (const float*)d_in[8];
    float* out = (float*)d_out;

    const int* src_u  = ei_u;
    const int* dst_u  = ei_u + NE;
    const int* src_u2 = ei_u2;
    const int* dst_u2 = ei_u2 + NE;

    char* w = (char*)d_ws;
    auto carve = [&](size_t bytes) {
        char* p = w;
        w += (bytes + 255) & ~(size_t)255;
        return p;
    };
    unsigned* hc_u   = (unsigned*)carve((size_t)NCH * NSB * sizeof(unsigned));
    unsigned* hc_u2  = (unsigned*)carve((size_t)NCH * NSB * sizeof(unsigned));
    unsigned* tot_u  = (unsigned*)carve(NSB * sizeof(unsigned));
    unsigned* tot_u2 = (unsigned*)carve(NSB * sizeof(unsigned));
    int*      bb_u   = (int*)carve((NSB + 1) * sizeof(int));
    int*      bb_u2  = (int*)carve((NSB + 1) * sizeof(int));
    unsigned* deg_u  = (unsigned*)carve(NN * sizeof(unsigned));
    unsigned* deg_u2 = (unsigned*)carve(NN * sizeof(unsigned));
    float*    dinv_u  = (float*)carve(NN * sizeof(float));
    float*    dinv_u2 = (float*)carve(NN * sizeof(float));
    int*      rp_u   = (int*)carve(NN * sizeof(int));
    int*      rp_u2  = (int*)carve(NN * sizeof(int));
    unsigned short* csr_u  = (unsigned short*)carve((size_t)NE * sizeof(unsigned short));
    unsigned short* csr_u2 = (unsigned short*)carve((size_t)NE * sizeof(unsigned short));
    float* h    = (float*)carve((size_t)NN * HID * sizeof(float));
    float* T_u  = (float*)carve((size_t)NN * HID * sizeof(float));
    float* T_u2 = (float*)carve((size_t)NN * HID * sizeof(float));
    float* z_u  = (float*)carve((size_t)NN * HID * sizeof(float));
    float* z_u2 = (float*)carve((size_t)NN * HID * sizeof(float));
    float* P    = (float*)carve((size_t)NN * 64 * sizeof(float));
    float* Q    = (float*)carve((size_t)NN * 64 * sizeof(float));
    int* tmp_u  = (int*)P;
    int* tmp_u2 = (int*)Q;

    const int BLK = 256;
    const int gP32 = (NN + 31) / 32;   // 1563
    const int gP64 = (NN + 15) / 16;   // 3125
    const int gR64 = (NN + 63) / 64;   // 782 (row-per-lane blocks of 64)
    const int gR128 = (NN + 127) / 128;// 391

    // --- CSR build ---
    k_hist<<<2 * NCH, BLK, 0, stream>>>(dst_u, dst_u2, hc_u, hc_u2, NCH);
    k_cscan<<<2 * NSB, BLK, 0, stream>>>(hc_u, hc_u2, tot_u, tot_u2, NSB);
    k_bscan<<<2, BLK, 0, stream>>>(tot_u, tot_u2, bb_u, bb_u2);
    k_bin1<<<2 * NCH, BLK, 0, stream>>>(src_u, dst_u, hc_u, bb_u, tmp_u,
                                        src_u2, dst_u2, hc_u2, bb_u2, tmp_u2, NCH);
    k_bin2<<<2 * NSB, BLK, 0, stream>>>(tmp_u, bb_u, csr_u, deg_u, dinv_u, rp_u,
                                        tmp_u2, bb_u2, csr_u2, deg_u2, dinv_u2, rp_u2, NSB);

    // --- layer 1 ---
    k_gemm_in<<<gR64, 64, 0, stream>>>(x, W_in, h, NN);
    k_pull_mix<<<gP64, BLK, 0, stream>>>(h,
        csr_u, rp_u, deg_u, dinv_u,
        csr_u2, rp_u2, deg_u2, dinv_u2,
        b_in, T_u, T_u2);

    // --- layer 2: aggregate-then-GEMM ---
    k_pull2<<<2 * gP32, BLK, 0, stream>>>(
        T_u, csr_u, rp_u, deg_u, dinv_u, z_u,
        T_u2, csr_u2, rp_u2, deg_u2, dinv_u2, z_u2, NN, gP32);
    k_hid_mix_pack<<<gR128, 128, 0, stream>>>(z_u, z_u2, W_hid, b_hid, dinv_u, P);

    // --- layer 3 ---
    k_pull64<<<gP64, BLK, 0, stream>>>(P, csr_u, rp_u, deg_u, dinv_u, Q, NN);
    k_gemm_out2<<<gR64, BLK, 0, stream>>>(Q, W_out, b_out, out, NN);

    (void)in_sizes; (void)n_in; (void)out_size; (void)ws_size;
}

// Round 9
// 305.593 us; speedup vs baseline: 3.0244x; 1.0240x over previous
//
#include <hip/hip_runtime.h>
#include <hip/hip_bf16.h>

#define NN 50000
#define NE 1600000
#define NIN 256
#define HID 32
#define FOUT 128
#define OSTR 256
#define NSB ((NN + 255) / 256)      // 196 superbuckets of 256 nodes
#define CHUNK 2048
#define NCH ((NE + CHUNK - 1) / CHUNK)  // 782 chunks per view

static constexpr float EPS = 1e-12f;

// ---------- pass 0: per-chunk histogram, stored (no atomics) ----------
__global__ __launch_bounds__(256) void k_hist(const int* __restrict__ dstA,
                                              const int* __restrict__ dstB,
                                              unsigned* __restrict__ hcA,
                                              unsigned* __restrict__ hcB, int half) {
    __shared__ unsigned h[NSB];
    for (int i = threadIdx.x; i < NSB; i += 256) h[i] = 0u;
    __syncthreads();
    bool sec = blockIdx.x >= half;
    int c = sec ? blockIdx.x - half : blockIdx.x;
    const int* dst = sec ? dstB : dstA;
    unsigned* hc = sec ? hcB : hcA;
    int beg = c * CHUNK, end = min(beg + CHUNK, NE);
    for (int e = beg + (int)threadIdx.x; e < end; e += 256)
        atomicAdd(&h[dst[e] >> 8], 1u);
    __syncthreads();
    for (int i = threadIdx.x; i < NSB; i += 256) hc[(size_t)c * NSB + i] = h[i];
}

// ---------- per-bucket scan over chunks ----------
__global__ __launch_bounds__(256) void k_cscan(unsigned* __restrict__ hcA,
                                               unsigned* __restrict__ hcB,
                                               unsigned* __restrict__ totA,
                                               unsigned* __restrict__ totB, int half) {
    __shared__ unsigned tile[256];
    __shared__ unsigned carry;
    bool sec = blockIdx.x >= half;
    int sb = sec ? blockIdx.x - half : blockIdx.x;
    unsigned* hc = sec ? hcB : hcA;
    unsigned* tot = sec ? totB : totA;
    if (threadIdx.x == 0) carry = 0u;
    __syncthreads();
    for (int base = 0; base < NCH; base += 256) {
        int c = base + (int)threadIdx.x;
        unsigned v = (c < NCH) ? hc[(size_t)c * NSB + sb] : 0u;
        tile[threadIdx.x] = v;
        __syncthreads();
        for (int off = 1; off < 256; off <<= 1) {
            unsigned t = (threadIdx.x >= (unsigned)off) ? tile[threadIdx.x - off] : 0u;
            __syncthreads();
            tile[threadIdx.x] += t;
            __syncthreads();
        }
        if (c < NCH) hc[(size_t)c * NSB + sb] = carry + tile[threadIdx.x] - v;
        __syncthreads();
        if (threadIdx.x == 0) carry += tile[255];
        __syncthreads();
    }
    if (threadIdx.x == 0) tot[sb] = carry;
}

// ---------- bucket bases ----------
__global__ __launch_bounds__(256) void k_bscan(const unsigned* __restrict__ totA,
                                               const unsigned* __restrict__ totB,
                                               int* __restrict__ bbA, int* __restrict__ bbB) {
    __shared__ unsigned tile[256];
    const unsigned* tot = blockIdx.x ? totB : totA;
    int* bb = blockIdx.x ? bbB : bbA;
    unsigned v = (threadIdx.x < NSB) ? tot[threadIdx.x] : 0u;
    tile[threadIdx.x] = v;
    __syncthreads();
    for (int off = 1; off < 256; off <<= 1) {
        unsigned t = (threadIdx.x >= (unsigned)off) ? tile[threadIdx.x - off] : 0u;
        __syncthreads();
        tile[threadIdx.x] += t;
        __syncthreads();
    }
    if (threadIdx.x < NSB) bb[threadIdx.x] = (int)(tile[threadIdx.x] - v);
    if (threadIdx.x == 0) bb[NSB] = NE;
}

// ---------- pass 1: coarse scatter ----------
__global__ __launch_bounds__(256) void k_bin1(const int* __restrict__ srcA,
                                              const int* __restrict__ dstA,
                                              const unsigned* __restrict__ hcA,
                                              const int* __restrict__ bbA,
                                              int* __restrict__ tmpA,
                                              const int* __restrict__ srcB,
                                              const int* __restrict__ dstB,
                                              const unsigned* __restrict__ hcB,
                                              const int* __restrict__ bbB,
                                              int* __restrict__ tmpB, int half) {
    __shared__ unsigned hbase[NSB];
    __shared__ unsigned hcnt[NSB];
    bool sec = blockIdx.x >= half;
    int c = sec ? blockIdx.x - half : blockIdx.x;
    const int* src = sec ? srcB : srcA;
    const int* dst = sec ? dstB : dstA;
    const unsigned* hc = sec ? hcB : hcA;
    const int* bb = sec ? bbB : bbA;
    int* tmp = sec ? tmpB : tmpA;
    for (int i = threadIdx.x; i < NSB; i += 256) {
        hbase[i] = (unsigned)bb[i] + hc[(size_t)c * NSB + i];
        hcnt[i] = 0u;
    }
    __syncthreads();
    int beg = c * CHUNK, end = min(beg + CHUNK, NE);
    for (int e = beg + (int)threadIdx.x; e < end; e += 256) {
        int d = dst[e];
        int sb = d >> 8;
        unsigned pos = hbase[sb] + atomicAdd(&hcnt[sb], 1u);
        tmp[pos] = ((d & 255) << 16) | src[e];
    }
}

// ---------- pass 2: per-superbucket fine scatter + deg/rowptr/dinv ----------
__global__ __launch_bounds__(256) void k_bin2(const int* __restrict__ tmpA,
                                              const int* __restrict__ bbA,
                                              unsigned short* __restrict__ csrA,
                                              unsigned* __restrict__ degA,
                                              float* __restrict__ dinvA,
                                              int* __restrict__ rpA,
                                              const int* __restrict__ tmpB,
                                              const int* __restrict__ bbB,
                                              unsigned short* __restrict__ csrB,
                                              unsigned* __restrict__ degB,
                                              float* __restrict__ dinvB,
                                              int* __restrict__ rpB, int half) {
    __shared__ unsigned cnt[256];
    __shared__ unsigned scan[256];
    __shared__ unsigned curs[256];
    bool sec = blockIdx.x >= half;
    int sb = sec ? blockIdx.x - half : blockIdx.x;
    const int* tmp = sec ? tmpB : tmpA;
    const int* bb = sec ? bbB : bbA;
    unsigned short* csr = sec ? csrB : csrA;
    unsigned* deg = sec ? degB : degA;
    float* dinv = sec ? dinvB : dinvA;
    int* rp = sec ? rpB : rpA;
    int beg = bb[sb], end = bb[sb + 1];
    cnt[threadIdx.x] = 0u;
    __syncthreads();
    for (int e = beg + (int)threadIdx.x; e < end; e += 256)
        atomicAdd(&cnt[(tmp[e] >> 16) & 255], 1u);
    __syncthreads();
    unsigned v = cnt[threadIdx.x];
    scan[threadIdx.x] = v;
    __syncthreads();
    for (int off = 1; off < 256; off <<= 1) {
        unsigned t = (threadIdx.x >= (unsigned)off) ? scan[threadIdx.x - off] : 0u;
        __syncthreads();
        scan[threadIdx.x] += t;
        __syncthreads();
    }
    unsigned excl = scan[threadIdx.x] - v;
    int n = sb * 256 + (int)threadIdx.x;
    if (n < NN) {
        deg[n] = v;
        rp[n] = beg + (int)excl;
        dinv[n] = rsqrtf((float)(v + 1u));
    }
    curs[threadIdx.x] = (unsigned)beg + excl;
    __syncthreads();
    for (int e = beg + (int)threadIdx.x; e < end; e += 256) {
        int p = tmp[e];
        unsigned pos = atomicAdd(&curs[(p >> 16) & 255], 1u);
        csr[pos] = (unsigned short)(p & 0xFFFF);
    }
}

// ---------- layer-1 GEMM: 4 waves/block, wave = 8-col slice, scalar W, unroll-4 ----------
__global__ __launch_bounds__(256) void k_gemm_in(const float* __restrict__ x,
                                                 const float* __restrict__ W,
                                                 float* __restrict__ h, int N) {
    int lane = threadIdx.x & 63;
    int c0 = __builtin_amdgcn_readfirstlane((threadIdx.x >> 6) * 8);  // wave-uniform col base
    int row = blockIdx.x * 64 + lane;
    if (row >= N) return;
    const float4* xr = reinterpret_cast<const float4*>(x + (size_t)row * NIN);
    float acc[8];
#pragma unroll
    for (int j = 0; j < 8; ++j) acc[j] = 0.f;
#pragma unroll 4
    for (int k4 = 0; k4 < NIN / 4; ++k4) {   // uniform k4, uniform c0 -> scalar W loads
        float4 v = xr[k4];
        const float* Wk = W + k4 * 4 * HID + c0;
#pragma unroll
        for (int j = 0; j < 8; ++j) {
            acc[j] = fmaf(v.x, Wk[j], acc[j]);
            acc[j] = fmaf(v.y, Wk[HID + j], acc[j]);
            acc[j] = fmaf(v.z, Wk[2 * HID + j], acc[j]);
            acc[j] = fmaf(v.w, Wk[3 * HID + j], acc[j]);
        }
    }
    float4* hr = reinterpret_cast<float4*>(h + (size_t)row * HID + c0);
    hr[0] = make_float4(acc[0], acc[1], acc[2], acc[3]);
    hr[1] = make_float4(acc[4], acc[5], acc[6], acc[7]);
}

// ---------- L1: pull both views from SHARED h + fused sim-mix ----------
__global__ __launch_bounds__(256) void k_pull_mix(
    const float* __restrict__ h,
    const unsigned short* __restrict__ csrU, const int* __restrict__ rpU,
    const unsigned* __restrict__ degU, const float* __restrict__ dinvU,
    const unsigned short* __restrict__ csrV, const int* __restrict__ rpV,
    const unsigned* __restrict__ degV, const float* __restrict__ dinvV,
    const float* __restrict__ bin, float* __restrict__ Tu, float* __restrict__ Tv) {
    __shared__ float sh[16][2][36];
    int t = threadIdx.x;
    int nl = t >> 4;
    int view = (t >> 3) & 1;
    int q = t & 7;
    int node = blockIdx.x * 16 + nl;
    const unsigned short* csr = view ? csrV : csrU;
    const int* rp = view ? rpV : rpU;
    const unsigned* deg = view ? degV : degU;
    const float* dv = view ? dinvV : dinvU;
    const float4* h4 = reinterpret_cast<const float4*>(h);
    float dnode = dv[node];
    float4 self = h4[(size_t)node * 8 + q];
    float4 acc;
    acc.x = self.x * dnode; acc.y = self.y * dnode;
    acc.z = self.z * dnode; acc.w = self.w * dnode;
    int beg = rp[node];
    int end = beg + (int)deg[node];
    int e = beg;
    for (; e + 2 <= end; e += 2) {
        int s0 = csr[e], s1 = csr[e + 1];
        float w0 = dv[s0], w1 = dv[s1];
        float4 x0 = h4[(size_t)s0 * 8 + q];
        float4 x1 = h4[(size_t)s1 * 8 + q];
        acc.x = fmaf(x0.x, w0, acc.x); acc.y = fmaf(x0.y, w0, acc.y);
        acc.z = fmaf(x0.z, w0, acc.z); acc.w = fmaf(x0.w, w0, acc.w);
        acc.x = fmaf(x1.x, w1, acc.x); acc.y = fmaf(x1.y, w1, acc.y);
        acc.z = fmaf(x1.z, w1, acc.z); acc.w = fmaf(x1.w, w1, acc.w);
    }
    if (e < end) {
        int s0 = csr[e];
        float w0 = dv[s0];
        float4 x0 = h4[(size_t)s0 * 8 + q];
        acc.x = fmaf(x0.x, w0, acc.x); acc.y = fmaf(x0.y, w0, acc.y);
        acc.z = fmaf(x0.z, w0, acc.z); acc.w = fmaf(x0.w, w0, acc.w);
    }
    sh[nl][view][q * 4 + 0] = fmaf(acc.x, dnode, bin[q * 4 + 0]);
    sh[nl][view][q * 4 + 1] = fmaf(acc.y, dnode, bin[q * 4 + 1]);
    sh[nl][view][q * 4 + 2] = fmaf(acc.z, dnode, bin[q * 4 + 2]);
    sh[nl][view][q * 4 + 3] = fmaf(acc.w, dnode, bin[q * 4 + 3]);
    __syncthreads();
    int l16 = t & 15;
    float a0 = sh[nl][0][l16], a1 = sh[nl][0][l16 + 16];
    float b0 = sh[nl][1][l16], b1 = sh[nl][1][l16 + 16];
    float n1 = a0 * a0 + a1 * a1;
    float n2 = b0 * b0 + b1 * b1;
    float dt = a0 * b0 + a1 * b1;
#pragma unroll
    for (int m = 8; m >= 1; m >>= 1) {
        n1 += __shfl_xor(n1, m);
        n2 += __shfl_xor(n2, m);
        dt += __shfl_xor(dt, m);
    }
    float sim = dt / (fmaxf(sqrtf(n1), EPS) * fmaxf(sqrtf(n2), EPS));
    float du = dinvU[node], dw = dinvV[node];
    Tu[(size_t)node * 32 + l16]      = (a0 + b0 * sim) * du;
    Tu[(size_t)node * 32 + l16 + 16] = (a1 + b1 * sim) * du;
    Tv[(size_t)node * 32 + l16]      = (b0 + a0 * sim) * dw;
    Tv[(size_t)node * 32 + l16 + 16] = (b1 + a1 * sim) * dw;
}

// ---------- generic pull (float4 gather, ushort csr) ----------
template <int F, int S>
__device__ __forceinline__ void pull_body(const float* __restrict__ hs,
                                          const unsigned short* __restrict__ csr,
                                          const int* __restrict__ rowptr,
                                          const unsigned* __restrict__ deg,
                                          const float* __restrict__ dinv,
                                          float* __restrict__ out, int N,
                                          int blk, int tid) {
    constexpr int L = F / 4;
    int node = blk * (256 / L) + tid / L;
    int q = tid % L;
    if (node >= N) return;
    const float4* h4 = reinterpret_cast<const float4*>(hs);
    int beg = rowptr[node];
    int end = beg + (int)deg[node];
    float4 acc = h4[(size_t)node * L + q];
    int e = beg;
    for (; e + 2 <= end; e += 2) {
        int s0 = csr[e], s1 = csr[e + 1];
        float4 v0 = h4[(size_t)s0 * L + q];
        float4 v1 = h4[(size_t)s1 * L + q];
        acc.x += v0.x + v1.x;
        acc.y += v0.y + v1.y;
        acc.z += v0.z + v1.z;
        acc.w += v0.w + v1.w;
    }
    if (e < end) {
        float4 v0 = h4[(size_t)csr[e] * L + q];
        acc.x += v0.x; acc.y += v0.y; acc.z += v0.z; acc.w += v0.w;
    }
    float di = dinv[node];
    float4 r;
    r.x = acc.x * di; r.y = acc.y * di; r.z = acc.z * di; r.w = acc.w * di;
    *reinterpret_cast<float4*>(out + (size_t)node * S + q * 4) = r;
}

__global__ __launch_bounds__(256) void k_pull2(
    const float* __restrict__ hsA, const unsigned short* __restrict__ csrA,
    const int* __restrict__ rpA, const unsigned* __restrict__ degA,
    const float* __restrict__ dinvA, float* __restrict__ outA,
    const float* __restrict__ hsB, const unsigned short* __restrict__ csrB,
    const int* __restrict__ rpB, const unsigned* __restrict__ degB,
    const float* __restrict__ dinvB, float* __restrict__ outB, int N, int half) {
    bool sec = blockIdx.x >= half;
    int blk = sec ? blockIdx.x - half : blockIdx.x;
    if (sec) pull_body<HID, HID>(hsB, csrB, rpB, degB, dinvB, outB, N, blk, threadIdx.x);
    else     pull_body<HID, HID>(hsA, csrA, rpA, degA, dinvA, outA, N, blk, threadIdx.x);
}

__global__ __launch_bounds__(256) void k_pull64(const float* __restrict__ hs,
                                                const unsigned short* __restrict__ csr,
                                                const int* __restrict__ rowptr,
                                                const unsigned* __restrict__ deg,
                                                const float* __restrict__ dinv,
                                                float* __restrict__ out, int N) {
    pull_body<64, 64>(hs, csr, rowptr, deg, dinv, out, N, blockIdx.x, threadIdx.x);
}

// ---------- L2 epilogue: row-per-lane GEMM + in-register sim-mix + pack ----------
__global__ __launch_bounds__(128) void k_hid_mix_pack(const float* __restrict__ zU,
                                                      const float* __restrict__ zV,
                                                      const float* __restrict__ W,
                                                      const float* __restrict__ bias,
                                                      const float* __restrict__ dinvU,
                                                      float* __restrict__ P) {
    int node = blockIdx.x * 128 + threadIdx.x;
    if (node >= NN) return;
    const float4* zu4 = reinterpret_cast<const float4*>(zU + (size_t)node * HID);
    const float4* zv4 = reinterpret_cast<const float4*>(zV + (size_t)node * HID);
    float a[HID], b[HID];
#pragma unroll
    for (int c = 0; c < HID; ++c) { a[c] = bias[c]; b[c] = bias[c]; }
#pragma unroll
    for (int k4 = 0; k4 < HID / 4; ++k4) {   // fully unrolled -> all z loads issued up front
        float4 u = zu4[k4];
        float4 v = zv4[k4];
        const float* Wk = W + k4 * 4 * HID;
#pragma unroll
        for (int c = 0; c < HID; ++c) {
            float w0 = Wk[c], w1 = Wk[HID + c], w2 = Wk[2 * HID + c], w3 = Wk[3 * HID + c];
            a[c] = fmaf(u.x, w0, a[c]); a[c] = fmaf(u.y, w1, a[c]);
            a[c] = fmaf(u.z, w2, a[c]); a[c] = fmaf(u.w, w3, a[c]);
            b[c] = fmaf(v.x, w0, b[c]); b[c] = fmaf(v.y, w1, b[c]);
            b[c] = fmaf(v.z, w2, b[c]); b[c] = fmaf(v.w, w3, b[c]);
        }
    }
    float n1 = 0.f, n2 = 0.f, dt = 0.f;
#pragma unroll
    for (int c = 0; c < HID; ++c) {
        n1 = fmaf(a[c], a[c], n1);
        n2 = fmaf(b[c], b[c], n2);
        dt = fmaf(a[c], b[c], dt);
    }
    float sim = dt / (fmaxf(sqrtf(n1), EPS) * fmaxf(sqrtf(n2), EPS));
    float du = dinvU[node];
    float4* p4 = reinterpret_cast<float4*>(P + (size_t)node * 64);
#pragma unroll
    for (int q = 0; q < HID / 4; ++q) {
        float4 m, s;
        m.x = (a[4 * q + 0] + b[4 * q + 0] * sim) * du;
        m.y = (a[4 * q + 1] + b[4 * q + 1] * sim) * du;
        m.z = (a[4 * q + 2] + b[4 * q + 2] * sim) * du;
        m.w = (a[4 * q + 3] + b[4 * q + 3] * sim) * du;
        s.x = (b[4 * q + 0] + a[4 * q + 0] * sim) * du;
        s.y = (b[4 * q + 1] + a[4 * q + 1] * sim) * du;
        s.z = (b[4 * q + 2] + a[4 * q + 2] * sim) * du;
        s.w = (b[4 * q + 3] + a[4 * q + 3] * sim) * du;
        p4[q] = m;
        p4[q + 8] = s;
    }
}

// ---------- L3 GEMM: 64 rows/block, wave = 32-col slice, scalar W ----------
__global__ __launch_bounds__(256) void k_gemm_out2(const float* __restrict__ Q,
                                                   const float* __restrict__ W,
                                                   const float* __restrict__ b,
                                                   float* __restrict__ out, int N) {
    int lane = threadIdx.x & 63;
    int c0 = __builtin_amdgcn_readfirstlane((threadIdx.x >> 6) * 32);  // wave-uniform col base
    int row = blockIdx.x * 64 + lane;
    if (row >= N) return;
    const float4* q4 = reinterpret_cast<const float4*>(Q + (size_t)row * 64);
    float a1[32], a2[32];
#pragma unroll
    for (int j = 0; j < 32; ++j) { a1[j] = b[c0 + j]; a2[j] = a1[j]; }
#pragma unroll 2
    for (int k4 = 0; k4 < 8; ++k4) {   // uniform loop -> scalar W loads
        float4 v1 = q4[k4];
        float4 v2 = q4[k4 + 8];
        const float* Wk = W + (k4 * 4) * FOUT + c0;
#pragma unroll
        for (int j = 0; j < 32; ++j) {
            float w0 = Wk[j], w1 = Wk[FOUT + j], w2 = Wk[2 * FOUT + j], w3 = Wk[3 * FOUT + j];
            a1[j] = fmaf(v1.x, w0, a1[j]); a1[j] = fmaf(v1.y, w1, a1[j]);
            a1[j] = fmaf(v1.z, w2, a1[j]); a1[j] = fmaf(v1.w, w3, a1[j]);
            a2[j] = fmaf(v2.x, w0, a2[j]); a2[j] = fmaf(v2.y, w1, a2[j]);
            a2[j] = fmaf(v2.z, w2, a2[j]); a2[j] = fmaf(v2.w, w3, a2[j]);
        }
    }
    float* o1 = out + (size_t)row * OSTR + c0;
    float* o2 = o1 + FOUT;
#pragma unroll
    for (int q = 0; q < 8; ++q) {
        *reinterpret_cast<float4*>(o1 + 4 * q) =
            make_float4(a1[4 * q], a1[4 * q + 1], a1[4 * q + 2], a1[4 * q + 3]);
        *reinterpret_cast<float4*>(o2 + 4 * q) =
            make_float4(a2[4 * q], a2[4 * q + 1], a2[4 * q + 2], a2[4 * q + 3]);
    }
}

// ---------------- host ----------------
extern "C" void kernel_launch(void* const* d_in, const int* in_sizes, int n_in,
                              void* d_out, int out_size, void* d_ws, size_t ws_size,
                              hipStream_t stream) {
    const float* x     = (const float*)d_in[0];
    const int*   ei_u  = (const int*)d_in[1];
    const int*   ei_u2 = (const int*)d_in[2];
    const float* W_in  = (const float*)d_in[3];
    const float* b_in  = (const float*)d_in[4];
    const float* W_hid = (const float*)d_in[5];
    const float* b_hid = (const float*)d_in[6];
    const float* W_out = (const float*)d_in[7];
    const float* b_out = (const float*)d_in[8];
    float* out = (float*)d_out;

    const int* src_u  = ei_u;
    const int* dst_u  = ei_u + NE;
    const int* src_u2 = ei_u2;
    const int* dst_u2 = ei_u2 + NE;

    char* w = (char*)d_ws;
    auto carve = [&](size_t bytes) {
        char* p = w;
        w += (bytes + 255) & ~(size_t)255;
        return p;
    };
    unsigned* hc_u   = (unsigned*)carve((size_t)NCH * NSB * sizeof(unsigned));
    unsigned* hc_u2  = (unsigned*)carve((size_t)NCH * NSB * sizeof(unsigned));
    unsigned* tot_u  = (unsigned*)carve(NSB * sizeof(unsigned));
    unsigned* tot_u2 = (unsigned*)carve(NSB * sizeof(unsigned));
    int*      bb_u   = (int*)carve((NSB + 1) * sizeof(int));
    int*      bb_u2  = (int*)carve((NSB + 1) * sizeof(int));
    unsigned* deg_u  = (unsigned*)carve(NN * sizeof(unsigned));
    unsigned* deg_u2 = (unsigned*)carve(NN * sizeof(unsigned));
    float*    dinv_u  = (float*)carve(NN * sizeof(float));
    float*    dinv_u2 = (float*)carve(NN * sizeof(float));
    int*      rp_u   = (int*)carve(NN * sizeof(int));
    int*      rp_u2  = (int*)carve(NN * sizeof(int));
    unsigned short* csr_u  = (unsigned short*)carve((size_t)NE * sizeof(unsigned short));
    unsigned short* csr_u2 = (unsigned short*)carve((size_t)NE * sizeof(unsigned short));
    float* h    = (float*)carve((size_t)NN * HID * sizeof(float));
    float* T_u  = (float*)carve((size_t)NN * HID * sizeof(float));
    float* T_u2 = (float*)carve((size_t)NN * HID * sizeof(float));
    float* z_u  = (float*)carve((size_t)NN * HID * sizeof(float));
    float* z_u2 = (float*)carve((size_t)NN * HID * sizeof(float));
    float* P    = (float*)carve((size_t)NN * 64 * sizeof(float));
    float* Q    = (float*)carve((size_t)NN * 64 * sizeof(float));
    int* tmp_u  = (int*)P;
    int* tmp_u2 = (int*)Q;

    const int BLK = 256;
    const int gP32 = (NN + 31) / 32;   // 1563
    const int gP64 = (NN + 15) / 16;   // 3125
    const int gR64 = (NN + 63) / 64;   // 782 (64 rows per 4-wave block)
    const int gR128 = (NN + 127) / 128;// 391

    // --- CSR build ---
    k_hist<<<2 * NCH, BLK, 0, stream>>>(dst_u, dst_u2, hc_u, hc_u2, NCH);
    k_cscan<<<2 * NSB, BLK, 0, stream>>>(hc_u, hc_u2, tot_u, tot_u2, NSB);
    k_bscan<<<2, BLK, 0, stream>>>(tot_u, tot_u2, bb_u, bb_u2);
    k_bin1<<<2 * NCH, BLK, 0, stream>>>(src_u, dst_u, hc_u, bb_u, tmp_u,
                                        src_u2, dst_u2, hc_u2, bb_u2, tmp_u2, NCH);
    k_bin2<<<2 * NSB, BLK, 0, stream>>>(tmp_u, bb_u, csr_u, deg_u, dinv_u, rp_u,
                                        tmp_u2, bb_u2, csr_u2, deg_u2, dinv_u2, rp_u2, NSB);

    // --- layer 1 ---
    k_gemm_in<<<gR64, BLK, 0, stream>>>(x, W_in, h, NN);
    k_pull_mix<<<gP64, BLK, 0, stream>>>(h,
        csr_u, rp_u, deg_u, dinv_u,
        csr_u2, rp_u2, deg_u2, dinv_u2,
        b_in, T_u, T_u2);

    // --- layer 2: aggregate-then-GEMM ---
    k_pull2<<<2 * gP32, BLK, 0, stream>>>(
        T_u, csr_u, rp_u, deg_u, dinv_u, z_u,
        T_u2, csr_u2, rp_u2, deg_u2, dinv_u2, z_u2, NN, gP32);
    k_hid_mix_pack<<<gR128, 128, 0, stream>>>(z_u, z_u2, W_hid, b_hid, dinv_u, P);

    // --- layer 3 ---
    k_pull64<<<gP64, BLK, 0, stream>>>(P, csr_u, rp_u, deg_u, dinv_u, Q, NN);
    k_gemm_out2<<<gR64, BLK, 0, stream>>>(Q, W_out, b_out, out, NN);

    (void)in_sizes; (void)n_in; (void)out_size; (void)ws_size;
}

// Round 10
// 254.185 us; speedup vs baseline: 3.6361x; 1.2022x over previous
//
#include <hip/hip_runtime.h>
#include <hip/hip_bf16.h>

#define NN 50000
#define NE 1600000
#define NIN 256
#define HID 32
#define FOUT 128
#define OSTR 256
#define NSB ((NN + 255) / 256)      // 196 superbuckets of 256 nodes
#define CHUNK 2048
#define NCH ((NE + CHUNK - 1) / CHUNK)  // 782 chunks per view

static constexpr float EPS = 1e-12f;

// ---------- bf16 helpers (tables stored bf16, all math f32) ----------
__device__ __forceinline__ float b2f(unsigned short s) {
    return __uint_as_float((unsigned)s << 16);
}
__device__ __forceinline__ unsigned short f2b(float f) {
    unsigned u = __float_as_uint(f);
    u += 0x7FFFu + ((u >> 16) & 1u);   // round-to-nearest-even
    return (unsigned short)(u >> 16);
}
__device__ __forceinline__ unsigned pack2(float a, float b) {
    return (unsigned)f2b(a) | ((unsigned)f2b(b) << 16);
}

// ---------- pass 0: per-chunk histogram, stored (no atomics) ----------
__global__ __launch_bounds__(256) void k_hist(const int* __restrict__ dstA,
                                              const int* __restrict__ dstB,
                                              unsigned* __restrict__ hcA,
                                              unsigned* __restrict__ hcB, int half) {
    __shared__ unsigned h[NSB];
    for (int i = threadIdx.x; i < NSB; i += 256) h[i] = 0u;
    __syncthreads();
    bool sec = blockIdx.x >= half;
    int c = sec ? blockIdx.x - half : blockIdx.x;
    const int* dst = sec ? dstB : dstA;
    unsigned* hc = sec ? hcB : hcA;
    int beg = c * CHUNK, end = min(beg + CHUNK, NE);
    for (int e = beg + (int)threadIdx.x; e < end; e += 256)
        atomicAdd(&h[dst[e] >> 8], 1u);
    __syncthreads();
    for (int i = threadIdx.x; i < NSB; i += 256) hc[(size_t)c * NSB + i] = h[i];
}

// ---------- per-bucket scan over chunks ----------
__global__ __launch_bounds__(256) void k_cscan(unsigned* __restrict__ hcA,
                                               unsigned* __restrict__ hcB,
                                               unsigned* __restrict__ totA,
                                               unsigned* __restrict__ totB, int half) {
    __shared__ unsigned tile[256];
    __shared__ unsigned carry;
    bool sec = blockIdx.x >= half;
    int sb = sec ? blockIdx.x - half : blockIdx.x;
    unsigned* hc = sec ? hcB : hcA;
    unsigned* tot = sec ? totB : totA;
    if (threadIdx.x == 0) carry = 0u;
    __syncthreads();
    for (int base = 0; base < NCH; base += 256) {
        int c = base + (int)threadIdx.x;
        unsigned v = (c < NCH) ? hc[(size_t)c * NSB + sb] : 0u;
        tile[threadIdx.x] = v;
        __syncthreads();
        for (int off = 1; off < 256; off <<= 1) {
            unsigned t = (threadIdx.x >= (unsigned)off) ? tile[threadIdx.x - off] : 0u;
            __syncthreads();
            tile[threadIdx.x] += t;
            __syncthreads();
        }
        if (c < NCH) hc[(size_t)c * NSB + sb] = carry + tile[threadIdx.x] - v;
        __syncthreads();
        if (threadIdx.x == 0) carry += tile[255];
        __syncthreads();
    }
    if (threadIdx.x == 0) tot[sb] = carry;
}

// ---------- bucket bases ----------
__global__ __launch_bounds__(256) void k_bscan(const unsigned* __restrict__ totA,
                                               const unsigned* __restrict__ totB,
                                               int* __restrict__ bbA, int* __restrict__ bbB) {
    __shared__ unsigned tile[256];
    const unsigned* tot = blockIdx.x ? totB : totA;
    int* bb = blockIdx.x ? bbB : bbA;
    unsigned v = (threadIdx.x < NSB) ? tot[threadIdx.x] : 0u;
    tile[threadIdx.x] = v;
    __syncthreads();
    for (int off = 1; off < 256; off <<= 1) {
        unsigned t = (threadIdx.x >= (unsigned)off) ? tile[threadIdx.x - off] : 0u;
        __syncthreads();
        tile[threadIdx.x] += t;
        __syncthreads();
    }
    if (threadIdx.x < NSB) bb[threadIdx.x] = (int)(tile[threadIdx.x] - v);
    if (threadIdx.x == 0) bb[NSB] = NE;
}

// ---------- pass 1: LDS counting-sort per chunk, ordered coalesced flush ----------
__global__ __launch_bounds__(256) void k_bin1(const int* __restrict__ srcA,
                                              const int* __restrict__ dstA,
                                              const unsigned* __restrict__ hcA,
                                              const int* __restrict__ bbA,
                                              int* __restrict__ tmpA,
                                              const int* __restrict__ srcB,
                                              const int* __restrict__ dstB,
                                              const unsigned* __restrict__ hcB,
                                              const int* __restrict__ bbB,
                                              int* __restrict__ tmpB, int half) {
    __shared__ unsigned hbase[NSB];
    __shared__ unsigned hcur[NSB];
    __shared__ unsigned hscan[NSB];
    __shared__ unsigned tile[256];
    __shared__ unsigned pay[CHUNK];
    __shared__ unsigned gpos[CHUNK];
    bool sec = blockIdx.x >= half;
    int c = sec ? blockIdx.x - half : blockIdx.x;
    const int* src = sec ? srcB : srcA;
    const int* dst = sec ? dstB : dstA;
    const unsigned* hc = sec ? hcB : hcA;
    const int* bb = sec ? bbB : bbA;
    int* tmp = sec ? tmpB : tmpA;
    for (int i = threadIdx.x; i < NSB; i += 256) {
        hbase[i] = (unsigned)bb[i] + hc[(size_t)c * NSB + i];
        hcur[i] = 0u;
    }
    __syncthreads();
    int beg = c * CHUNK;
    int len = min(CHUNK, NE - beg);
    int d[8], s[8];
#pragma unroll
    for (int j = 0; j < 8; ++j) {
        int idx = j * 256 + (int)threadIdx.x;
        if (idx < len) { d[j] = dst[beg + idx]; s[j] = src[beg + idx]; }
        else d[j] = -1;
    }
#pragma unroll
    for (int j = 0; j < 8; ++j)
        if (d[j] >= 0) atomicAdd(&hcur[d[j] >> 8], 1u);
    __syncthreads();
    // exclusive scan of the 196 counts (single 256-tile)
    unsigned v = (threadIdx.x < NSB) ? hcur[threadIdx.x] : 0u;
    tile[threadIdx.x] = v;
    __syncthreads();
    for (int off = 1; off < 256; off <<= 1) {
        unsigned t = (threadIdx.x >= (unsigned)off) ? tile[threadIdx.x - off] : 0u;
        __syncthreads();
        tile[threadIdx.x] += t;
        __syncthreads();
    }
    if (threadIdx.x < NSB) {
        unsigned excl = tile[threadIdx.x] - v;
        hscan[threadIdx.x] = excl;
        hcur[threadIdx.x] = excl;   // reuse as insert cursor
    }
    __syncthreads();
#pragma unroll
    for (int j = 0; j < 8; ++j) {
        if (d[j] >= 0) {
            int sb = d[j] >> 8;
            unsigned p = atomicAdd(&hcur[sb], 1u);
            pay[p] = ((unsigned)(d[j] & 255) << 16) | (unsigned)s[j];
            gpos[p] = hbase[sb] + (p - hscan[sb]);
        }
    }
    __syncthreads();
    // ordered flush: consecutive i -> contiguous global runs per bucket
    for (int i = threadIdx.x; i < len; i += 256)
        tmp[gpos[i]] = (int)pay[i];
}

// ---------- pass 2: per-superbucket fine scatter + deg/rowptr/dinv ----------
__global__ __launch_bounds__(256) void k_bin2(const int* __restrict__ tmpA,
                                              const int* __restrict__ bbA,
                                              unsigned short* __restrict__ csrA,
                                              unsigned* __restrict__ degA,
                                              float* __restrict__ dinvA,
                                              int* __restrict__ rpA,
                                              const int* __restrict__ tmpB,
                                              const int* __restrict__ bbB,
                                              unsigned short* __restrict__ csrB,
                                              unsigned* __restrict__ degB,
                                              float* __restrict__ dinvB,
                                              int* __restrict__ rpB, int half) {
    __shared__ unsigned cnt[256];
    __shared__ unsigned scan[256];
    __shared__ unsigned curs[256];
    bool sec = blockIdx.x >= half;
    int sb = sec ? blockIdx.x - half : blockIdx.x;
    const int* tmp = sec ? tmpB : tmpA;
    const int* bb = sec ? bbB : bbA;
    unsigned short* csr = sec ? csrB : csrA;
    unsigned* deg = sec ? degB : degA;
    float* dinv = sec ? dinvB : dinvA;
    int* rp = sec ? rpB : rpA;
    int beg = bb[sb], end = bb[sb + 1];
    cnt[threadIdx.x] = 0u;
    __syncthreads();
    for (int e = beg + (int)threadIdx.x; e < end; e += 256)
        atomicAdd(&cnt[(tmp[e] >> 16) & 255], 1u);
    __syncthreads();
    unsigned v = cnt[threadIdx.x];
    scan[threadIdx.x] = v;
    __syncthreads();
    for (int off = 1; off < 256; off <<= 1) {
        unsigned t = (threadIdx.x >= (unsigned)off) ? scan[threadIdx.x - off] : 0u;
        __syncthreads();
        scan[threadIdx.x] += t;
        __syncthreads();
    }
    unsigned excl = scan[threadIdx.x] - v;
    int n = sb * 256 + (int)threadIdx.x;
    if (n < NN) {
        deg[n] = v;
        rp[n] = beg + (int)excl;
        dinv[n] = rsqrtf((float)(v + 1u));
    }
    curs[threadIdx.x] = (unsigned)beg + excl;
    __syncthreads();
    for (int e = beg + (int)threadIdx.x; e < end; e += 256) {
        int p = tmp[e];
        unsigned pos = atomicAdd(&curs[(p >> 16) & 255], 1u);
        csr[pos] = (unsigned short)(p & 0xFFFF);
    }
}

// ---------- layer-1 GEMM: 4 waves/block, wave = 8-col slice, scalar W, bf16 out ----------
__global__ __launch_bounds__(256) void k_gemm_in(const float* __restrict__ x,
                                                 const float* __restrict__ W,
                                                 unsigned short* __restrict__ h, int N) {
    int lane = threadIdx.x & 63;
    int c0 = __builtin_amdgcn_readfirstlane((threadIdx.x >> 6) * 8);
    int row = blockIdx.x * 64 + lane;
    if (row >= N) return;
    const float4* xr = reinterpret_cast<const float4*>(x + (size_t)row * NIN);
    float acc[8];
#pragma unroll
    for (int j = 0; j < 8; ++j) acc[j] = 0.f;
#pragma unroll 4
    for (int k4 = 0; k4 < NIN / 4; ++k4) {
        float4 v = xr[k4];
        const float* Wk = W + k4 * 4 * HID + c0;
#pragma unroll
        for (int j = 0; j < 8; ++j) {
            acc[j] = fmaf(v.x, Wk[j], acc[j]);
            acc[j] = fmaf(v.y, Wk[HID + j], acc[j]);
            acc[j] = fmaf(v.z, Wk[2 * HID + j], acc[j]);
            acc[j] = fmaf(v.w, Wk[3 * HID + j], acc[j]);
        }
    }
    uint4 wv;
    wv.x = pack2(acc[0], acc[1]);
    wv.y = pack2(acc[2], acc[3]);
    wv.z = pack2(acc[4], acc[5]);
    wv.w = pack2(acc[6], acc[7]);
    *reinterpret_cast<uint4*>(h + (size_t)row * HID + c0) = wv;
}

// ---------- L1: pull both views from SHARED bf16 h + fused sim-mix, bf16 T out ----------
__global__ __launch_bounds__(256) void k_pull_mix(
    const unsigned short* __restrict__ h,
    const unsigned short* __restrict__ csrU, const int* __restrict__ rpU,
    const unsigned* __restrict__ degU, const float* __restrict__ dinvU,
    const unsigned short* __restrict__ csrV, const int* __restrict__ rpV,
    const unsigned* __restrict__ degV, const float* __restrict__ dinvV,
    const float* __restrict__ bin,
    unsigned short* __restrict__ Tu, unsigned short* __restrict__ Tv) {
    __shared__ float sh[16][2][36];
    int t = threadIdx.x;
    int nl = t >> 4;
    int view = (t >> 3) & 1;
    int q = t & 7;
    int node = blockIdx.x * 16 + nl;   // 3125*16 = 50000 exact
    const unsigned short* csr = view ? csrV : csrU;
    const int* rp = view ? rpV : rpU;
    const unsigned* deg = view ? degV : degU;
    const float* dv = view ? dinvV : dinvU;
    const ushort4* h4 = reinterpret_cast<const ushort4*>(h);
    float dnode = dv[node];
    ushort4 sv = h4[(size_t)node * 8 + q];
    float4 acc;
    acc.x = b2f(sv.x) * dnode; acc.y = b2f(sv.y) * dnode;
    acc.z = b2f(sv.z) * dnode; acc.w = b2f(sv.w) * dnode;
    int beg = rp[node];
    int end = beg + (int)deg[node];
    int e = beg;
    for (; e + 2 <= end; e += 2) {
        int s0 = csr[e], s1 = csr[e + 1];
        float w0 = dv[s0], w1 = dv[s1];
        ushort4 x0 = h4[(size_t)s0 * 8 + q];
        ushort4 x1 = h4[(size_t)s1 * 8 + q];
        acc.x = fmaf(b2f(x0.x), w0, acc.x); acc.y = fmaf(b2f(x0.y), w0, acc.y);
        acc.z = fmaf(b2f(x0.z), w0, acc.z); acc.w = fmaf(b2f(x0.w), w0, acc.w);
        acc.x = fmaf(b2f(x1.x), w1, acc.x); acc.y = fmaf(b2f(x1.y), w1, acc.y);
        acc.z = fmaf(b2f(x1.z), w1, acc.z); acc.w = fmaf(b2f(x1.w), w1, acc.w);
    }
    if (e < end) {
        int s0 = csr[e];
        float w0 = dv[s0];
        ushort4 x0 = h4[(size_t)s0 * 8 + q];
        acc.x = fmaf(b2f(x0.x), w0, acc.x); acc.y = fmaf(b2f(x0.y), w0, acc.y);
        acc.z = fmaf(b2f(x0.z), w0, acc.z); acc.w = fmaf(b2f(x0.w), w0, acc.w);
    }
    sh[nl][view][q * 4 + 0] = fmaf(acc.x, dnode, bin[q * 4 + 0]);
    sh[nl][view][q * 4 + 1] = fmaf(acc.y, dnode, bin[q * 4 + 1]);
    sh[nl][view][q * 4 + 2] = fmaf(acc.z, dnode, bin[q * 4 + 2]);
    sh[nl][view][q * 4 + 3] = fmaf(acc.w, dnode, bin[q * 4 + 3]);
    __syncthreads();
    int l16 = t & 15;
    float a0 = sh[nl][0][l16], a1 = sh[nl][0][l16 + 16];
    float b0 = sh[nl][1][l16], b1 = sh[nl][1][l16 + 16];
    float n1 = a0 * a0 + a1 * a1;
    float n2 = b0 * b0 + b1 * b1;
    float dt = a0 * b0 + a1 * b1;
#pragma unroll
    for (int m = 8; m >= 1; m >>= 1) {
        n1 += __shfl_xor(n1, m);
        n2 += __shfl_xor(n2, m);
        dt += __shfl_xor(dt, m);
    }
    float sim = dt / (fmaxf(sqrtf(n1), EPS) * fmaxf(sqrtf(n2), EPS));
    float du = dinvU[node], dw = dinvV[node];
    Tu[(size_t)node * 32 + l16]      = f2b((a0 + b0 * sim) * du);
    Tu[(size_t)node * 32 + l16 + 16] = f2b((a1 + b1 * sim) * du);
    Tv[(size_t)node * 32 + l16]      = f2b((b0 + a0 * sim) * dw);
    Tv[(size_t)node * 32 + l16 + 16] = f2b((b1 + a1 * sim) * dw);
}

// ---------- generic pull: bf16 table gather, f32 accumulate, f32 out ----------
template <int F, int S>
__device__ __forceinline__ void pull_body(const unsigned short* __restrict__ hs,
                                          const unsigned short* __restrict__ csr,
                                          const int* __restrict__ rowptr,
                                          const unsigned* __restrict__ deg,
                                          const float* __restrict__ dinv,
                                          float* __restrict__ out, int N,
                                          int blk, int tid) {
    constexpr int L = F / 4;
    int node = blk * (256 / L) + tid / L;
    int q = tid % L;
    if (node >= N) return;
    const ushort4* h4 = reinterpret_cast<const ushort4*>(hs);
    int beg = rowptr[node];
    int end = beg + (int)deg[node];
    ushort4 sv = h4[(size_t)node * L + q];
    float4 acc;
    acc.x = b2f(sv.x); acc.y = b2f(sv.y); acc.z = b2f(sv.z); acc.w = b2f(sv.w);
    int e = beg;
    for (; e + 2 <= end; e += 2) {
        int s0 = csr[e], s1 = csr[e + 1];
        ushort4 v0 = h4[(size_t)s0 * L + q];
        ushort4 v1 = h4[(size_t)s1 * L + q];
        acc.x += b2f(v0.x) + b2f(v1.x);
        acc.y += b2f(v0.y) + b2f(v1.y);
        acc.z += b2f(v0.z) + b2f(v1.z);
        acc.w += b2f(v0.w) + b2f(v1.w);
    }
    if (e < end) {
        ushort4 v0 = h4[(size_t)csr[e] * L + q];
        acc.x += b2f(v0.x); acc.y += b2f(v0.y);
        acc.z += b2f(v0.z); acc.w += b2f(v0.w);
    }
    float di = dinv[node];
    float4 r;
    r.x = acc.x * di; r.y = acc.y * di; r.z = acc.z * di; r.w = acc.w * di;
    *reinterpret_cast<float4*>(out + (size_t)node * S + q * 4) = r;
}

__global__ __launch_bounds__(256) void k_pull2(
    const unsigned short* __restrict__ hsA, const unsigned short* __restrict__ csrA,
    const int* __restrict__ rpA, const unsigned* __restrict__ degA,
    const float* __restrict__ dinvA, float* __restrict__ outA,
    const unsigned short* __restrict__ hsB, const unsigned short* __restrict__ csrB,
    const int* __restrict__ rpB, const unsigned* __restrict__ degB,
    const float* __restrict__ dinvB, float* __restrict__ outB, int N, int half) {
    bool sec = blockIdx.x >= half;
    int blk = sec ? blockIdx.x - half : blockIdx.x;
    if (sec) pull_body<HID, HID>(hsB, csrB, rpB, degB, dinvB, outB, N, blk, threadIdx.x);
    else     pull_body<HID, HID>(hsA, csrA, rpA, degA, dinvA, outA, N, blk, threadIdx.x);
}

__global__ __launch_bounds__(256) void k_pull64(const unsigned short* __restrict__ hs,
                                                const unsigned short* __restrict__ csr,
                                                const int* __restrict__ rowptr,
                                                const unsigned* __restrict__ deg,
                                                const float* __restrict__ dinv,
                                                float* __restrict__ out, int N) {
    pull_body<64, 64>(hs, csr, rowptr, deg, dinv, out, N, blockIdx.x, threadIdx.x);
}

// ---------- L2 epilogue: row-per-lane GEMM + in-register sim-mix + bf16 P pack ----------
__global__ __launch_bounds__(128) void k_hid_mix_pack(const float* __restrict__ zU,
                                                      const float* __restrict__ zV,
                                                      const float* __restrict__ W,
                                                      const float* __restrict__ bias,
                                                      const float* __restrict__ dinvU,
                                                      unsigned short* __restrict__ P) {
    int node = blockIdx.x * 128 + threadIdx.x;
    if (node >= NN) return;
    const float4* zu4 = reinterpret_cast<const float4*>(zU + (size_t)node * HID);
    const float4* zv4 = reinterpret_cast<const float4*>(zV + (size_t)node * HID);
    float a[HID], b[HID];
#pragma unroll
    for (int c = 0; c < HID; ++c) { a[c] = bias[c]; b[c] = bias[c]; }
#pragma unroll
    for (int k4 = 0; k4 < HID / 4; ++k4) {
        float4 u = zu4[k4];
        float4 v = zv4[k4];
        const float* Wk = W + k4 * 4 * HID;
#pragma unroll
        for (int c = 0; c < HID; ++c) {
            float w0 = Wk[c], w1 = Wk[HID + c], w2 = Wk[2 * HID + c], w3 = Wk[3 * HID + c];
            a[c] = fmaf(u.x, w0, a[c]); a[c] = fmaf(u.y, w1, a[c]);
            a[c] = fmaf(u.z, w2, a[c]); a[c] = fmaf(u.w, w3, a[c]);
            b[c] = fmaf(v.x, w0, b[c]); b[c] = fmaf(v.y, w1, b[c]);
            b[c] = fmaf(v.z, w2, b[c]); b[c] = fmaf(v.w, w3, b[c]);
        }
    }
    float n1 = 0.f, n2 = 0.f, dt = 0.f;
#pragma unroll
    for (int c = 0; c < HID; ++c) {
        n1 = fmaf(a[c], a[c], n1);
        n2 = fmaf(b[c], b[c], n2);
        dt = fmaf(a[c], b[c], dt);
    }
    float sim = dt / (fmaxf(sqrtf(n1), EPS) * fmaxf(sqrtf(n2), EPS));
    float du = dinvU[node];
    uint4* p4 = reinterpret_cast<uint4*>(P + (size_t)node * 64);
#pragma unroll
    for (int g = 0; g < 4; ++g) {
        int c = g * 8;
        uint4 m, s;
        m.x = pack2((a[c+0] + b[c+0] * sim) * du, (a[c+1] + b[c+1] * sim) * du);
        m.y = pack2((a[c+2] + b[c+2] * sim) * du, (a[c+3] + b[c+3] * sim) * du);
        m.z = pack2((a[c+4] + b[c+4] * sim) * du, (a[c+5] + b[c+5] * sim) * du);
        m.w = pack2((a[c+6] + b[c+6] * sim) * du, (a[c+7] + b[c+7] * sim) * du);
        s.x = pack2((b[c+0] + a[c+0] * sim) * du, (b[c+1] + a[c+1] * sim) * du);
        s.y = pack2((b[c+2] + a[c+2] * sim) * du, (b[c+3] + a[c+3] * sim) * du);
        s.z = pack2((b[c+4] + a[c+4] * sim) * du, (b[c+5] + a[c+5] * sim) * du);
        s.w = pack2((b[c+6] + a[c+6] * sim) * du, (b[c+7] + a[c+7] * sim) * du);
        p4[g] = m;
        p4[g + 4] = s;
    }
}

// ---------- L3 GEMM: 64 rows/block, wave = 32-col slice, scalar W ----------
__global__ __launch_bounds__(256) void k_gemm_out2(const float* __restrict__ Q,
                                                   const float* __restrict__ W,
                                                   const float* __restrict__ b,
                                                   float* __restrict__ out, int N) {
    int lane = threadIdx.x & 63;
    int c0 = __builtin_amdgcn_readfirstlane((threadIdx.x >> 6) * 32);
    int row = blockIdx.x * 64 + lane;
    if (row >= N) return;
    const float4* q4 = reinterpret_cast<const float4*>(Q + (size_t)row * 64);
    float a1[32], a2[32];
#pragma unroll
    for (int j = 0; j < 32; ++j) { a1[j] = b[c0 + j]; a2[j] = a1[j]; }
#pragma unroll 2
    for (int k4 = 0; k4 < 8; ++k4) {
        float4 v1 = q4[k4];
        float4 v2 = q4[k4 + 8];
        const float* Wk = W + (k4 * 4) * FOUT + c0;
#pragma unroll
        for (int j = 0; j < 32; ++j) {
            float w0 = Wk[j], w1 = Wk[FOUT + j], w2 = Wk[2 * FOUT + j], w3 = Wk[3 * FOUT + j];
            a1[j] = fmaf(v1.x, w0, a1[j]); a1[j] = fmaf(v1.y, w1, a1[j]);
            a1[j] = fmaf(v1.z, w2, a1[j]); a1[j] = fmaf(v1.w, w3, a1[j]);
            a2[j] = fmaf(v2.x, w0, a2[j]); a2[j] = fmaf(v2.y, w1, a2[j]);
            a2[j] = fmaf(v2.z, w2, a2[j]); a2[j] = fmaf(v2.w, w3, a2[j]);
        }
    }
    float* o1 = out + (size_t)row * OSTR + c0;
    float* o2 = o1 + FOUT;
#pragma unroll
    for (int q = 0; q < 8; ++q) {
        *reinterpret_cast<float4*>(o1 + 4 * q) =
            make_float4(a1[4 * q], a1[4 * q + 1], a1[4 * q + 2], a1[4 * q + 3]);
        *reinterpret_cast<float4*>(o2 + 4 * q) =
            make_float4(a2[4 * q], a2[4 * q + 1], a2[4 * q + 2], a2[4 * q + 3]);
    }
}

// ---------------- host ----------------
extern "C" void kernel_launch(void* const* d_in, const int* in_sizes, int n_in,
                              void* d_out, int out_size, void* d_ws, size_t ws_size,
                              hipStream_t stream) {
    const float* x     = (const float*)d_in[0];
    const int*   ei_u  = (const int*)d_in[1];
    const int*   ei_u2 = (const int*)d_in[2];
    const float* W_in  = (const float*)d_in[3];
    const float* b_in  = (const float*)d_in[4];
    const float* W_hid = (const float*)d_in[5];
    const float* b_hid = (const float*)d_in[6];
    const float* W_out = (const float*)d_in[7];
    const float* b_out = (const float*)d_in[8];
    float* out = (float*)d_out;

    const int* src_u  = ei_u;
    const int* dst_u  = ei_u + NE;
    const int* src_u2 = ei_u2;
    const int* dst_u2 = ei_u2 + NE;

    char* w = (char*)d_ws;
    auto carve = [&](size_t bytes) {
        char* p = w;
        w += (bytes + 255) & ~(size_t)255;
        return p;
    };
    unsigned* hc_u   = (unsigned*)carve((size_t)NCH * NSB * sizeof(unsigned));
    unsigned* hc_u2  = (unsigned*)carve((size_t)NCH * NSB * sizeof(unsigned));
    unsigned* tot_u  = (unsigned*)carve(NSB * sizeof(unsigned));
    unsigned* tot_u2 = (unsigned*)carve(NSB * sizeof(unsigned));
    int*      bb_u   = (int*)carve((NSB + 1) * sizeof(int));
    int*      bb_u2  = (int*)carve((NSB + 1) * sizeof(int));
    unsigned* deg_u  = (unsigned*)carve(NN * sizeof(unsigned));
    unsigned* deg_u2 = (unsigned*)carve(NN * sizeof(unsigned));
    float*    dinv_u  = (float*)carve(NN * sizeof(float));
    float*    dinv_u2 = (float*)carve(NN * sizeof(float));
    int*      rp_u   = (int*)carve(NN * sizeof(int));
    int*      rp_u2  = (int*)carve(NN * sizeof(int));
    unsigned short* csr_u  = (unsigned short*)carve((size_t)NE * sizeof(unsigned short));
    unsigned short* csr_u2 = (unsigned short*)carve((size_t)NE * sizeof(unsigned short));
    unsigned short* h    = (unsigned short*)carve((size_t)NN * HID * sizeof(unsigned short));
    unsigned short* T_u  = (unsigned short*)carve((size_t)NN * HID * sizeof(unsigned short));
    unsigned short* T_u2 = (unsigned short*)carve((size_t)NN * HID * sizeof(unsigned short));
    float* z_u  = (float*)carve((size_t)NN * HID * sizeof(float));
    float* z_u2 = (float*)carve((size_t)NN * HID * sizeof(float));
    unsigned short* P = (unsigned short*)carve((size_t)NE * sizeof(int));  // >= NN*64*2
    float* Q = (float*)carve((size_t)NN * 64 * sizeof(float));
    // coarse-bin payload buffers alias P (exact fit) and Q
    int* tmp_u  = (int*)P;
    int* tmp_u2 = (int*)Q;

    const int BLK = 256;
    const int gP32 = (NN + 31) / 32;   // 1563
    const int gP64 = (NN + 15) / 16;   // 3125
    const int gR64 = (NN + 63) / 64;   // 782
    const int gR128 = (NN + 127) / 128;// 391

    // --- CSR build ---
    k_hist<<<2 * NCH, BLK, 0, stream>>>(dst_u, dst_u2, hc_u, hc_u2, NCH);
    k_cscan<<<2 * NSB, BLK, 0, stream>>>(hc_u, hc_u2, tot_u, tot_u2, NSB);
    k_bscan<<<2, BLK, 0, stream>>>(tot_u, tot_u2, bb_u, bb_u2);
    k_bin1<<<2 * NCH, BLK, 0, stream>>>(src_u, dst_u, hc_u, bb_u, tmp_u,
                                        src_u2, dst_u2, hc_u2, bb_u2, tmp_u2, NCH);
    k_bin2<<<2 * NSB, BLK, 0, stream>>>(tmp_u, bb_u, csr_u, deg_u, dinv_u, rp_u,
                                        tmp_u2, bb_u2, csr_u2, deg_u2, dinv_u2, rp_u2, NSB);

    // --- layer 1 ---
    k_gemm_in<<<gR64, BLK, 0, stream>>>(x, W_in, h, NN);
    k_pull_mix<<<gP64, BLK, 0, stream>>>(h,
        csr_u, rp_u, deg_u, dinv_u,
        csr_u2, rp_u2, deg_u2, dinv_u2,
        b_in, T_u, T_u2);

    // --- layer 2: aggregate-then-GEMM ---
    k_pull2<<<2 * gP32, BLK, 0, stream>>>(
        T_u, csr_u, rp_u, deg_u, dinv_u, z_u,
        T_u2, csr_u2, rp_u2, deg_u2, dinv_u2, z_u2, NN, gP32);
    k_hid_mix_pack<<<gR128, 128, 0, stream>>>(z_u, z_u2, W_hid, b_hid, dinv_u, P);

    // --- layer 3 ---
    k_pull64<<<gP64, BLK, 0, stream>>>(P, csr_u, rp_u, deg_u, dinv_u, Q, NN);
    k_gemm_out2<<<gR64, BLK, 0, stream>>>(Q, W_out, b_out, out, NN);

    (void)in_sizes; (void)n_in; (void)out_size; (void)ws_size;
}

// Round 11
// 229.318 us; speedup vs baseline: 4.0304x; 1.1084x over previous
//
#include <hip/hip_runtime.h>
#include <hip/hip_bf16.h>

#define NN 50000
#define NE 1600000
#define NIN 256
#define HID 32
#define FOUT 128
#define OSTR 256
#define NSB ((NN + 255) / 256)      // 196 superbuckets of 256 nodes
#define CHUNK 2048
#define NCH ((NE + CHUNK - 1) / CHUNK)  // 782 chunks per view

static constexpr float EPS = 1e-12f;

// ---------- bf16 helpers (tables stored bf16, all math f32) ----------
__device__ __forceinline__ float b2f(unsigned short s) {
    return __uint_as_float((unsigned)s << 16);
}
__device__ __forceinline__ unsigned short f2b(float f) {
    unsigned u = __float_as_uint(f);
    u += 0x7FFFu + ((u >> 16) & 1u);   // round-to-nearest-even
    return (unsigned short)(u >> 16);
}
__device__ __forceinline__ unsigned pack2(float a, float b) {
    return (unsigned)f2b(a) | ((unsigned)f2b(b) << 16);
}

// ---------- pass 0: per-chunk histogram, stored (no atomics) ----------
__global__ __launch_bounds__(256) void k_hist(const int* __restrict__ dstA,
                                              const int* __restrict__ dstB,
                                              unsigned* __restrict__ hcA,
                                              unsigned* __restrict__ hcB, int half) {
    __shared__ unsigned h[NSB];
    for (int i = threadIdx.x; i < NSB; i += 256) h[i] = 0u;
    __syncthreads();
    bool sec = blockIdx.x >= half;
    int c = sec ? blockIdx.x - half : blockIdx.x;
    const int* dst = sec ? dstB : dstA;
    unsigned* hc = sec ? hcB : hcA;
    int beg = c * CHUNK, end = min(beg + CHUNK, NE);
    for (int e = beg + (int)threadIdx.x; e < end; e += 256)
        atomicAdd(&h[dst[e] >> 8], 1u);
    __syncthreads();
    for (int i = threadIdx.x; i < NSB; i += 256) hc[(size_t)c * NSB + i] = h[i];
}

// ---------- per-bucket scan over chunks ----------
__global__ __launch_bounds__(256) void k_cscan(unsigned* __restrict__ hcA,
                                               unsigned* __restrict__ hcB,
                                               unsigned* __restrict__ totA,
                                               unsigned* __restrict__ totB, int half) {
    __shared__ unsigned tile[256];
    __shared__ unsigned carry;
    bool sec = blockIdx.x >= half;
    int sb = sec ? blockIdx.x - half : blockIdx.x;
    unsigned* hc = sec ? hcB : hcA;
    unsigned* tot = sec ? totB : totA;
    if (threadIdx.x == 0) carry = 0u;
    __syncthreads();
    for (int base = 0; base < NCH; base += 256) {
        int c = base + (int)threadIdx.x;
        unsigned v = (c < NCH) ? hc[(size_t)c * NSB + sb] : 0u;
        tile[threadIdx.x] = v;
        __syncthreads();
        for (int off = 1; off < 256; off <<= 1) {
            unsigned t = (threadIdx.x >= (unsigned)off) ? tile[threadIdx.x - off] : 0u;
            __syncthreads();
            tile[threadIdx.x] += t;
            __syncthreads();
        }
        if (c < NCH) hc[(size_t)c * NSB + sb] = carry + tile[threadIdx.x] - v;
        __syncthreads();
        if (threadIdx.x == 0) carry += tile[255];
        __syncthreads();
    }
    if (threadIdx.x == 0) tot[sb] = carry;
}

// ---------- bucket bases ----------
__global__ __launch_bounds__(256) void k_bscan(const unsigned* __restrict__ totA,
                                               const unsigned* __restrict__ totB,
                                               int* __restrict__ bbA, int* __restrict__ bbB) {
    __shared__ unsigned tile[256];
    const unsigned* tot = blockIdx.x ? totB : totA;
    int* bb = blockIdx.x ? bbB : bbA;
    unsigned v = (threadIdx.x < NSB) ? tot[threadIdx.x] : 0u;
    tile[threadIdx.x] = v;
    __syncthreads();
    for (int off = 1; off < 256; off <<= 1) {
        unsigned t = (threadIdx.x >= (unsigned)off) ? tile[threadIdx.x - off] : 0u;
        __syncthreads();
        tile[threadIdx.x] += t;
        __syncthreads();
    }
    if (threadIdx.x < NSB) bb[threadIdx.x] = (int)(tile[threadIdx.x] - v);
    if (threadIdx.x == 0) bb[NSB] = NE;
}

// ---------- pass 1: LDS counting-sort per chunk, ordered coalesced flush ----------
__global__ __launch_bounds__(256) void k_bin1(const int* __restrict__ srcA,
                                              const int* __restrict__ dstA,
                                              const unsigned* __restrict__ hcA,
                                              const int* __restrict__ bbA,
                                              int* __restrict__ tmpA,
                                              const int* __restrict__ srcB,
                                              const int* __restrict__ dstB,
                                              const unsigned* __restrict__ hcB,
                                              const int* __restrict__ bbB,
                                              int* __restrict__ tmpB, int half) {
    __shared__ unsigned hbase[NSB];
    __shared__ unsigned hcur[NSB];
    __shared__ unsigned hscan[NSB];
    __shared__ unsigned tile[256];
    __shared__ unsigned pay[CHUNK];
    __shared__ unsigned gpos[CHUNK];
    bool sec = blockIdx.x >= half;
    int c = sec ? blockIdx.x - half : blockIdx.x;
    const int* src = sec ? srcB : srcA;
    const int* dst = sec ? dstB : dstA;
    const unsigned* hc = sec ? hcB : hcA;
    const int* bb = sec ? bbB : bbA;
    int* tmp = sec ? tmpB : tmpA;
    for (int i = threadIdx.x; i < NSB; i += 256) {
        hbase[i] = (unsigned)bb[i] + hc[(size_t)c * NSB + i];
        hcur[i] = 0u;
    }
    __syncthreads();
    int beg = c * CHUNK;
    int len = min(CHUNK, NE - beg);
    int d[8], s[8];
#pragma unroll
    for (int j = 0; j < 8; ++j) {
        int idx = j * 256 + (int)threadIdx.x;
        if (idx < len) { d[j] = dst[beg + idx]; s[j] = src[beg + idx]; }
        else d[j] = -1;
    }
#pragma unroll
    for (int j = 0; j < 8; ++j)
        if (d[j] >= 0) atomicAdd(&hcur[d[j] >> 8], 1u);
    __syncthreads();
    unsigned v = (threadIdx.x < NSB) ? hcur[threadIdx.x] : 0u;
    tile[threadIdx.x] = v;
    __syncthreads();
    for (int off = 1; off < 256; off <<= 1) {
        unsigned t = (threadIdx.x >= (unsigned)off) ? tile[threadIdx.x - off] : 0u;
        __syncthreads();
        tile[threadIdx.x] += t;
        __syncthreads();
    }
    if (threadIdx.x < NSB) {
        unsigned excl = tile[threadIdx.x] - v;
        hscan[threadIdx.x] = excl;
        hcur[threadIdx.x] = excl;
    }
    __syncthreads();
#pragma unroll
    for (int j = 0; j < 8; ++j) {
        if (d[j] >= 0) {
            int sb = d[j] >> 8;
            unsigned p = atomicAdd(&hcur[sb], 1u);
            pay[p] = ((unsigned)(d[j] & 255) << 16) | (unsigned)s[j];
            gpos[p] = hbase[sb] + (p - hscan[sb]);
        }
    }
    __syncthreads();
    for (int i = threadIdx.x; i < len; i += 256)
        tmp[gpos[i]] = (int)pay[i];
}

// ---------- pass 2: per-superbucket fine scatter + deg/rowptr/dinv ----------
__global__ __launch_bounds__(256) void k_bin2(const int* __restrict__ tmpA,
                                              const int* __restrict__ bbA,
                                              unsigned short* __restrict__ csrA,
                                              unsigned* __restrict__ degA,
                                              float* __restrict__ dinvA,
                                              int* __restrict__ rpA,
                                              const int* __restrict__ tmpB,
                                              const int* __restrict__ bbB,
                                              unsigned short* __restrict__ csrB,
                                              unsigned* __restrict__ degB,
                                              float* __restrict__ dinvB,
                                              int* __restrict__ rpB, int half) {
    __shared__ unsigned cnt[256];
    __shared__ unsigned scan[256];
    __shared__ unsigned curs[256];
    bool sec = blockIdx.x >= half;
    int sb = sec ? blockIdx.x - half : blockIdx.x;
    const int* tmp = sec ? tmpB : tmpA;
    const int* bb = sec ? bbB : bbA;
    unsigned short* csr = sec ? csrB : csrA;
    unsigned* deg = sec ? degB : degA;
    float* dinv = sec ? dinvB : dinvA;
    int* rp = sec ? rpB : rpA;
    int beg = bb[sb], end = bb[sb + 1];
    cnt[threadIdx.x] = 0u;
    __syncthreads();
    for (int e = beg + (int)threadIdx.x; e < end; e += 256)
        atomicAdd(&cnt[(tmp[e] >> 16) & 255], 1u);
    __syncthreads();
    unsigned v = cnt[threadIdx.x];
    scan[threadIdx.x] = v;
    __syncthreads();
    for (int off = 1; off < 256; off <<= 1) {
        unsigned t = (threadIdx.x >= (unsigned)off) ? scan[threadIdx.x - off] : 0u;
        __syncthreads();
        scan[threadIdx.x] += t;
        __syncthreads();
    }
    unsigned excl = scan[threadIdx.x] - v;
    int n = sb * 256 + (int)threadIdx.x;
    if (n < NN) {
        deg[n] = v;
        rp[n] = beg + (int)excl;
        dinv[n] = rsqrtf((float)(v + 1u));
    }
    curs[threadIdx.x] = (unsigned)beg + excl;
    __syncthreads();
    for (int e = beg + (int)threadIdx.x; e < end; e += 256) {
        int p = tmp[e];
        unsigned pos = atomicAdd(&curs[(p >> 16) & 255], 1u);
        csr[pos] = (unsigned short)(p & 0xFFFF);
    }
}

// ---------- layer-1 GEMM: writes BOTH pre-scaled bf16 tables ----------
__global__ __launch_bounds__(256) void k_gemm_in(const float* __restrict__ x,
                                                 const float* __restrict__ W,
                                                 const float* __restrict__ dinvU,
                                                 const float* __restrict__ dinvV,
                                                 unsigned short* __restrict__ hU,
                                                 unsigned short* __restrict__ hV, int N) {
    int lane = threadIdx.x & 63;
    int c0 = __builtin_amdgcn_readfirstlane((threadIdx.x >> 6) * 8);
    int row = blockIdx.x * 64 + lane;
    if (row >= N) return;
    const float4* xr = reinterpret_cast<const float4*>(x + (size_t)row * NIN);
    float acc[8];
#pragma unroll
    for (int j = 0; j < 8; ++j) acc[j] = 0.f;
#pragma unroll 4
    for (int k4 = 0; k4 < NIN / 4; ++k4) {
        float4 v = xr[k4];
        const float* Wk = W + k4 * 4 * HID + c0;
#pragma unroll
        for (int j = 0; j < 8; ++j) {
            acc[j] = fmaf(v.x, Wk[j], acc[j]);
            acc[j] = fmaf(v.y, Wk[HID + j], acc[j]);
            acc[j] = fmaf(v.z, Wk[2 * HID + j], acc[j]);
            acc[j] = fmaf(v.w, Wk[3 * HID + j], acc[j]);
        }
    }
    float du = dinvU[row], dw = dinvV[row];
    uint4 wu, wv;
    wu.x = pack2(acc[0] * du, acc[1] * du); wu.y = pack2(acc[2] * du, acc[3] * du);
    wu.z = pack2(acc[4] * du, acc[5] * du); wu.w = pack2(acc[6] * du, acc[7] * du);
    wv.x = pack2(acc[0] * dw, acc[1] * dw); wv.y = pack2(acc[2] * dw, acc[3] * dw);
    wv.z = pack2(acc[4] * dw, acc[5] * dw); wv.w = pack2(acc[6] * dw, acc[7] * dw);
    *reinterpret_cast<uint4*>(hU + (size_t)row * HID + c0) = wu;
    *reinterpret_cast<uint4*>(hV + (size_t)row * HID + c0) = wv;
}

// ---------- unified pair pull: pure bf16 gather-sum, XCD-partitioned views ----------
// table rows pre-scaled by dinv[src]; out = f32 raw sum (self + neighbors)
__device__ __forceinline__ void pull_sum(const unsigned short* __restrict__ t,
                                         const unsigned short* __restrict__ csr,
                                         const int* __restrict__ rowptr,
                                         const unsigned* __restrict__ deg,
                                         float* __restrict__ out, int blk, int tid) {
    int node = blk * 32 + tid / 8;
    int q = tid % 8;
    if (node >= NN) return;
    const ushort4* h4 = reinterpret_cast<const ushort4*>(t);
    int beg = rowptr[node];
    int end = beg + (int)deg[node];
    ushort4 sv = h4[(size_t)node * 8 + q];
    float4 acc;
    acc.x = b2f(sv.x); acc.y = b2f(sv.y); acc.z = b2f(sv.z); acc.w = b2f(sv.w);
    int e = beg;
    for (; e + 4 <= end; e += 4) {
        int s0 = csr[e], s1 = csr[e + 1], s2 = csr[e + 2], s3 = csr[e + 3];
        ushort4 v0 = h4[(size_t)s0 * 8 + q];
        ushort4 v1 = h4[(size_t)s1 * 8 + q];
        ushort4 v2 = h4[(size_t)s2 * 8 + q];
        ushort4 v3 = h4[(size_t)s3 * 8 + q];
        acc.x += (b2f(v0.x) + b2f(v1.x)) + (b2f(v2.x) + b2f(v3.x));
        acc.y += (b2f(v0.y) + b2f(v1.y)) + (b2f(v2.y) + b2f(v3.y));
        acc.z += (b2f(v0.z) + b2f(v1.z)) + (b2f(v2.z) + b2f(v3.z));
        acc.w += (b2f(v0.w) + b2f(v1.w)) + (b2f(v2.w) + b2f(v3.w));
    }
    for (; e < end; ++e) {
        ushort4 v0 = h4[(size_t)csr[e] * 8 + q];
        acc.x += b2f(v0.x); acc.y += b2f(v0.y);
        acc.z += b2f(v0.z); acc.w += b2f(v0.w);
    }
    *reinterpret_cast<float4*>(out + (size_t)node * HID + q * 4) = acc;
}

// grid = nPairs*8; XCDs 0-3 take view A, 4-7 view B (blockIdx%8 == XCD heuristic)
__global__ __launch_bounds__(256) void k_pull_pair(
    const unsigned short* __restrict__ tA, const unsigned short* __restrict__ csrA,
    const int* __restrict__ rpA, const unsigned* __restrict__ degA, float* __restrict__ outA,
    const unsigned short* __restrict__ tB, const unsigned short* __restrict__ csrB,
    const int* __restrict__ rpB, const unsigned* __restrict__ degB, float* __restrict__ outB,
    int nblk) {
    int b = blockIdx.x;
    int xcd = b & 7;
    int blk = (b >> 3) * 4 + (xcd & 3);
    if (blk >= nblk) return;
    if (xcd >= 4) pull_sum(tB, csrB, rpB, degB, outB, blk, threadIdx.x);
    else          pull_sum(tA, csrA, rpA, degA, outA, blk, threadIdx.x);
}

// ---------- L1 mix: x = dinv*S + b ; sim ; write next bf16 tables ----------
__global__ __launch_bounds__(256) void k_mix1(const float* __restrict__ Su,
                                              const float* __restrict__ Sv,
                                              const float* __restrict__ dinvU,
                                              const float* __restrict__ dinvV,
                                              const float* __restrict__ bias,
                                              unsigned short* __restrict__ Tu,
                                              unsigned short* __restrict__ Tv) {
    int node = blockIdx.x * 256 + threadIdx.x;
    if (node >= NN) return;
    const float4* su4 = reinterpret_cast<const float4*>(Su + (size_t)node * HID);
    const float4* sv4 = reinterpret_cast<const float4*>(Sv + (size_t)node * HID);
    float du = dinvU[node], dw = dinvV[node];
    float a[HID], b[HID];
#pragma unroll
    for (int k4 = 0; k4 < 8; ++k4) {
        float4 u = su4[k4];
        float4 v = sv4[k4];
        a[4 * k4 + 0] = fmaf(u.x, du, bias[4 * k4 + 0]);
        a[4 * k4 + 1] = fmaf(u.y, du, bias[4 * k4 + 1]);
        a[4 * k4 + 2] = fmaf(u.z, du, bias[4 * k4 + 2]);
        a[4 * k4 + 3] = fmaf(u.w, du, bias[4 * k4 + 3]);
        b[4 * k4 + 0] = fmaf(v.x, dw, bias[4 * k4 + 0]);
        b[4 * k4 + 1] = fmaf(v.y, dw, bias[4 * k4 + 1]);
        b[4 * k4 + 2] = fmaf(v.z, dw, bias[4 * k4 + 2]);
        b[4 * k4 + 3] = fmaf(v.w, dw, bias[4 * k4 + 3]);
    }
    float n1 = 0.f, n2 = 0.f, dt = 0.f;
#pragma unroll
    for (int c = 0; c < HID; ++c) {
        n1 = fmaf(a[c], a[c], n1);
        n2 = fmaf(b[c], b[c], n2);
        dt = fmaf(a[c], b[c], dt);
    }
    float sim = dt / (fmaxf(sqrtf(n1), EPS) * fmaxf(sqrtf(n2), EPS));
    uint4* pu = reinterpret_cast<uint4*>(Tu + (size_t)node * HID);
    uint4* pv = reinterpret_cast<uint4*>(Tv + (size_t)node * HID);
#pragma unroll
    for (int g = 0; g < 4; ++g) {
        int c = g * 8;
        uint4 mu, mv;
        mu.x = pack2((a[c+0] + b[c+0] * sim) * du, (a[c+1] + b[c+1] * sim) * du);
        mu.y = pack2((a[c+2] + b[c+2] * sim) * du, (a[c+3] + b[c+3] * sim) * du);
        mu.z = pack2((a[c+4] + b[c+4] * sim) * du, (a[c+5] + b[c+5] * sim) * du);
        mu.w = pack2((a[c+6] + b[c+6] * sim) * du, (a[c+7] + b[c+7] * sim) * du);
        mv.x = pack2((b[c+0] + a[c+0] * sim) * dw, (b[c+1] + a[c+1] * sim) * dw);
        mv.y = pack2((b[c+2] + a[c+2] * sim) * dw, (b[c+3] + a[c+3] * sim) * dw);
        mv.z = pack2((b[c+4] + a[c+4] * sim) * dw, (b[c+5] + a[c+5] * sim) * dw);
        mv.w = pack2((b[c+6] + a[c+6] * sim) * dw, (b[c+7] + a[c+7] * sim) * dw);
        pu[g] = mu;
        pv[g] = mv;
    }
}

// ---------- L2 epilogue: z = (dinv*S)@W + b, sim-mix, write bf16 Pa/Pb (both dinv_u) ----------
__global__ __launch_bounds__(128) void k_hid_mix_pack(const float* __restrict__ Su,
                                                      const float* __restrict__ Sv,
                                                      const float* __restrict__ W,
                                                      const float* __restrict__ bias,
                                                      const float* __restrict__ dinvU,
                                                      const float* __restrict__ dinvV,
                                                      unsigned short* __restrict__ Pa,
                                                      unsigned short* __restrict__ Pb) {
    int node = blockIdx.x * 128 + threadIdx.x;
    if (node >= NN) return;
    const float4* su4 = reinterpret_cast<const float4*>(Su + (size_t)node * HID);
    const float4* sv4 = reinterpret_cast<const float4*>(Sv + (size_t)node * HID);
    float du = dinvU[node], dw = dinvV[node];
    float a[HID], b[HID];
#pragma unroll
    for (int c = 0; c < HID; ++c) { a[c] = 0.f; b[c] = 0.f; }
#pragma unroll
    for (int k4 = 0; k4 < HID / 4; ++k4) {
        float4 u = su4[k4];
        float4 v = sv4[k4];
        const float* Wk = W + k4 * 4 * HID;
#pragma unroll
        for (int c = 0; c < HID; ++c) {
            float w0 = Wk[c], w1 = Wk[HID + c], w2 = Wk[2 * HID + c], w3 = Wk[3 * HID + c];
            a[c] = fmaf(u.x, w0, a[c]); a[c] = fmaf(u.y, w1, a[c]);
            a[c] = fmaf(u.z, w2, a[c]); a[c] = fmaf(u.w, w3, a[c]);
            b[c] = fmaf(v.x, w0, b[c]); b[c] = fmaf(v.y, w1, b[c]);
            b[c] = fmaf(v.z, w2, b[c]); b[c] = fmaf(v.w, w3, b[c]);
        }
    }
    // fold dinv scale + bias: z1 = du*(S@W) + bias
#pragma unroll
    for (int c = 0; c < HID; ++c) {
        a[c] = fmaf(a[c], du, bias[c]);
        b[c] = fmaf(b[c], dw, bias[c]);
    }
    float n1 = 0.f, n2 = 0.f, dt = 0.f;
#pragma unroll
    for (int c = 0; c < HID; ++c) {
        n1 = fmaf(a[c], a[c], n1);
        n2 = fmaf(b[c], b[c], n2);
        dt = fmaf(a[c], b[c], dt);
    }
    float sim = dt / (fmaxf(sqrtf(n1), EPS) * fmaxf(sqrtf(n2), EPS));
    uint4* pa = reinterpret_cast<uint4*>(Pa + (size_t)node * HID);
    uint4* pb = reinterpret_cast<uint4*>(Pb + (size_t)node * HID);
#pragma unroll
    for (int g = 0; g < 4; ++g) {
        int c = g * 8;
        uint4 ma, mb;
        ma.x = pack2((a[c+0] + b[c+0] * sim) * du, (a[c+1] + b[c+1] * sim) * du);
        ma.y = pack2((a[c+2] + b[c+2] * sim) * du, (a[c+3] + b[c+3] * sim) * du);
        ma.z = pack2((a[c+4] + b[c+4] * sim) * du, (a[c+5] + b[c+5] * sim) * du);
        ma.w = pack2((a[c+6] + b[c+6] * sim) * du, (a[c+7] + b[c+7] * sim) * du);
        mb.x = pack2((b[c+0] + a[c+0] * sim) * du, (b[c+1] + a[c+1] * sim) * du);
        mb.y = pack2((b[c+2] + a[c+2] * sim) * du, (b[c+3] + a[c+3] * sim) * du);
        mb.z = pack2((b[c+4] + a[c+4] * sim) * du, (b[c+5] + a[c+5] * sim) * du);
        mb.w = pack2((b[c+6] + a[c+6] * sim) * du, (b[c+7] + a[c+7] * sim) * du);
        pa[g] = ma;
        pb[g] = mb;
    }
}

// ---------- L3 GEMM: out = (dinv_u*Qa)@W + b | (dinv_u*Qb)@W + b ----------
__global__ __launch_bounds__(256) void k_gemm_out2(const float* __restrict__ Qa,
                                                   const float* __restrict__ Qb,
                                                   const float* __restrict__ dinvU,
                                                   const float* __restrict__ W,
                                                   const float* __restrict__ b,
                                                   float* __restrict__ out, int N) {
    int lane = threadIdx.x & 63;
    int c0 = __builtin_amdgcn_readfirstlane((threadIdx.x >> 6) * 32);
    int row = blockIdx.x * 64 + lane;
    if (row >= N) return;
    const float4* qa4 = reinterpret_cast<const float4*>(Qa + (size_t)row * HID);
    const float4* qb4 = reinterpret_cast<const float4*>(Qb + (size_t)row * HID);
    float a1[32], a2[32];
#pragma unroll
    for (int j = 0; j < 32; ++j) { a1[j] = 0.f; a2[j] = 0.f; }
#pragma unroll 2
    for (int k4 = 0; k4 < 8; ++k4) {
        float4 v1 = qa4[k4];
        float4 v2 = qb4[k4];
        const float* Wk = W + (k4 * 4) * FOUT + c0;
#pragma unroll
        for (int j = 0; j < 32; ++j) {
            float w0 = Wk[j], w1 = Wk[FOUT + j], w2 = Wk[2 * FOUT + j], w3 = Wk[3 * FOUT + j];
            a1[j] = fmaf(v1.x, w0, a1[j]); a1[j] = fmaf(v1.y, w1, a1[j]);
            a1[j] = fmaf(v1.z, w2, a1[j]); a1[j] = fmaf(v1.w, w3, a1[j]);
            a2[j] = fmaf(v2.x, w0, a2[j]); a2[j] = fmaf(v2.y, w1, a2[j]);
            a2[j] = fmaf(v2.z, w2, a2[j]); a2[j] = fmaf(v2.w, w3, a2[j]);
        }
    }
    float du = dinvU[row];
    float* o1 = out + (size_t)row * OSTR + c0;
    float* o2 = o1 + FOUT;
#pragma unroll
    for (int q = 0; q < 8; ++q) {
        float4 r1, r2;
        r1.x = fmaf(a1[4*q+0], du, b[c0+4*q+0]); r1.y = fmaf(a1[4*q+1], du, b[c0+4*q+1]);
        r1.z = fmaf(a1[4*q+2], du, b[c0+4*q+2]); r1.w = fmaf(a1[4*q+3], du, b[c0+4*q+3]);
        r2.x = fmaf(a2[4*q+0], du, b[c0+4*q+0]); r2.y = fmaf(a2[4*q+1], du, b[c0+4*q+1]);
        r2.z = fmaf(a2[4*q+2], du, b[c0+4*q+2]); r2.w = fmaf(a2[4*q+3], du, b[c0+4*q+3]);
        *reinterpret_cast<float4*>(o1 + 4 * q) = r1;
        *reinterpret_cast<float4*>(o2 + 4 * q) = r2;
    }
}

// ---------------- host ----------------
extern "C" void kernel_launch(void* const* d_in, const int* in_sizes, int n_in,
                              void* d_out, int out_size, void* d_ws, size_t ws_size,
                              hipStream_t stream) {
    const float* x     = (const float*)d_in[0];
    const int*   ei_u  = (const int*)d_in[1];
    const int*   ei_u2 = (const int*)d_in[2];
    const float* W_in  = (const float*)d_in[3];
    const float* b_in  = (const float*)d_in[4];
    const float* W_hid = (const float*)d_in[5];
    const float* b_hid = (const float*)d_in[6];
    const float* W_out = (const float*)d_in[7];
    const float* b_out = (const float*)d_in[8];
    float* out = (float*)d_out;

    const int* src_u  = ei_u;
    const int* dst_u  = ei_u + NE;
    const int* src_u2 = ei_u2;
    const int* dst_u2 = ei_u2 + NE;

    char* w = (char*)d_ws;
    auto carve = [&](size_t bytes) {
        char* p = w;
        w += (bytes + 255) & ~(size_t)255;
        return p;
    };
    unsigned* hc_u   = (unsigned*)carve((size_t)NCH * NSB * sizeof(unsigned));
    unsigned* hc_u2  = (unsigned*)carve((size_t)NCH * NSB * sizeof(unsigned));
    unsigned* tot_u  = (unsigned*)carve(NSB * sizeof(unsigned));
    unsigned* tot_u2 = (unsigned*)carve(NSB * sizeof(unsigned));
    int*      bb_u   = (int*)carve((NSB + 1) * sizeof(int));
    int*      bb_u2  = (int*)carve((NSB + 1) * sizeof(int));
    unsigned* deg_u  = (unsigned*)carve(NN * sizeof(unsigned));
    unsigned* deg_u2 = (unsigned*)carve(NN * sizeof(unsigned));
    float*    dinv_u  = (float*)carve(NN * sizeof(float));
    float*    dinv_u2 = (float*)carve(NN * sizeof(float));
    int*      rp_u   = (int*)carve(NN * sizeof(int));
    int*      rp_u2  = (int*)carve(NN * sizeof(int));
    unsigned short* csr_u  = (unsigned short*)carve((size_t)NE * sizeof(unsigned short));
    unsigned short* csr_u2 = (unsigned short*)carve((size_t)NE * sizeof(unsigned short));
    unsigned short* hU = (unsigned short*)carve((size_t)NN * HID * sizeof(unsigned short));
    unsigned short* hV = (unsigned short*)carve((size_t)NN * HID * sizeof(unsigned short));
    unsigned short* Tu = (unsigned short*)carve((size_t)NN * HID * sizeof(unsigned short));
    unsigned short* Tv = (unsigned short*)carve((size_t)NN * HID * sizeof(unsigned short));
    unsigned short* Pa = (unsigned short*)carve((size_t)NN * HID * sizeof(unsigned short));
    unsigned short* Pb = (unsigned short*)carve((size_t)NN * HID * sizeof(unsigned short));
    float* Su = (float*)carve((size_t)NN * HID * sizeof(float));
    float* Sv = (float*)carve((size_t)NN * HID * sizeof(float));
    // coarse-bin payload buffers alias Su/Sv (6.4 MB each; used only before layer 1)
    int* tmp_u  = (int*)Su;
    int* tmp_u2 = (int*)Sv;

    const int BLK = 256;
    const int gP32 = (NN + 31) / 32;       // 1563 blocks per view
    const int nPair = ((gP32 + 3) / 4) * 8; // XCD-partitioned pair grid = 3128
    const int gR64 = (NN + 63) / 64;       // 782
    const int gR128 = (NN + 127) / 128;    // 391
    const int gN = (NN + 255) / 256;       // 196

    // --- CSR build ---
    k_hist<<<2 * NCH, BLK, 0, stream>>>(dst_u, dst_u2, hc_u, hc_u2, NCH);
    k_cscan<<<2 * NSB, BLK, 0, stream>>>(hc_u, hc_u2, tot_u, tot_u2, NSB);
    k_bscan<<<2, BLK, 0, stream>>>(tot_u, tot_u2, bb_u, bb_u2);
    k_bin1<<<2 * NCH, BLK, 0, stream>>>(src_u, dst_u, hc_u, bb_u, tmp_u,
                                        src_u2, dst_u2, hc_u2, bb_u2, tmp_u2, NCH);
    k_bin2<<<2 * NSB, BLK, 0, stream>>>(tmp_u, bb_u, csr_u, deg_u, dinv_u, rp_u,
                                        tmp_u2, bb_u2, csr_u2, deg_u2, dinv_u2, rp_u2, NSB);

    // --- layer 1 ---
    k_gemm_in<<<gR64, BLK, 0, stream>>>(x, W_in, dinv_u, dinv_u2, hU, hV, NN);
    k_pull_pair<<<nPair, BLK, 0, stream>>>(hU, csr_u, rp_u, deg_u, Su,
                                           hV, csr_u2, rp_u2, deg_u2, Sv, gP32);
    k_mix1<<<gN, BLK, 0, stream>>>(Su, Sv, dinv_u, dinv_u2, b_in, Tu, Tv);

    // --- layer 2 (aggregate-then-GEMM) ---
    k_pull_pair<<<nPair, BLK, 0, stream>>>(Tu, csr_u, rp_u, deg_u, Su,
                                           Tv, csr_u2, rp_u2, deg_u2, Sv, gP32);
    k_hid_mix_pack<<<gR128, 128, 0, stream>>>(Su, Sv, W_hid, b_hid, dinv_u, dinv_u2, Pa, Pb);

    // --- layer 3 (both branches on view u) ---
    k_pull_pair<<<nPair, BLK, 0, stream>>>(Pa, csr_u, rp_u, deg_u, Su,
                                           Pb, csr_u, rp_u, deg_u, Sv, gP32);
    k_gemm_out2<<<gR64, BLK, 0, stream>>>(Su, Sv, dinv_u, W_out, b_out, out, NN);

    (void)in_sizes; (void)n_in; (void)out_size; (void)ws_size;
}